// Round 2
// baseline (2894.676 us; speedup 1.0000x reference)
//
#include <hip/hip_runtime.h>
#include <hip/hip_bf16.h>

// Decoder (LSTM + attention captioner), MI355X. Round 14:
//  - r13 post-mortem: persistent k_loop passed but 2170us. FETCH_SIZE=738MB
//    (working set ~85MB): gsync's __threadfence() = seq_cst agent fence =
//    buffer_wbl2+buffer_inv -> full L2 invalidate 15K times. fb/G2/eu were
//    re-fetched from HBM every step. VALUBusy 2.4% -> pure fetch latency.
//  - r14: NO fences at all. Cross-sync payload (hst/zbf A->B, gp B->A) moves
//    via relaxed agent-scope atomics (sc1: bypass L2, hit MALL coherence
//    point per-access). hst[s]/zbf[s] are fresh addresses each step (cannot
//    be stale); gp reuses addresses so A reads it with sc1 loads. Read-only
//    fb/G2/eu/weights stay L2-resident. __syncthreads drains vmcnt before
//    the counter add, giving release ordering without cache ops.

#define NB 64
#define NP 144
#define DE 1792
#define DD 512
#define DA 512
#define EM 300
#define NV 32000
#define NTT 30
#define NS 29
#define G4 2048
#define KP 320
#define KG1 2304
#define LN_EPS 1e-5f
#define RSCALE 0.044194173824159216f   // 1/sqrt(512)

#define NBLK 256      // persistent grid
#define NAB 64        // A-role blocks (one per batch)
#define KSPL 12       // K splits in B-role
#define KSL 192       // K per split (12*192 = 2304)

typedef __attribute__((ext_vector_type(8))) short short8;
typedef __attribute__((ext_vector_type(4))) float f32x4;
typedef __attribute__((ext_vector_type(8))) unsigned short ushort8v;

__device__ __forceinline__ float bf2f(unsigned short u){
  union { unsigned int i; float f; } w; w.i = ((unsigned int)u) << 16; return w.f;
}
__device__ __forceinline__ unsigned short f2bf(float f){
  union { float f; unsigned int i; } u; u.f = f;
  unsigned int r = u.i + 0x7FFFu + ((u.i >> 16) & 1u);
  return (unsigned short)(r >> 16);
}
__device__ __forceinline__ float sigm(float x){ return 1.f/(1.f + __expf(-x)); }

// ---- agent-scope coherent (sc1) accessors: bypass L2, no cache invalidation
__device__ __forceinline__ float aload_f(const float* p){
  return __hip_atomic_load((float*)p, __ATOMIC_RELAXED, __HIP_MEMORY_SCOPE_AGENT);
}
__device__ __forceinline__ unsigned long long aload_u64(const void* p){
  return __hip_atomic_load((unsigned long long*)p, __ATOMIC_RELAXED, __HIP_MEMORY_SCOPE_AGENT);
}
__device__ __forceinline__ void astore_u64(void* p, unsigned long long v){
  __hip_atomic_store((unsigned long long*)p, v, __ATOMIC_RELAXED, __HIP_MEMORY_SCOPE_AGENT);
}
__device__ __forceinline__ void astore_u16(unsigned short* p, unsigned short v){
  __hip_atomic_store(p, v, __ATOMIC_RELAXED, __HIP_MEMORY_SCOPE_AGENT);
}
__device__ __forceinline__ void astore_f(float* p, float v){
  __hip_atomic_store(p, v, __ATOMIC_RELAXED, __HIP_MEMORY_SCOPE_AGENT);
}

__device__ __forceinline__ float wave_reduce_sum(float v){
  #pragma unroll
  for (int o = 32; o >= 1; o >>= 1) v += __shfl_xor(v, o);
  return v;
}
__device__ __forceinline__ float wave_reduce_max(float v){
  #pragma unroll
  for (int o = 32; o >= 1; o >>= 1) v = fmaxf(v, __shfl_xor(v, o));
  return v;
}
__device__ __forceinline__ float block_sum256(float v, float* sbuf){
  v = wave_reduce_sum(v);
  const int lane = threadIdx.x & 63, wid = threadIdx.x >> 6;
  if (lane == 0) sbuf[wid] = v;
  __syncthreads();
  const float r = sbuf[0] + sbuf[1] + sbuf[2] + sbuf[3];
  __syncthreads();
  return r;
}
__device__ __forceinline__ float block_sum512(float v, float* sbuf8){
  v = wave_reduce_sum(v);
  const int lane = threadIdx.x & 63, wid = threadIdx.x >> 6;
  if (lane == 0) sbuf8[wid] = v;
  __syncthreads();
  float r = 0.f;
  #pragma unroll
  for (int i = 0; i < 8; ++i) r += sbuf8[i];
  __syncthreads();
  return r;
}

// ---- manual grid barrier: monotonic counter, NO cache maintenance.
// __syncthreads drains vmcnt(0) per wave (compiler-guaranteed before
// s_barrier), so all prior sc1 payload stores are at the coherence point
// before tid0's counter add. Consumers read payload with sc1 loads.
__device__ __forceinline__ void gsync(unsigned int* cnt, unsigned int target){
  __syncthreads();
  if (threadIdx.x == 0){
    __hip_atomic_fetch_add(cnt, 1u, __ATOMIC_RELAXED, __HIP_MEMORY_SCOPE_AGENT);
    while (__hip_atomic_load(cnt, __ATOMIC_RELAXED, __HIP_MEMORY_SCOPE_AGENT) < target) {}
  }
  __syncthreads();
}

// ---- shared MFMA 64x64-tile helpers (validated r4..r10) ----
__device__ __forceinline__ void stage_tile(const unsigned short* __restrict__ src,
    int row_stride, int k0, char* lds){
  const int tid = threadIdx.x;
  #pragma unroll
  for (int c = 0; c < 2; ++c){
    const int o = tid + c*256;
    const int m = o >> 3, ks8 = o & 7;
    const ushort8v v = *(const ushort8v*)&src[(size_t)m*row_stride + k0 + ks8*8];
    *(ushort8v*)&lds[m*128 + ((ks8 ^ (m&7))<<4)] = v;
  }
}
__device__ __forceinline__ void mma64(const char* Alds, const char* Blds,
    int w, int lane, f32x4 acc[4]){
  #pragma unroll
  for (int ks = 0; ks < 2; ++ks){
    const int slot = ks*4 + (lane>>4);
    const int n = w*16 + (lane&15);
    const short8 bfv = *(const short8*)&Blds[n*128 + ((slot ^ (n&7))<<4)];
    #pragma unroll
    for (int fm = 0; fm < 4; ++fm){
      const int m = fm*16 + (lane&15);
      const short8 afv = *(const short8*)&Alds[m*128 + ((slot ^ (m&7))<<4)];
      acc[fm] = __builtin_amdgcn_mfma_f32_16x16x32_bf16(afv, bfv, acc[fm], 0, 0, 0);
    }
  }
}

// ---- zero t=0 rows of both outputs + the grid-sync counter
__global__ __launch_bounds__(256) void k_zero(float* __restrict__ pred,
                                              float* __restrict__ alph,
                                              unsigned int* __restrict__ syncc){
  const int idx = blockIdx.x * 256 + threadIdx.x;
  if (idx == 0)
    __hip_atomic_store(syncc, 0u, __ATOMIC_RELAXED, __HIP_MEMORY_SCOPE_AGENT);
  {
    const int b = idx / NV, v = idx - b * NV;
    pred[(size_t)b * NTT * NV + v] = 0.f;
  }
  if (idx < NB * NP){
    const int b = idx / NP, p = idx - b * NP;
    alph[(size_t)b * NTT * NP + p] = 0.f;
  }
}

// ---- LayerNorm(features) -> bf16
__global__ __launch_bounds__(256) void k_ln_feats(const float* __restrict__ feats,
    const float* __restrict__ g, const float* __restrict__ bb,
    unsigned short* __restrict__ out){
  __shared__ float sbuf[4];
  const int row = blockIdx.x;
  const float* x = feats + (size_t)row * DE;
  float v[7]; float s = 0.f;
  #pragma unroll
  for (int i = 0; i < 7; ++i){ v[i] = x[i*256 + threadIdx.x]; s += v[i]; }
  const float mean = block_sum256(s, sbuf) * (1.f/DE);
  float q = 0.f;
  #pragma unroll
  for (int i = 0; i < 7; ++i){ const float d = v[i] - mean; q += d*d; }
  const float var = block_sum256(q, sbuf) * (1.f/DE);
  const float rinv = rsqrtf(var + LN_EPS);
  #pragma unroll
  for (int i = 0; i < 7; ++i){
    const int idx = i*256 + threadIdx.x;
    out[(size_t)row*DE + idx] = f2bf((v[i]-mean)*rinv*g[idx] + bb[idx]);
  }
}

// ---- mean over patches
__global__ __launch_bounds__(256) void k_mean(const float* __restrict__ feats,
                                              float* __restrict__ mean_a){
  const int idx = blockIdx.x * 256 + threadIdx.x;
  const int b = idx / DE, d = idx - b * DE;
  const float* p = feats + (size_t)b * NP * DE + d;
  float s = 0.f;
  for (int pp = 0; pp < NP; ++pp) s += p[(size_t)pp * DE];
  mean_a[idx] = s * (1.f/NP);
}

// ---- generic transpose: src fp32 [K][N] -> dst bf16 [N][KPad]
__global__ __launch_bounds__(256) void k_cvt_T(const float* __restrict__ src,
    unsigned short* __restrict__ dst, const int K, const int N, const int KPad){
  __shared__ float t[64][65];
  const int n0 = blockIdx.x*64, k0 = blockIdx.y*64;
  for (int i = threadIdx.x; i < 4096; i += 256){
    const int k = i>>6, n = i&63;
    t[k][n] = (k0 + k < K) ? src[(size_t)(k0+k)*N + n0+n] : 0.f;
  }
  __syncthreads();
  for (int i = threadIdx.x; i < 4096; i += 256){
    const int n = i>>6, k = i&63;
    dst[(size_t)(n0+n)*KPad + k0+k] = f2bf(t[k][n]);
  }
}

// ---- WLt [320 e][2304 k] bf16 <- transpose of [W_Lh; W_Lz]
__global__ __launch_bounds__(256) void k_cvt_wlt(const float* __restrict__ W_Lh,
    const float* __restrict__ W_Lz, unsigned short* __restrict__ WLt){
  __shared__ float t[64][65];
  const int e0 = blockIdx.x*64, k0 = blockIdx.y*64;
  for (int i = threadIdx.x; i < 4096; i += 256){
    const int k = i>>6, e2 = i&63;
    const int kg = k0 + k, e = e0 + e2;
    float v = 0.f;
    if (e < EM) v = (kg < DD) ? W_Lh[(size_t)kg*EM + e] : W_Lz[(size_t)(kg-DD)*EM + e];
    t[k][e2] = v;
  }
  __syncthreads();
  for (int i = threadIdx.x; i < 4096; i += 256){
    const int e2 = i>>6, k = i&63;
    WLt[(size_t)(e0+e2)*KG1 + k0+k] = f2bf(t[k][e2]);
  }
}

// ---- Wg[k][a] = g[k]*Wq[k][a] bf16
__global__ __launch_bounds__(256) void k_wg(const float* __restrict__ Wq,
    const float* __restrict__ g, unsigned short* __restrict__ Wg){
  const int idx = blockIdx.x*256 + threadIdx.x;
  const int k = idx >> 9;
  Wg[idx] = f2bf(g[k]*Wq[idx]);
}

// ---- vq[k] = dot(Wq[k,:], bk)
__global__ __launch_bounds__(512) void k_pre_vq(const float* __restrict__ Wq,
    const float* __restrict__ bk, float* __restrict__ vq){
  const int k = threadIdx.x;
  const float* row = Wq + (size_t)k*DA;
  float acc = 0.f;
  for (int a = 0; a < DA; ++a) acc = fmaf(row[a], bk[a], acc);
  vq[k] = acc;
}

// ---- u[a], voff[a], gw, cscal[4]
__global__ __launch_bounds__(512) void k_uvoff(const float* __restrict__ Wq,
    const float* __restrict__ g, const float* __restrict__ bln,
    const float* __restrict__ bq, const float* __restrict__ Wbeta,
    const float* __restrict__ bbeta, const float* __restrict__ bk,
    float* __restrict__ u_, float* __restrict__ voff,
    float* __restrict__ gw, float* __restrict__ cscal){
  __shared__ float sbuf8[8];
  const int a = threadIdx.x;
  float uu = 0.f, vv = 0.f;
  for (int k = 0; k < DD; ++k){
    const float wv = Wq[(size_t)k*DA + a];
    uu = fmaf(g[k],   wv, uu);
    vv = fmaf(bln[k], wv, vv);
  }
  const float vo = vv + bq[a];
  u_[a]   = uu;
  voff[a] = vo;
  gw[a]   = g[a]*Wbeta[a];
  const float c1 = block_sum512(g[a]*Wbeta[a], sbuf8);
  const float c2 = block_sum512(bln[a]*Wbeta[a], sbuf8);
  const float c3 = block_sum512(uu*bk[a], sbuf8);
  const float c4 = block_sum512(vo*bk[a], sbuf8);
  if (a == 0){ cscal[0]=c1; cscal[1]=c2+bbeta[0]; cscal[2]=c3; cscal[3]=c4; }
}

// ---- KF = feats_bf @ Wk  (bf16 [NB*NP][512]).  grid (144, 8).
__global__ __launch_bounds__(256) void k_KF(const unsigned short* __restrict__ fb,
    const unsigned short* __restrict__ WkT, unsigned short* __restrict__ KF){
  __shared__ char Alds[8192];
  __shared__ char Blds[8192];
  const int mt = blockIdx.x, nt = blockIdx.y;
  const int tid = threadIdx.x, w = tid>>6, lane = tid&63;
  f32x4 acc[4];
  #pragma unroll
  for (int i = 0; i < 4; ++i) acc[i] = (f32x4)(0.f);
  for (int kt = 0; kt < 28; ++kt){
    __syncthreads();
    stage_tile(fb  + (size_t)mt*64*DE, DE, kt*64, Alds);
    stage_tile(WkT + (size_t)nt*64*DE, DE, kt*64, Blds);
    __syncthreads();
    mma64(Alds, Blds, w, lane, acc);
  }
  const int q = nt*64 + w*16 + (lane&15);
  #pragma unroll
  for (int fm = 0; fm < 4; ++fm)
    #pragma unroll
    for (int r = 0; r < 4; ++r){
      const int row = mt*64 + fm*16 + (lane>>4)*4 + r;
      KF[(size_t)row*DD + q] = f2bf(acc[fm][r]);
    }
}

// ---- G2[row][k] = sum_a KF[row][a]*Wg[k][a] + g[k]*vq[k].  grid (144, 8).
__global__ __launch_bounds__(256) void k_QG2(const unsigned short* __restrict__ KF,
    const unsigned short* __restrict__ Wg, const float* __restrict__ g_,
    const float* __restrict__ vq, unsigned short* __restrict__ G2){
  __shared__ char Alds[8192];
  __shared__ char Blds[8192];
  const int mt = blockIdx.x, nt = blockIdx.y;
  const int tid = threadIdx.x, w = tid>>6, lane = tid&63;
  f32x4 acc[4];
  #pragma unroll
  for (int i = 0; i < 4; ++i) acc[i] = (f32x4)(0.f);
  for (int kt = 0; kt < 8; ++kt){
    __syncthreads();
    stage_tile(KF + (size_t)mt*64*DD, DD, kt*64, Alds);
    stage_tile(Wg + (size_t)nt*64*DD, DD, kt*64, Blds);
    __syncthreads();
    mma64(Alds, Blds, w, lane, acc);
  }
  const int q = nt*64 + w*16 + (lane&15);
  const float add = g_[q]*vq[q];
  #pragma unroll
  for (int fm = 0; fm < 4; ++fm)
    #pragma unroll
    for (int r = 0; r < 4; ++r){
      const int row = mt*64 + fm*16 + (lane>>4)*4 + r;
      G2[(size_t)row*DD + q] = f2bf(acc[fm][r] + add);
    }
}

// ---- sc12[row].  grid 144 x 512.
__global__ __launch_bounds__(512) void k_sc12(const unsigned short* __restrict__ KF,
    const float* __restrict__ u_, const float* __restrict__ voff,
    const float* __restrict__ cscal, float2* __restrict__ sc12){
  const int w = threadIdx.x>>6, lane = threadIdx.x&63;
  const int row = blockIdx.x*8 + w;
  const unsigned short* kf = KF + (size_t)row*DD + lane*8;
  float s1 = 0.f, s2 = 0.f;
  #pragma unroll
  for (int j = 0; j < 8; ++j){
    const float kv = bf2f(kf[j]);
    s1 = fmaf(u_[lane*8 + j],   kv, s1);
    s2 = fmaf(voff[lane*8 + j], kv, s2);
  }
  s1 = wave_reduce_sum(s1);
  s2 = wave_reduce_sum(s2);
  if (lane == 0){
    float2 o; o.x = s1 + cscal[2]; o.y = s2 + cscal[3];
    sc12[row] = o;
  }
}

// ---- h0/c0 GEMM (+ optional bf16 mirror)
__global__ __launch_bounds__(256) void k_init_g(const float* __restrict__ mean_a,
    const float* __restrict__ W, const float* __restrict__ bias,
    float* __restrict__ out, unsigned short* __restrict__ outbf){
  __shared__ float la[64*68];
  __shared__ float lb[64*68];
  const int j0 = blockIdx.x*64;
  const int tid = threadIdx.x, tr = tid&15, tn = tid>>4;
  float acc[16] = {0.f};
  for (int a0 = 0; a0 < DE; a0 += 64){
    __syncthreads();
    for (int i = tid; i < 4096; i += 256){
      const int b = i>>6, k = i&63;
      la[k*68 + b] = mean_a[(size_t)b*DE + a0+k];
    }
    for (int i = tid; i < 4096; i += 256){
      const int k = i>>6, j = i&63;
      lb[k*68 + j] = W[(size_t)(a0+k)*DD + j0+j];
    }
    __syncthreads();
    for (int k = 0; k < 64; ++k){
      float av[4], bv[4];
      #pragma unroll
      for (int ii = 0; ii < 4; ++ii) av[ii] = la[k*68 + tr*4+ii];
      #pragma unroll
      for (int jj = 0; jj < 4; ++jj) bv[jj] = lb[k*68 + tn*4+jj];
      #pragma unroll
      for (int ii = 0; ii < 4; ++ii)
        #pragma unroll
        for (int jj = 0; jj < 4; ++jj)
          acc[ii*4+jj] = fmaf(av[ii], bv[jj], acc[ii*4+jj]);
    }
  }
  #pragma unroll
  for (int ii = 0; ii < 4; ++ii)
    #pragma unroll
    for (int jj = 0; jj < 4; ++jj){
      const size_t idx = (size_t)(tr*4+ii)*DD + j0 + tn*4+jj;
      const float val = acc[ii*4+jj] + bias[j0 + tn*4+jj];
      out[idx] = val;
      if (outbf) outbf[idx] = f2bf(val);
    }
}

// ---- precompute eu_all[s][b][2048] = emb(s)@Wu (fp32).  grid (32 jt, 29 s).
__global__ __launch_bounds__(256) void k_EU(const float* __restrict__ emb_table,
    const int* __restrict__ captions, const unsigned short* __restrict__ wut,
    float* __restrict__ eu){
  __shared__ char Alds[8192];
  __shared__ char Blds[8192];
  __shared__ int capL[64];
  const int jt = blockIdx.x, s = blockIdx.y;
  const int tid = threadIdx.x, w = tid>>6, lane = tid&63;
  if (tid < 64) capL[tid] = captions[tid*NTT + s];
  f32x4 acc[4];
  #pragma unroll
  for (int i = 0; i < 4; ++i) acc[i] = (f32x4)(0.f);
  for (int kt = 0; kt < 5; ++kt){
    __syncthreads();
    #pragma unroll
    for (int c = 0; c < 2; ++c){
      const int o = tid + c*256;
      const int m = o>>3, ks8 = o&7;
      const int e0 = kt*64 + ks8*8;
      const float* er = emb_table + (size_t)capL[m]*EM;
      ushort8v v;
      #pragma unroll
      for (int jj = 0; jj < 8; ++jj)
        v[jj] = (e0 + jj < EM) ? f2bf(er[e0 + jj]) : (unsigned short)0;
      *(ushort8v*)&Alds[m*128 + ((ks8 ^ (m&7))<<4)] = v;
    }
    stage_tile(wut + (size_t)jt*64*KP, KP, kt*64, Blds);
    __syncthreads();
    mma64(Alds, Blds, w, lane, acc);
  }
  const int j = jt*64 + w*16 + (lane&15);
  #pragma unroll
  for (int fm = 0; fm < 4; ++fm)
    #pragma unroll
    for (int r = 0; r < 4; ++r){
      const int b = fm*16 + (lane>>4)*4 + r;
      eu[((size_t)s*NB + b)*G4 + j] = acc[fm][r];
    }
}

// ======== persistent decode loop: replaces 29x(k_A,k_B)+final k_A ========
// grid 256 x 512.  blocks 0..63: A-role (batch b).  64..255: B-role GEMM.
// LDS: 48KB weight slice + 24KB A-stage + ~2.4KB A-role arrays = 74.3KB
//      -> capacity 2 blocks/CU (152KB<=160KB) -> grid 256 always co-resident.
// Cross-sync payload via sc1 atomics only; NO fences (see r14 header note).
__global__ __launch_bounds__(512, 4) void k_loop(
    const float* __restrict__ eu, const float* __restrict__ b_gates,
    const float* __restrict__ c0in, unsigned short* __restrict__ hst,
    const unsigned short* __restrict__ G2, const float2* __restrict__ sc12,
    const unsigned short* __restrict__ fb, const float* __restrict__ gw,
    const float* __restrict__ cscal, const unsigned short* __restrict__ whT,
    const unsigned short* __restrict__ wat, float* __restrict__ gp,
    float* __restrict__ alph, unsigned short* __restrict__ zbf,
    unsigned int* __restrict__ syncc){
  __shared__ char sW[49152];            // B-role: 6 weight tiles [kt*2+half]
  __shared__ char sA[24576];            // B-role: 3 A-tiles
  __shared__ alignas(16) unsigned short hL[DD];   // A-role
  __shared__ float sc[NP];
  __shared__ float al[NP];
  __shared__ float sred[32];
  __shared__ float sbufM[8];
  __shared__ float sbufS[8];
  const int tid = threadIdx.x, w = tid>>6, lane = tid&63;
  const int bid = blockIdx.x;
  unsigned int tgt = 0;

  if (bid < NAB){
    // ================= A role: batch b =================
    const int b = bid;
    float creg = c0in[(size_t)b*DD + tid];
    const float bg0 = b_gates[tid],        bg1 = b_gates[DD + tid];
    const float bg2 = b_gates[2*DD + tid], bg3 = b_gates[3*DD + tid];
    const float gwv = gw[tid];
    const float csc0 = cscal[0], csc1 = cscal[1];
    const float* gpb = gp + (size_t)b*G4 + tid;
    for (int s = 0; s <= NS; ++s){
      float hn;
      if (s == 0){
        const unsigned short hb = hst[(size_t)b*DD + tid];   // h0 (pre-kernel)
        hn = bf2f(hb);
        hL[tid] = hb;
      } else {
        const float* eur = eu + ((size_t)(s-1)*NB + b)*G4 + tid;
        float g0 = bg0 + eur[0];
        float g1 = bg1 + eur[DD];
        float g2 = bg2 + eur[2*DD];
        float g3 = bg3 + eur[3*DD];
        // gp addresses are reused every step -> must bypass stale L2 (sc1)
        #pragma unroll
        for (int ks = 0; ks < KSPL; ++ks){
          const float* gr = gpb + (size_t)ks*NB*G4;
          g0 += aload_f(gr);
          g1 += aload_f(gr + DD);
          g2 += aload_f(gr + 2*DD);
          g3 += aload_f(gr + 3*DD);
        }
        creg = sigm(g1)*creg + sigm(g0)*tanhf(g3);
        hn = sigm(g2)*tanhf(creg);
        const unsigned short hb = f2bf(hn);
        astore_u16(&hst[((size_t)s*NB + b)*DD + tid], hb);   // publish (sc1)
        hL[tid] = hb;
        if (s == NS) break;               // h_29 stored; done
      }
      // ---- LN stats + beta
      float p1 = hn, p2 = hn*hn, p3 = hn*gwv;
      #pragma unroll
      for (int o = 32; o >= 1; o >>= 1){
        p1 += __shfl_xor(p1, o);
        p2 += __shfl_xor(p2, o);
        p3 += __shfl_xor(p3, o);
      }
      if (lane == 0){ sred[w*4] = p1; sred[w*4+1] = p2; sred[w*4+2] = p3; }
      __syncthreads();
      float S1 = 0.f, S2 = 0.f, S3 = 0.f;
      #pragma unroll
      for (int i = 0; i < 8; ++i){
        S1 += sred[i*4]; S2 += sred[i*4+1]; S3 += sred[i*4+2];
      }
      const float mean = S1*(1.f/512.f);
      const float var  = S2*(1.f/512.f) - mean*mean;
      const float rinv = rsqrtf(var + LN_EPS);
      const float beta = sigm(rinv*(S3 - mean*csc0) + csc1);
      // ---- scores: wave w owns rows w, w+8, ..., w+136
      const ushort4 h0v = *(const ushort4*)&hL[lane*8];
      const ushort4 h1v = *(const ushort4*)&hL[lane*8 + 4];
      for (int i = 0; i < 18; ++i){
        const int p = w + 8*i;
        const int row = b*NP + p;
        const unsigned short* g2r = G2 + (size_t)row*DD + lane*8;
        const ushort4 u0 = *(const ushort4*)g2r;
        const ushort4 u1 = *(const ushort4*)(g2r + 4);
        float a2 = 0.f;
        a2 = fmaf(bf2f(u0.x), bf2f(h0v.x), a2); a2 = fmaf(bf2f(u0.y), bf2f(h0v.y), a2);
        a2 = fmaf(bf2f(u0.z), bf2f(h0v.z), a2); a2 = fmaf(bf2f(u0.w), bf2f(h0v.w), a2);
        a2 = fmaf(bf2f(u1.x), bf2f(h1v.x), a2); a2 = fmaf(bf2f(u1.y), bf2f(h1v.y), a2);
        a2 = fmaf(bf2f(u1.z), bf2f(h1v.z), a2); a2 = fmaf(bf2f(u1.w), bf2f(h1v.w), a2);
        a2 = wave_reduce_sum(a2);
        if (lane == 0){
          const float2 sv2 = sc12[row];
          sc[p] = RSCALE*(rinv*a2 - rinv*mean*sv2.x + sv2.y);
        }
      }
      __syncthreads();
      // ---- softmax over 144
      const float v = (tid < NP) ? sc[tid] : -1e30f;
      const float mv = wave_reduce_max(v);
      if (lane == 0) sbufM[w] = mv;
      __syncthreads();
      float mm = sbufM[0];
      #pragma unroll
      for (int i = 1; i < 8; ++i) mm = fmaxf(mm, sbufM[i]);
      const float e = (tid < NP) ? __expf(v - mm) : 0.f;
      const float sv = wave_reduce_sum(e);
      if (lane == 0) sbufS[w] = sv;
      __syncthreads();
      float ssum = 0.f;
      #pragma unroll
      for (int i = 0; i < 8; ++i) ssum += sbufS[i];
      if (tid < NP){
        const float a3 = e / ssum;
        al[tid] = a3;
        alph[((size_t)b*NTT + s + 1)*NP + tid] = a3;
      }
      __syncthreads();
      // ---- z = beta * (alpha^T fb[b]), 4 cols/thread, 8B loads
      if (tid < 448){
        const int d0 = tid*4;
        const unsigned short* fB = fb + (size_t)b*NP*DE + d0;
        float a0 = 0.f, a1 = 0.f, a2v = 0.f, a3v = 0.f;
        #pragma unroll 4
        for (int p = 0; p < NP; ++p){
          const ushort4 fv = *(const ushort4*)&fB[(size_t)p*DE];
          const float ap = al[p];
          a0  = fmaf(ap, bf2f(fv.x), a0);
          a1  = fmaf(ap, bf2f(fv.y), a1);
          a2v = fmaf(ap, bf2f(fv.z), a2v);
          a3v = fmaf(ap, bf2f(fv.w), a3v);
        }
        union { ushort4 s4; unsigned long long q; } zz;
        zz.s4.x = f2bf(a0*beta);  zz.s4.y = f2bf(a1*beta);
        zz.s4.z = f2bf(a2v*beta); zz.s4.w = f2bf(a3v*beta);
        astore_u64(&zbf[((size_t)s*NB + b)*DE + d0], zz.q);  // publish (sc1)
      }
      gsync(syncc, tgt += NBLK);   // z_s, h_s published
      gsync(syncc, tgt += NBLK);   // gp (from B) ready for s+1
    }
  } else {
    // ================= B role: gates GEMM =================
    const int bid2 = bid - NAB;
    const int ks  = bid2 >> 4;    // 0..11
    const int nt8 = bid2 & 15;    // 0..15 (128 cols each)
    // startup: resident weight slice [128 cols][192 k] -> LDS, swizzled
    for (int i = tid; i < 6*4096; i += 512){
      const int ti = i >> 12, rem = i & 4095;
      const int n = rem >> 6, kk = rem & 63;
      const int kt = ti >> 1, half = ti & 1;
      const int j = nt8*128 + half*64 + n;
      const int k = ks*KSL + kt*64 + kk;
      const unsigned short wv = (k < DD) ? whT[(size_t)j*DD + k]
                                         : wat[(size_t)j*DE + (k - DD)];
      *(unsigned short*)&sW[ti*8192 + n*128 + (((kk>>3) ^ (n&7))<<4) + (kk&7)*2] = wv;
    }
    const int half = w >> 2, w2 = w & 3;
    for (int s = 0; s < NS; ++s){
      gsync(syncc, tgt += NBLK);   // wait for z_s, h_s
      {
        const int m = tid >> 3, ks8 = tid & 7;
        #pragma unroll
        for (int kt = 0; kt < 3; ++kt){
          const int k0 = ks*KSL + kt*64;       // 64-aligned; single source
          const unsigned short* src = (k0 < DD)
              ? hst + ((size_t)s*NB + m)*DD + k0
              : zbf + ((size_t)s*NB + m)*DE + (k0 - DD);
          // payload reads: sc1 (fresh addresses, but bypass any speculation)
          union { unsigned long long q[2]; ushort8v v; } uu;
          uu.q[0] = aload_u64(src + ks8*8);
          uu.q[1] = aload_u64(src + ks8*8 + 4);
          *(ushort8v*)&sA[kt*8192 + m*128 + ((ks8 ^ (m&7))<<4)] = uu.v;
        }
      }
      __syncthreads();
      f32x4 acc[4];
      #pragma unroll
      for (int i = 0; i < 4; ++i) acc[i] = (f32x4)(0.f);
      #pragma unroll
      for (int kt = 0; kt < 3; ++kt)
        mma64(sA + kt*8192, sW + (kt*2+half)*8192, w2, lane, acc);
      const int j = nt8*128 + half*64 + w2*16 + (lane&15);
      float* gps = gp + (size_t)ks*NB*G4;
      #pragma unroll
      for (int fm = 0; fm < 4; ++fm)
        #pragma unroll
        for (int r = 0; r < 4; ++r){
          const int row = fm*16 + (lane>>4)*4 + r;
          astore_f(&gps[(size_t)row*G4 + j], acc[fm][r]);   // publish (sc1)
        }
      gsync(syncc, tgt += NBLK);   // gp published
    }
  }
}

// ---- post G1: out_o partial MFMA.  grid (5 e-tiles, 29 s, 6 ksplit).
__global__ __launch_bounds__(256) void k_G1m(const unsigned short* __restrict__ hstbf,
    const unsigned short* __restrict__ zbf, const unsigned short* __restrict__ WLt,
    float* __restrict__ g1p){
  __shared__ char Alds[8192];
  __shared__ char Blds[8192];
  const int e0 = blockIdx.x*64, s = blockIdx.y, ks6 = blockIdx.z;
  const int tid = threadIdx.x, w = tid>>6, lane = tid&63;
  const unsigned short* hrow = hstbf + (size_t)(s+1)*NB*DD;
  const unsigned short* zrow = zbf + (size_t)s*NB*DE;
  f32x4 acc[4];
  #pragma unroll
  for (int i = 0; i < 4; ++i) acc[i] = (f32x4)(0.f);
  for (int kt = 0; kt < 6; ++kt){
    const int k0 = ks6*384 + kt*64;
    __syncthreads();
    if (k0 < DD) stage_tile(hrow, DD, k0, Alds);
    else         stage_tile(zrow, DE, k0 - DD, Alds);
    stage_tile(WLt + (size_t)e0*KG1, KG1, k0, Blds);
    __syncthreads();
    mma64(Alds, Blds, w, lane, acc);
  }
  const int e = e0 + w*16 + (lane&15);
  float* dst = g1p + (size_t)ks6*NS*NB*KP;
  #pragma unroll
  for (int fm = 0; fm < 4; ++fm)
    #pragma unroll
    for (int r = 0; r < 4; ++r){
      const int b = fm*16 + (lane>>4)*4 + r;
      dst[((size_t)s*NB + b)*KP + e] = acc[fm][r];
    }
}

// ---- post G1red: sum 6 partials + emb + biases -> outo bf16
__global__ __launch_bounds__(256) void k_G1red(const float* __restrict__ g1p,
    const float* __restrict__ b_Lh, const float* __restrict__ b_Lz,
    const float* __restrict__ emb_table, const int* __restrict__ captions,
    unsigned short* __restrict__ outo){
  const int idx = blockIdx.x*256 + threadIdx.x;
  const int row = idx / KP, e = idx - row*KP;
  const int s = row >> 6, b = row & 63;
  float v = 0.f;
  #pragma unroll
  for (int ks6 = 0; ks6 < 6; ++ks6) v += g1p[(size_t)ks6*NS*NB*KP + idx];
  if (e < EM){
    const int cap = captions[b*NTT + s];
    v += b_Lh[e] + b_Lz[e] + emb_table[(size_t)cap*EM + e];
  } else v = 0.f;
  outo[idx] = f2bf(v);
}

// ---- post G2: logits MFMA, M-tile 128, grid (125, 15), NONTEMPORAL stores.
__global__ __launch_bounds__(256) void k_G2(const unsigned short* __restrict__ Abf,
    const unsigned short* __restrict__ Bt, const float* __restrict__ b_Lo,
    float* __restrict__ pred){
  __shared__ char Alds[128*128];
  __shared__ char Blds[256*128];
  const int nt = blockIdx.x, mt = blockIdx.y;
  const int tid = threadIdx.x, w = tid>>6, lane = tid&63;
  f32x4 acc[8][4];
  #pragma unroll
  for (int i = 0; i < 8; ++i)
    #pragma unroll
    for (int j = 0; j < 4; ++j)
      acc[i][j] = (f32x4)(0.f);
  for (int kt = 0; kt < 5; ++kt){
    const int k0 = kt*64;
    __syncthreads();
    #pragma unroll
    for (int c2 = 0; c2 < 4; ++c2){
      const int o16 = tid + c2*256;
      const int m = o16>>3, ks8 = o16&7;
      const ushort8v v = *(const ushort8v*)&Abf[(size_t)(mt*128+m)*KP + k0 + ks8*8];
      *(ushort8v*)&Alds[m*128 + ((ks8 ^ (m&7))<<4)] = v;
    }
    #pragma unroll
    for (int c2 = 0; c2 < 8; ++c2){
      const int o16 = tid + c2*256;
      const int n = o16>>3, ks8 = o16&7;
      const ushort8v v = *(const ushort8v*)&Bt[(size_t)(nt*256+n)*KP + k0 + ks8*8];
      *(ushort8v*)&Blds[n*128 + ((ks8 ^ (n&7))<<4)] = v;
    }
    __syncthreads();
    #pragma unroll
    for (int ks = 0; ks < 2; ++ks){
      const int slot = ks*4 + (lane>>4);
      short8 af[8];
      #pragma unroll
      for (int fm = 0; fm < 8; ++fm){
        const int m = fm*16 + (lane&15);
        af[fm] = *(const short8*)&Alds[m*128 + ((slot ^ (m&7))<<4)];
      }
      #pragma unroll
      for (int fn = 0; fn < 4; ++fn){
        const int n = w*64 + fn*16 + (lane&15);
        const short8 bfv = *(const short8*)&Blds[n*128 + ((slot ^ (n&7))<<4)];
        #pragma unroll
        for (int fm = 0; fm < 8; ++fm)
          acc[fm][fn] = __builtin_amdgcn_mfma_f32_16x16x32_bf16(af[fm], bfv, acc[fm][fn], 0, 0, 0);
      }
    }
  }
  const int ncol0 = nt*256 + w*64 + (lane&15);
  #pragma unroll
  for (int fm = 0; fm < 8; ++fm){
    #pragma unroll
    for (int r = 0; r < 4; ++r){
      const int row = mt*128 + fm*16 + (lane>>4)*4 + r;
      if (row < NS*NB){
        const int s = row >> 6, b = row & 63;
        float* prow = &pred[((size_t)b*NTT + s + 1)*NV + ncol0];
        #pragma unroll
        for (int fn = 0; fn < 4; ++fn)
          __builtin_nontemporal_store(acc[fm][fn][r] + b_Lo[ncol0 + fn*16],
                                      &prow[fn*16]);
      }
    }
  }
}

extern "C" void kernel_launch(void* const* d_in, const int* in_sizes, int n_in,
                              void* d_out, int out_size, void* d_ws, size_t ws_size,
                              hipStream_t stream){
  const float* features  = (const float*)d_in[0];
  const int*   captions  = (const int*)  d_in[1];
  const float* emb_table = (const float*)d_in[2];
  const float* ln_q_g = (const float*)d_in[3];
  const float* ln_q_b = (const float*)d_in[4];
  const float* ln_kv_g= (const float*)d_in[5];
  const float* ln_kv_b= (const float*)d_in[6];
  const float* Wq     = (const float*)d_in[7];
  const float* bq     = (const float*)d_in[8];
  const float* Wk     = (const float*)d_in[9];
  const float* bk     = (const float*)d_in[10];
  const float* Wbeta  = (const float*)d_in[11];
  const float* bbeta  = (const float*)d_in[12];
  const float* Wh     = (const float*)d_in[13];
  const float* Wu     = (const float*)d_in[14];
  const float* Wa     = (const float*)d_in[15];
  const float* b_gates= (const float*)d_in[16];
  const float* W_Lh   = (const float*)d_in[17];
  const float* b_Lh   = (const float*)d_in[18];
  const float* W_Lz   = (const float*)d_in[19];
  const float* b_Lz   = (const float*)d_in[20];
  const float* W_Lo   = (const float*)d_in[21];
  const float* b_Lo   = (const float*)d_in[22];
  const float* W_ih   = (const float*)d_in[23];
  const float* b_ih   = (const float*)d_in[24];
  const float* W_ic   = (const float*)d_in[25];
  const float* b_ic   = (const float*)d_in[26];

  float* pred = (float*)d_out;
  float* alph = pred + (size_t)NB * NTT * NV;

  char* w = (char*)d_ws;
  auto alloc = [&](size_t bytes) -> void* {
    void* p = (void*)w; w += (bytes + 255) & ~(size_t)255; return p;
  };
  unsigned short* feats_bf = (unsigned short*)alloc((size_t)NB*NP*DE * 2);
  unsigned short* wlo_t    = (unsigned short*)alloc((size_t)NV*KP * 2);
  unsigned short* whT      = (unsigned short*)alloc((size_t)G4*DD * 2);
  unsigned short* wut      = (unsigned short*)alloc((size_t)G4*KP * 2);
  unsigned short* wat      = (unsigned short*)alloc((size_t)G4*DE * 2);
  unsigned short* WkT      = (unsigned short*)alloc((size_t)DD*DE * 2);
  unsigned short* WLt      = (unsigned short*)alloc((size_t)KP*KG1 * 2);
  unsigned short* Wg       = (unsigned short*)alloc((size_t)DD*DD * 2);
  unsigned short* KFbf     = (unsigned short*)alloc((size_t)NB*NP*DD * 2);
  unsigned short* G2bf     = (unsigned short*)alloc((size_t)NB*NP*DD * 2);
  float2* sc12  = (float2*)alloc((size_t)NB*NP * 8);
  float* vq     = (float*)alloc((size_t)DD * 4);
  float* u_     = (float*)alloc((size_t)DD * 4);
  float* voff   = (float*)alloc((size_t)DD * 4);
  float* gw     = (float*)alloc((size_t)DD * 4);
  float* cscal  = (float*)alloc(16);
  float* mean_a = (float*)alloc((size_t)NB*DE * 4);
  float* hbuf   = (float*)alloc((size_t)NB*DD * 4);
  float* cb0    = (float*)alloc((size_t)NB*DD * 4);
  unsigned short* hstbf = (unsigned short*)alloc((size_t)(NS+1)*NB*DD * 2);
  unsigned short* zbf   = (unsigned short*)alloc((size_t)NS*NB*DE * 2);
  unsigned short* outo  = (unsigned short*)alloc((size_t)1920*KP * 2);
  float* gp     = (float*)alloc((size_t)KSPL*NB*G4 * 4);
  float* eu_all = (float*)alloc((size_t)NS*NB*G4 * 4);
  float* g1p    = (float*)alloc((size_t)6*NS*NB*KP * 4);
  unsigned int* syncc = (unsigned int*)alloc(256);

  k_zero<<<dim3((NB*NV)/256), dim3(256), 0, stream>>>(pred, alph, syncc);
  k_ln_feats<<<dim3(NB*NP), dim3(256), 0, stream>>>(features, ln_kv_g, ln_kv_b, feats_bf);
  k_mean<<<dim3((NB*DE)/256), dim3(256), 0, stream>>>(features, mean_a);
  k_cvt_T<<<dim3(NV/64, KP/64), dim3(256), 0, stream>>>(W_Lo, wlo_t, EM, NV, KP);
  k_cvt_T<<<dim3(G4/64, DD/64), dim3(256), 0, stream>>>(Wh, whT, DD, G4, DD);
  k_cvt_T<<<dim3(G4/64, KP/64), dim3(256), 0, stream>>>(Wu, wut, EM, G4, KP);
  k_cvt_T<<<dim3(G4/64, DE/64), dim3(256), 0, stream>>>(Wa, wat, DE, G4, DE);
  k_cvt_T<<<dim3(DD/64, DE/64), dim3(256), 0, stream>>>(Wk, WkT, DE, DD, DE);
  k_cvt_wlt<<<dim3(KP/64, KG1/64), dim3(256), 0, stream>>>(W_Lh, W_Lz, WLt);
  k_wg<<<dim3((DD*DD)/256), dim3(256), 0, stream>>>(Wq, ln_q_g, Wg);
  k_pre_vq<<<dim3(1), dim3(512), 0, stream>>>(Wq, bk, vq);
  k_uvoff<<<dim3(1), dim3(512), 0, stream>>>(Wq, ln_q_g, ln_q_b, bq, Wbeta, bbeta,
      bk, u_, voff, gw, cscal);
  k_KF<<<dim3(NB*NP/64, DD/64), dim3(256), 0, stream>>>(feats_bf, WkT, KFbf);
  k_QG2<<<dim3(NB*NP/64, DD/64), dim3(256), 0, stream>>>(KFbf, Wg, ln_q_g, vq, G2bf);
  k_sc12<<<dim3(NB*NP/8), dim3(512), 0, stream>>>(KFbf, u_, voff, cscal, sc12);
  k_init_g<<<dim3(DD/64), dim3(256), 0, stream>>>(mean_a, W_ih, b_ih, hbuf, hstbf);
  k_init_g<<<dim3(DD/64), dim3(256), 0, stream>>>(mean_a, W_ic, b_ic, cb0, nullptr);
  k_EU<<<dim3(G4/64, NS), dim3(256), 0, stream>>>(emb_table, captions, wut, eu_all);

  // persistent fused decode loop (replaces 29x(k_A,k_B) + final k_A)
  k_loop<<<dim3(NBLK), dim3(512), 0, stream>>>(eu_all, b_gates, cb0, hstbf,
      G2bf, sc12, feats_bf, gw, cscal, whT, wat, gp, alph, zbf, syncc);

  k_G1m<<<dim3(5, NS, 6), dim3(256), 0, stream>>>(hstbf, zbf, WLt, g1p);
  k_G1red<<<dim3((NS*NB*KP)/256), dim3(256), 0, stream>>>(g1p, b_Lh, b_Lz,
      emb_table, captions, outo);
  k_G2<<<dim3(NV/256, 15), dim3(256), 0, stream>>>(outo, wlo_t, b_Lo, pred);
}

// Round 3
// 2785.955 us; speedup vs baseline: 1.0390x; 1.0390x over previous
//
#include <hip/hip_runtime.h>
#include <hip/hip_bf16.h>

// Decoder (LSTM + attention captioner), MI355X. Round 15:
//  - r14 post-mortem: removing fences did NOT cut FETCH (811MB) or dur
//    (2285us). Re-fetch is L2 CAPACITY (fb 33MB/step vs 4MB/XCD), and the
//    real regression vs r12 is A-phase parallelism: 64 blocks working, 192
//    spinning. z-GEMV per block 516KB latency-bound (r12: 129KB x 256 blk).
//  - r15: MERGED roles. All 256 blocks run the A-phase with r12 geometry
//    (b=bid&63, sl=bid>>6; gates/LN/scores redundant x4 - same-b blocks on
//    same XCD share L2 lines; each block owns a 448-col z slice). Blocks
//    0..191 also carry the LDS-resident-weight gates GEMM (12 ks x 16 nt,
//    r14 layout). Same 2 syncs/step, same sc1 payload scheme (passed twice).
//    z-loop unroll 4->16 for memory-level parallelism.

#define NB 64
#define NP 144
#define DE 1792
#define DD 512
#define DA 512
#define EM 300
#define NV 32000
#define NTT 30
#define NS 29
#define G4 2048
#define KP 320
#define KG1 2304
#define LN_EPS 1e-5f
#define RSCALE 0.044194173824159216f   // 1/sqrt(512)

#define NBLK 256      // persistent grid
#define NGB 192       // blocks that also run the GEMM role
#define KSPL 12       // K splits in GEMM role
#define KSL 192       // K per split (12*192 = 2304)

typedef __attribute__((ext_vector_type(8))) short short8;
typedef __attribute__((ext_vector_type(4))) float f32x4;
typedef __attribute__((ext_vector_type(8))) unsigned short ushort8v;

__device__ __forceinline__ float bf2f(unsigned short u){
  union { unsigned int i; float f; } w; w.i = ((unsigned int)u) << 16; return w.f;
}
__device__ __forceinline__ unsigned short f2bf(float f){
  union { float f; unsigned int i; } u; u.f = f;
  unsigned int r = u.i + 0x7FFFu + ((u.i >> 16) & 1u);
  return (unsigned short)(r >> 16);
}
__device__ __forceinline__ float sigm(float x){ return 1.f/(1.f + __expf(-x)); }

// ---- agent-scope coherent (sc1) accessors: bypass L2, no cache invalidation
__device__ __forceinline__ float aload_f(const float* p){
  return __hip_atomic_load((float*)p, __ATOMIC_RELAXED, __HIP_MEMORY_SCOPE_AGENT);
}
__device__ __forceinline__ unsigned long long aload_u64(const void* p){
  return __hip_atomic_load((unsigned long long*)p, __ATOMIC_RELAXED, __HIP_MEMORY_SCOPE_AGENT);
}
__device__ __forceinline__ void astore_u16(unsigned short* p, unsigned short v){
  __hip_atomic_store(p, v, __ATOMIC_RELAXED, __HIP_MEMORY_SCOPE_AGENT);
}
__device__ __forceinline__ void astore_f(float* p, float v){
  __hip_atomic_store(p, v, __ATOMIC_RELAXED, __HIP_MEMORY_SCOPE_AGENT);
}

__device__ __forceinline__ float wave_reduce_sum(float v){
  #pragma unroll
  for (int o = 32; o >= 1; o >>= 1) v += __shfl_xor(v, o);
  return v;
}
__device__ __forceinline__ float wave_reduce_max(float v){
  #pragma unroll
  for (int o = 32; o >= 1; o >>= 1) v = fmaxf(v, __shfl_xor(v, o));
  return v;
}
__device__ __forceinline__ float block_sum256(float v, float* sbuf){
  v = wave_reduce_sum(v);
  const int lane = threadIdx.x & 63, wid = threadIdx.x >> 6;
  if (lane == 0) sbuf[wid] = v;
  __syncthreads();
  const float r = sbuf[0] + sbuf[1] + sbuf[2] + sbuf[3];
  __syncthreads();
  return r;
}
__device__ __forceinline__ float block_sum512(float v, float* sbuf8){
  v = wave_reduce_sum(v);
  const int lane = threadIdx.x & 63, wid = threadIdx.x >> 6;
  if (lane == 0) sbuf8[wid] = v;
  __syncthreads();
  float r = 0.f;
  #pragma unroll
  for (int i = 0; i < 8; ++i) r += sbuf8[i];
  __syncthreads();
  return r;
}

// ---- manual grid barrier: monotonic counter, no cache maintenance (r14).
__device__ __forceinline__ void gsync(unsigned int* cnt, unsigned int target){
  __syncthreads();
  if (threadIdx.x == 0){
    __hip_atomic_fetch_add(cnt, 1u, __ATOMIC_RELAXED, __HIP_MEMORY_SCOPE_AGENT);
    while (__hip_atomic_load(cnt, __ATOMIC_RELAXED, __HIP_MEMORY_SCOPE_AGENT) < target) {}
  }
  __syncthreads();
}

// ---- shared MFMA 64x64-tile helpers (validated r4..r10) ----
__device__ __forceinline__ void stage_tile(const unsigned short* __restrict__ src,
    int row_stride, int k0, char* lds){
  const int tid = threadIdx.x;
  #pragma unroll
  for (int c = 0; c < 2; ++c){
    const int o = tid + c*256;
    const int m = o >> 3, ks8 = o & 7;
    const ushort8v v = *(const ushort8v*)&src[(size_t)m*row_stride + k0 + ks8*8];
    *(ushort8v*)&lds[m*128 + ((ks8 ^ (m&7))<<4)] = v;
  }
}
__device__ __forceinline__ void mma64(const char* Alds, const char* Blds,
    int w, int lane, f32x4 acc[4]){
  #pragma unroll
  for (int ks = 0; ks < 2; ++ks){
    const int slot = ks*4 + (lane>>4);
    const int n = w*16 + (lane&15);
    const short8 bfv = *(const short8*)&Blds[n*128 + ((slot ^ (n&7))<<4)];
    #pragma unroll
    for (int fm = 0; fm < 4; ++fm){
      const int m = fm*16 + (lane&15);
      const short8 afv = *(const short8*)&Alds[m*128 + ((slot ^ (m&7))<<4)];
      acc[fm] = __builtin_amdgcn_mfma_f32_16x16x32_bf16(afv, bfv, acc[fm], 0, 0, 0);
    }
  }
}

// ---- zero t=0 rows of both outputs + the grid-sync counter
__global__ __launch_bounds__(256) void k_zero(float* __restrict__ pred,
                                              float* __restrict__ alph,
                                              unsigned int* __restrict__ syncc){
  const int idx = blockIdx.x * 256 + threadIdx.x;
  if (idx == 0)
    __hip_atomic_store(syncc, 0u, __ATOMIC_RELAXED, __HIP_MEMORY_SCOPE_AGENT);
  {
    const int b = idx / NV, v = idx - b * NV;
    pred[(size_t)b * NTT * NV + v] = 0.f;
  }
  if (idx < NB * NP){
    const int b = idx / NP, p = idx - b * NP;
    alph[(size_t)b * NTT * NP + p] = 0.f;
  }
}

// ---- LayerNorm(features) -> bf16
__global__ __launch_bounds__(256) void k_ln_feats(const float* __restrict__ feats,
    const float* __restrict__ g, const float* __restrict__ bb,
    unsigned short* __restrict__ out){
  __shared__ float sbuf[4];
  const int row = blockIdx.x;
  const float* x = feats + (size_t)row * DE;
  float v[7]; float s = 0.f;
  #pragma unroll
  for (int i = 0; i < 7; ++i){ v[i] = x[i*256 + threadIdx.x]; s += v[i]; }
  const float mean = block_sum256(s, sbuf) * (1.f/DE);
  float q = 0.f;
  #pragma unroll
  for (int i = 0; i < 7; ++i){ const float d = v[i] - mean; q += d*d; }
  const float var = block_sum256(q, sbuf) * (1.f/DE);
  const float rinv = rsqrtf(var + LN_EPS);
  #pragma unroll
  for (int i = 0; i < 7; ++i){
    const int idx = i*256 + threadIdx.x;
    out[(size_t)row*DE + idx] = f2bf((v[i]-mean)*rinv*g[idx] + bb[idx]);
  }
}

// ---- mean over patches
__global__ __launch_bounds__(256) void k_mean(const float* __restrict__ feats,
                                              float* __restrict__ mean_a){
  const int idx = blockIdx.x * 256 + threadIdx.x;
  const int b = idx / DE, d = idx - b * DE;
  const float* p = feats + (size_t)b * NP * DE + d;
  float s = 0.f;
  for (int pp = 0; pp < NP; ++pp) s += p[(size_t)pp * DE];
  mean_a[idx] = s * (1.f/NP);
}

// ---- generic transpose: src fp32 [K][N] -> dst bf16 [N][KPad]
__global__ __launch_bounds__(256) void k_cvt_T(const float* __restrict__ src,
    unsigned short* __restrict__ dst, const int K, const int N, const int KPad){
  __shared__ float t[64][65];
  const int n0 = blockIdx.x*64, k0 = blockIdx.y*64;
  for (int i = threadIdx.x; i < 4096; i += 256){
    const int k = i>>6, n = i&63;
    t[k][n] = (k0 + k < K) ? src[(size_t)(k0+k)*N + n0+n] : 0.f;
  }
  __syncthreads();
  for (int i = threadIdx.x; i < 4096; i += 256){
    const int n = i>>6, k = i&63;
    dst[(size_t)(n0+n)*KPad + k0+k] = f2bf(t[k][n]);
  }
}

// ---- WLt [320 e][2304 k] bf16 <- transpose of [W_Lh; W_Lz]
__global__ __launch_bounds__(256) void k_cvt_wlt(const float* __restrict__ W_Lh,
    const float* __restrict__ W_Lz, unsigned short* __restrict__ WLt){
  __shared__ float t[64][65];
  const int e0 = blockIdx.x*64, k0 = blockIdx.y*64;
  for (int i = threadIdx.x; i < 4096; i += 256){
    const int k = i>>6, e2 = i&63;
    const int kg = k0 + k, e = e0 + e2;
    float v = 0.f;
    if (e < EM) v = (kg < DD) ? W_Lh[(size_t)kg*EM + e] : W_Lz[(size_t)(kg-DD)*EM + e];
    t[k][e2] = v;
  }
  __syncthreads();
  for (int i = threadIdx.x; i < 4096; i += 256){
    const int e2 = i>>6, k = i&63;
    WLt[(size_t)(e0+e2)*KG1 + k0+k] = f2bf(t[k][e2]);
  }
}

// ---- Wg[k][a] = g[k]*Wq[k][a] bf16
__global__ __launch_bounds__(256) void k_wg(const float* __restrict__ Wq,
    const float* __restrict__ g, unsigned short* __restrict__ Wg){
  const int idx = blockIdx.x*256 + threadIdx.x;
  const int k = idx >> 9;
  Wg[idx] = f2bf(g[k]*Wq[idx]);
}

// ---- vq[k] = dot(Wq[k,:], bk)
__global__ __launch_bounds__(512) void k_pre_vq(const float* __restrict__ Wq,
    const float* __restrict__ bk, float* __restrict__ vq){
  const int k = threadIdx.x;
  const float* row = Wq + (size_t)k*DA;
  float acc = 0.f;
  for (int a = 0; a < DA; ++a) acc = fmaf(row[a], bk[a], acc);
  vq[k] = acc;
}

// ---- u[a], voff[a], gw, cscal[4]
__global__ __launch_bounds__(512) void k_uvoff(const float* __restrict__ Wq,
    const float* __restrict__ g, const float* __restrict__ bln,
    const float* __restrict__ bq, const float* __restrict__ Wbeta,
    const float* __restrict__ bbeta, const float* __restrict__ bk,
    float* __restrict__ u_, float* __restrict__ voff,
    float* __restrict__ gw, float* __restrict__ cscal){
  __shared__ float sbuf8[8];
  const int a = threadIdx.x;
  float uu = 0.f, vv = 0.f;
  for (int k = 0; k < DD; ++k){
    const float wv = Wq[(size_t)k*DA + a];
    uu = fmaf(g[k],   wv, uu);
    vv = fmaf(bln[k], wv, vv);
  }
  const float vo = vv + bq[a];
  u_[a]   = uu;
  voff[a] = vo;
  gw[a]   = g[a]*Wbeta[a];
  const float c1 = block_sum512(g[a]*Wbeta[a], sbuf8);
  const float c2 = block_sum512(bln[a]*Wbeta[a], sbuf8);
  const float c3 = block_sum512(uu*bk[a], sbuf8);
  const float c4 = block_sum512(vo*bk[a], sbuf8);
  if (a == 0){ cscal[0]=c1; cscal[1]=c2+bbeta[0]; cscal[2]=c3; cscal[3]=c4; }
}

// ---- KF = feats_bf @ Wk  (bf16 [NB*NP][512]).  grid (144, 8).
__global__ __launch_bounds__(256) void k_KF(const unsigned short* __restrict__ fb,
    const unsigned short* __restrict__ WkT, unsigned short* __restrict__ KF){
  __shared__ char Alds[8192];
  __shared__ char Blds[8192];
  const int mt = blockIdx.x, nt = blockIdx.y;
  const int tid = threadIdx.x, w = tid>>6, lane = tid&63;
  f32x4 acc[4];
  #pragma unroll
  for (int i = 0; i < 4; ++i) acc[i] = (f32x4)(0.f);
  for (int kt = 0; kt < 28; ++kt){
    __syncthreads();
    stage_tile(fb  + (size_t)mt*64*DE, DE, kt*64, Alds);
    stage_tile(WkT + (size_t)nt*64*DE, DE, kt*64, Blds);
    __syncthreads();
    mma64(Alds, Blds, w, lane, acc);
  }
  const int q = nt*64 + w*16 + (lane&15);
  #pragma unroll
  for (int fm = 0; fm < 4; ++fm)
    #pragma unroll
    for (int r = 0; r < 4; ++r){
      const int row = mt*64 + fm*16 + (lane>>4)*4 + r;
      KF[(size_t)row*DD + q] = f2bf(acc[fm][r]);
    }
}

// ---- G2[row][k] = sum_a KF[row][a]*Wg[k][a] + g[k]*vq[k].  grid (144, 8).
__global__ __launch_bounds__(256) void k_QG2(const unsigned short* __restrict__ KF,
    const unsigned short* __restrict__ Wg, const float* __restrict__ g_,
    const float* __restrict__ vq, unsigned short* __restrict__ G2){
  __shared__ char Alds[8192];
  __shared__ char Blds[8192];
  const int mt = blockIdx.x, nt = blockIdx.y;
  const int tid = threadIdx.x, w = tid>>6, lane = tid&63;
  f32x4 acc[4];
  #pragma unroll
  for (int i = 0; i < 4; ++i) acc[i] = (f32x4)(0.f);
  for (int kt = 0; kt < 8; ++kt){
    __syncthreads();
    stage_tile(KF + (size_t)mt*64*DD, DD, kt*64, Alds);
    stage_tile(Wg + (size_t)nt*64*DD, DD, kt*64, Blds);
    __syncthreads();
    mma64(Alds, Blds, w, lane, acc);
  }
  const int q = nt*64 + w*16 + (lane&15);
  const float add = g_[q]*vq[q];
  #pragma unroll
  for (int fm = 0; fm < 4; ++fm)
    #pragma unroll
    for (int r = 0; r < 4; ++r){
      const int row = mt*64 + fm*16 + (lane>>4)*4 + r;
      G2[(size_t)row*DD + q] = f2bf(acc[fm][r] + add);
    }
}

// ---- sc12[row].  grid 144 x 512.
__global__ __launch_bounds__(512) void k_sc12(const unsigned short* __restrict__ KF,
    const float* __restrict__ u_, const float* __restrict__ voff,
    const float* __restrict__ cscal, float2* __restrict__ sc12){
  const int w = threadIdx.x>>6, lane = threadIdx.x&63;
  const int row = blockIdx.x*8 + w;
  const unsigned short* kf = KF + (size_t)row*DD + lane*8;
  float s1 = 0.f, s2 = 0.f;
  #pragma unroll
  for (int j = 0; j < 8; ++j){
    const float kv = bf2f(kf[j]);
    s1 = fmaf(u_[lane*8 + j],   kv, s1);
    s2 = fmaf(voff[lane*8 + j], kv, s2);
  }
  s1 = wave_reduce_sum(s1);
  s2 = wave_reduce_sum(s2);
  if (lane == 0){
    float2 o; o.x = s1 + cscal[2]; o.y = s2 + cscal[3];
    sc12[row] = o;
  }
}

// ---- h0/c0 GEMM (+ optional bf16 mirror)
__global__ __launch_bounds__(256) void k_init_g(const float* __restrict__ mean_a,
    const float* __restrict__ W, const float* __restrict__ bias,
    float* __restrict__ out, unsigned short* __restrict__ outbf){
  __shared__ float la[64*68];
  __shared__ float lb[64*68];
  const int j0 = blockIdx.x*64;
  const int tid = threadIdx.x, tr = tid&15, tn = tid>>4;
  float acc[16] = {0.f};
  for (int a0 = 0; a0 < DE; a0 += 64){
    __syncthreads();
    for (int i = tid; i < 4096; i += 256){
      const int b = i>>6, k = i&63;
      la[k*68 + b] = mean_a[(size_t)b*DE + a0+k];
    }
    for (int i = tid; i < 4096; i += 256){
      const int k = i>>6, j = i&63;
      lb[k*68 + j] = W[(size_t)(a0+k)*DD + j0+j];
    }
    __syncthreads();
    for (int k = 0; k < 64; ++k){
      float av[4], bv[4];
      #pragma unroll
      for (int ii = 0; ii < 4; ++ii) av[ii] = la[k*68 + tr*4+ii];
      #pragma unroll
      for (int jj = 0; jj < 4; ++jj) bv[jj] = lb[k*68 + tn*4+jj];
      #pragma unroll
      for (int ii = 0; ii < 4; ++ii)
        #pragma unroll
        for (int jj = 0; jj < 4; ++jj)
          acc[ii*4+jj] = fmaf(av[ii], bv[jj], acc[ii*4+jj]);
    }
  }
  #pragma unroll
  for (int ii = 0; ii < 4; ++ii)
    #pragma unroll
    for (int jj = 0; jj < 4; ++jj){
      const size_t idx = (size_t)(tr*4+ii)*DD + j0 + tn*4+jj;
      const float val = acc[ii*4+jj] + bias[j0 + tn*4+jj];
      out[idx] = val;
      if (outbf) outbf[idx] = f2bf(val);
    }
}

// ---- precompute eu_all[s][b][2048] = emb(s)@Wu (fp32).  grid (32 jt, 29 s).
__global__ __launch_bounds__(256) void k_EU(const float* __restrict__ emb_table,
    const int* __restrict__ captions, const unsigned short* __restrict__ wut,
    float* __restrict__ eu){
  __shared__ char Alds[8192];
  __shared__ char Blds[8192];
  __shared__ int capL[64];
  const int jt = blockIdx.x, s = blockIdx.y;
  const int tid = threadIdx.x, w = tid>>6, lane = tid&63;
  if (tid < 64) capL[tid] = captions[tid*NTT + s];
  f32x4 acc[4];
  #pragma unroll
  for (int i = 0; i < 4; ++i) acc[i] = (f32x4)(0.f);
  for (int kt = 0; kt < 5; ++kt){
    __syncthreads();
    #pragma unroll
    for (int c = 0; c < 2; ++c){
      const int o = tid + c*256;
      const int m = o>>3, ks8 = o&7;
      const int e0 = kt*64 + ks8*8;
      const float* er = emb_table + (size_t)capL[m]*EM;
      ushort8v v;
      #pragma unroll
      for (int jj = 0; jj < 8; ++jj)
        v[jj] = (e0 + jj < EM) ? f2bf(er[e0 + jj]) : (unsigned short)0;
      *(ushort8v*)&Alds[m*128 + ((ks8 ^ (m&7))<<4)] = v;
    }
    stage_tile(wut + (size_t)jt*64*KP, KP, kt*64, Blds);
    __syncthreads();
    mma64(Alds, Blds, w, lane, acc);
  }
  const int j = jt*64 + w*16 + (lane&15);
  #pragma unroll
  for (int fm = 0; fm < 4; ++fm)
    #pragma unroll
    for (int r = 0; r < 4; ++r){
      const int b = fm*16 + (lane>>4)*4 + r;
      eu[((size_t)s*NB + b)*G4 + j] = acc[fm][r];
    }
}

// ======== persistent decode loop (merged roles, r15) ========
// grid 256 x 512.  A-part: every block, b = bid&63, sl = bid>>6 (the 4
// blocks of one batch land on the same XCD under %8 round-robin -> fb/G2
// L2 sharing).  GEMM-part: blocks 0..191, ks = bid>>4, nt8 = bid&15, 48KB
// weight slice LDS-resident across all steps.  2 grid syncs/step.
// LDS ~76.3KB -> 2 blocks/CU capacity -> grid always co-resident.
__global__ __launch_bounds__(512, 4) void k_loop(
    const float* __restrict__ eu, const float* __restrict__ b_gates,
    const float* __restrict__ c0in, unsigned short* __restrict__ hst,
    const unsigned short* __restrict__ G2, const float2* __restrict__ sc12,
    const unsigned short* __restrict__ fb, const float* __restrict__ gw,
    const float* __restrict__ cscal, const unsigned short* __restrict__ whT,
    const unsigned short* __restrict__ wat, float* __restrict__ gp,
    float* __restrict__ alph, unsigned short* __restrict__ zbf,
    unsigned int* __restrict__ syncc){
  __shared__ char sW[49152];            // GEMM: 6 weight tiles [kt*2+half]
  __shared__ char sA[24576];            // GEMM: 3 A-tiles
  __shared__ alignas(16) unsigned short hL[DD];
  __shared__ float sc[NP];
  __shared__ float al[NP];
  __shared__ float sred[32];
  __shared__ float sbufM[8];
  __shared__ float sbufS[8];
  const int tid = threadIdx.x, w = tid>>6, lane = tid&63;
  const int bid = blockIdx.x;
  const int b = bid & 63, sl = bid >> 6;     // A mapping
  const bool isg = (bid < NGB);
  const int ksG = bid >> 4, nt8 = bid & 15;  // GEMM mapping (valid if isg)
  unsigned int tgt = 0;

  // GEMM blocks: load resident weight slice [128 cols][192 k] once
  if (isg){
    for (int i = tid; i < 6*4096; i += 512){
      const int ti = i >> 12, rem = i & 4095;
      const int n = rem >> 6, kk = rem & 63;
      const int kt = ti >> 1, half = ti & 1;
      const int j = nt8*128 + half*64 + n;
      const int k = ksG*KSL + kt*64 + kk;
      const unsigned short wv = (k < DD) ? whT[(size_t)j*DD + k]
                                         : wat[(size_t)j*DE + (k - DD)];
      *(unsigned short*)&sW[ti*8192 + n*128 + (((kk>>3) ^ (n&7))<<4) + (kk&7)*2] = wv;
    }
  }
  // A constants
  float creg = c0in[(size_t)b*DD + tid];
  const float bg0 = b_gates[tid],        bg1 = b_gates[DD + tid];
  const float bg2 = b_gates[2*DD + tid], bg3 = b_gates[3*DD + tid];
  const float gwv = gw[tid];
  const float csc0 = cscal[0], csc1 = cscal[1];
  const float* gpb = gp + (size_t)b*G4 + tid;
  const int halfG = w >> 2, w2 = w & 3;

  for (int s = 0; s <= NS; ++s){
    float hn;
    if (s == 0){
      const unsigned short hb = hst[(size_t)b*DD + tid];   // h0 (pre-kernel)
      hn = bf2f(hb);
      hL[tid] = hb;
    } else {
      const float* eur = eu + ((size_t)(s-1)*NB + b)*G4 + tid;
      float g0 = bg0 + eur[0];
      float g1 = bg1 + eur[DD];
      float g2 = bg2 + eur[2*DD];
      float g3 = bg3 + eur[3*DD];
      // gp addresses reused every step -> sc1 (bypass stale L2)
      #pragma unroll
      for (int ks = 0; ks < KSPL; ++ks){
        const float* gr = gpb + (size_t)ks*NB*G4;
        g0 += aload_f(gr);
        g1 += aload_f(gr + DD);
        g2 += aload_f(gr + 2*DD);
        g3 += aload_f(gr + 3*DD);
      }
      creg = sigm(g1)*creg + sigm(g0)*tanhf(g3);
      hn = sigm(g2)*tanhf(creg);
      const unsigned short hb = f2bf(hn);
      if (sl == 0) astore_u16(&hst[((size_t)s*NB + b)*DD + tid], hb);
      hL[tid] = hb;
      if (s == NS) break;               // h_29 published; done
    }
    // ---- LN stats + beta
    float p1 = hn, p2 = hn*hn, p3 = hn*gwv;
    #pragma unroll
    for (int o = 32; o >= 1; o >>= 1){
      p1 += __shfl_xor(p1, o);
      p2 += __shfl_xor(p2, o);
      p3 += __shfl_xor(p3, o);
    }
    if (lane == 0){ sred[w*4] = p1; sred[w*4+1] = p2; sred[w*4+2] = p3; }
    __syncthreads();
    float S1 = 0.f, S2 = 0.f, S3 = 0.f;
    #pragma unroll
    for (int i = 0; i < 8; ++i){
      S1 += sred[i*4]; S2 += sred[i*4+1]; S3 += sred[i*4+2];
    }
    const float mean = S1*(1.f/512.f);
    const float var  = S2*(1.f/512.f) - mean*mean;
    const float rinv = rsqrtf(var + LN_EPS);
    const float beta = sigm(rinv*(S3 - mean*csc0) + csc1);
    // ---- scores: wave w owns rows w, w+8, ..., w+136 (x4 sl-redundant)
    const ushort4 h0v = *(const ushort4*)&hL[lane*8];
    const ushort4 h1v = *(const ushort4*)&hL[lane*8 + 4];
    for (int i = 0; i < 18; ++i){
      const int p = w + 8*i;
      const int row = b*NP + p;
      const unsigned short* g2r = G2 + (size_t)row*DD + lane*8;
      const ushort4 u0 = *(const ushort4*)g2r;
      const ushort4 u1 = *(const ushort4*)(g2r + 4);
      float a2 = 0.f;
      a2 = fmaf(bf2f(u0.x), bf2f(h0v.x), a2); a2 = fmaf(bf2f(u0.y), bf2f(h0v.y), a2);
      a2 = fmaf(bf2f(u0.z), bf2f(h0v.z), a2); a2 = fmaf(bf2f(u0.w), bf2f(h0v.w), a2);
      a2 = fmaf(bf2f(u1.x), bf2f(h1v.x), a2); a2 = fmaf(bf2f(u1.y), bf2f(h1v.y), a2);
      a2 = fmaf(bf2f(u1.z), bf2f(h1v.z), a2); a2 = fmaf(bf2f(u1.w), bf2f(h1v.w), a2);
      a2 = wave_reduce_sum(a2);
      if (lane == 0){
        const float2 sv2 = sc12[row];
        sc[p] = RSCALE*(rinv*a2 - rinv*mean*sv2.x + sv2.y);
      }
    }
    __syncthreads();
    // ---- softmax over 144
    const float v = (tid < NP) ? sc[tid] : -1e30f;
    const float mv = wave_reduce_max(v);
    if (lane == 0) sbufM[w] = mv;
    __syncthreads();
    float mm = sbufM[0];
    #pragma unroll
    for (int i = 1; i < 8; ++i) mm = fmaxf(mm, sbufM[i]);
    const float e = (tid < NP) ? __expf(v - mm) : 0.f;
    const float sv = wave_reduce_sum(e);
    if (lane == 0) sbufS[w] = sv;
    __syncthreads();
    float ssum = 0.f;
    #pragma unroll
    for (int i = 0; i < 8; ++i) ssum += sbufS[i];
    if (tid < NP){
      const float a3 = e / ssum;
      al[tid] = a3;
      if (sl == 0) alph[((size_t)b*NTT + s + 1)*NP + tid] = a3;
    }
    __syncthreads();
    // ---- z slice: this block owns cols [sl*448, sl*448+448)
    if (tid < 448){
      const int d = sl*448 + tid;
      const unsigned short* fcol = fb + (size_t)b*NP*DE + d;
      float acc = 0.f;
      #pragma unroll 16
      for (int p = 0; p < NP; ++p)
        acc = fmaf(al[p], bf2f(fcol[(size_t)p*DE]), acc);
      astore_u16(&zbf[((size_t)s*NB + b)*DE + d], f2bf(acc*beta));
    }
    gsync(syncc, tgt += NBLK);   // h_s, z_s published
    // ---- GEMM part (blocks 0..191): gates partial for step s
    if (isg){
      {
        const int m = tid >> 3, ks8 = tid & 7;
        #pragma unroll
        for (int kt = 0; kt < 3; ++kt){
          const int k0 = ksG*KSL + kt*64;      // 64-aligned; single source
          const unsigned short* src = (k0 < DD)
              ? hst + ((size_t)s*NB + m)*DD + k0
              : zbf + ((size_t)s*NB + m)*DE + (k0 - DD);
          union { unsigned long long q[2]; ushort8v v; } uu;
          uu.q[0] = aload_u64(src + ks8*8);
          uu.q[1] = aload_u64(src + ks8*8 + 4);
          *(ushort8v*)&sA[kt*8192 + m*128 + ((ks8 ^ (m&7))<<4)] = uu.v;
        }
      }
      __syncthreads();
      f32x4 acc[4];
      #pragma unroll
      for (int i = 0; i < 4; ++i) acc[i] = (f32x4)(0.f);
      #pragma unroll
      for (int kt = 0; kt < 3; ++kt)
        mma64(sA + kt*8192, sW + (kt*2+halfG)*8192, w2, lane, acc);
      const int j = nt8*128 + halfG*64 + w2*16 + (lane&15);
      float* gps = gp + (size_t)ksG*NB*G4;
      #pragma unroll
      for (int fm = 0; fm < 4; ++fm)
        #pragma unroll
        for (int r = 0; r < 4; ++r){
          const int row = fm*16 + (lane>>4)*4 + r;
          astore_f(&gps[(size_t)row*G4 + j], acc[fm][r]);   // publish (sc1)
        }
    }
    gsync(syncc, tgt += NBLK);   // gp published
  }
}

// ---- post G1: out_o partial MFMA.  grid (5 e-tiles, 29 s, 6 ksplit).
__global__ __launch_bounds__(256) void k_G1m(const unsigned short* __restrict__ hstbf,
    const unsigned short* __restrict__ zbf, const unsigned short* __restrict__ WLt,
    float* __restrict__ g1p){
  __shared__ char Alds[8192];
  __shared__ char Blds[8192];
  const int e0 = blockIdx.x*64, s = blockIdx.y, ks6 = blockIdx.z;
  const int tid = threadIdx.x, w = tid>>6, lane = tid&63;
  const unsigned short* hrow = hstbf + (size_t)(s+1)*NB*DD;
  const unsigned short* zrow = zbf + (size_t)s*NB*DE;
  f32x4 acc[4];
  #pragma unroll
  for (int i = 0; i < 4; ++i) acc[i] = (f32x4)(0.f);
  for (int kt = 0; kt < 6; ++kt){
    const int k0 = ks6*384 + kt*64;
    __syncthreads();
    if (k0 < DD) stage_tile(hrow, DD, k0, Alds);
    else         stage_tile(zrow, DE, k0 - DD, Alds);
    stage_tile(WLt + (size_t)e0*KG1, KG1, k0, Blds);
    __syncthreads();
    mma64(Alds, Blds, w, lane, acc);
  }
  const int e = e0 + w*16 + (lane&15);
  float* dst = g1p + (size_t)ks6*NS*NB*KP;
  #pragma unroll
  for (int fm = 0; fm < 4; ++fm)
    #pragma unroll
    for (int r = 0; r < 4; ++r){
      const int b = fm*16 + (lane>>4)*4 + r;
      dst[((size_t)s*NB + b)*KP + e] = acc[fm][r];
    }
}

// ---- post G1red: sum 6 partials + emb + biases -> outo bf16
__global__ __launch_bounds__(256) void k_G1red(const float* __restrict__ g1p,
    const float* __restrict__ b_Lh, const float* __restrict__ b_Lz,
    const float* __restrict__ emb_table, const int* __restrict__ captions,
    unsigned short* __restrict__ outo){
  const int idx = blockIdx.x*256 + threadIdx.x;
  const int row = idx / KP, e = idx - row*KP;
  const int s = row >> 6, b = row & 63;
  float v = 0.f;
  #pragma unroll
  for (int ks6 = 0; ks6 < 6; ++ks6) v += g1p[(size_t)ks6*NS*NB*KP + idx];
  if (e < EM){
    const int cap = captions[b*NTT + s];
    v += b_Lh[e] + b_Lz[e] + emb_table[(size_t)cap*EM + e];
  } else v = 0.f;
  outo[idx] = f2bf(v);
}

// ---- post G2: logits MFMA, M-tile 128, grid (125, 15), NONTEMPORAL stores.
__global__ __launch_bounds__(256) void k_G2(const unsigned short* __restrict__ Abf,
    const unsigned short* __restrict__ Bt, const float* __restrict__ b_Lo,
    float* __restrict__ pred){
  __shared__ char Alds[128*128];
  __shared__ char Blds[256*128];
  const int nt = blockIdx.x, mt = blockIdx.y;
  const int tid = threadIdx.x, w = tid>>6, lane = tid&63;
  f32x4 acc[8][4];
  #pragma unroll
  for (int i = 0; i < 8; ++i)
    #pragma unroll
    for (int j = 0; j < 4; ++j)
      acc[i][j] = (f32x4)(0.f);
  for (int kt = 0; kt < 5; ++kt){
    const int k0 = kt*64;
    __syncthreads();
    #pragma unroll
    for (int c2 = 0; c2 < 4; ++c2){
      const int o16 = tid + c2*256;
      const int m = o16>>3, ks8 = o16&7;
      const ushort8v v = *(const ushort8v*)&Abf[(size_t)(mt*128+m)*KP + k0 + ks8*8];
      *(ushort8v*)&Alds[m*128 + ((ks8 ^ (m&7))<<4)] = v;
    }
    #pragma unroll
    for (int c2 = 0; c2 < 8; ++c2){
      const int o16 = tid + c2*256;
      const int n = o16>>3, ks8 = o16&7;
      const ushort8v v = *(const ushort8v*)&Bt[(size_t)(nt*256+n)*KP + k0 + ks8*8];
      *(ushort8v*)&Blds[n*128 + ((ks8 ^ (n&7))<<4)] = v;
    }
    __syncthreads();
    #pragma unroll
    for (int ks = 0; ks < 2; ++ks){
      const int slot = ks*4 + (lane>>4);
      short8 af[8];
      #pragma unroll
      for (int fm = 0; fm < 8; ++fm){
        const int m = fm*16 + (lane&15);
        af[fm] = *(const short8*)&Alds[m*128 + ((slot ^ (m&7))<<4)];
      }
      #pragma unroll
      for (int fn = 0; fn < 4; ++fn){
        const int n = w*64 + fn*16 + (lane&15);
        const short8 bfv = *(const short8*)&Blds[n*128 + ((slot ^ (n&7))<<4)];
        #pragma unroll
        for (int fm = 0; fm < 8; ++fm)
          acc[fm][fn] = __builtin_amdgcn_mfma_f32_16x16x32_bf16(af[fm], bfv, acc[fm][fn], 0, 0, 0);
      }
    }
  }
  const int ncol0 = nt*256 + w*64 + (lane&15);
  #pragma unroll
  for (int fm = 0; fm < 8; ++fm){
    #pragma unroll
    for (int r = 0; r < 4; ++r){
      const int row = mt*128 + fm*16 + (lane>>4)*4 + r;
      if (row < NS*NB){
        const int s = row >> 6, b = row & 63;
        float* prow = &pred[((size_t)b*NTT + s + 1)*NV + ncol0];
        #pragma unroll
        for (int fn = 0; fn < 4; ++fn)
          __builtin_nontemporal_store(acc[fm][fn][r] + b_Lo[ncol0 + fn*16],
                                      &prow[fn*16]);
      }
    }
  }
}

extern "C" void kernel_launch(void* const* d_in, const int* in_sizes, int n_in,
                              void* d_out, int out_size, void* d_ws, size_t ws_size,
                              hipStream_t stream){
  const float* features  = (const float*)d_in[0];
  const int*   captions  = (const int*)  d_in[1];
  const float* emb_table = (const float*)d_in[2];
  const float* ln_q_g = (const float*)d_in[3];
  const float* ln_q_b = (const float*)d_in[4];
  const float* ln_kv_g= (const float*)d_in[5];
  const float* ln_kv_b= (const float*)d_in[6];
  const float* Wq     = (const float*)d_in[7];
  const float* bq     = (const float*)d_in[8];
  const float* Wk     = (const float*)d_in[9];
  const float* bk     = (const float*)d_in[10];
  const float* Wbeta  = (const float*)d_in[11];
  const float* bbeta  = (const float*)d_in[12];
  const float* Wh     = (const float*)d_in[13];
  const float* Wu     = (const float*)d_in[14];
  const float* Wa     = (const float*)d_in[15];
  const float* b_gates= (const float*)d_in[16];
  const float* W_Lh   = (const float*)d_in[17];
  const float* b_Lh   = (const float*)d_in[18];
  const float* W_Lz   = (const float*)d_in[19];
  const float* b_Lz   = (const float*)d_in[20];
  const float* W_Lo   = (const float*)d_in[21];
  const float* b_Lo   = (const float*)d_in[22];
  const float* W_ih   = (const float*)d_in[23];
  const float* b_ih   = (const float*)d_in[24];
  const float* W_ic   = (const float*)d_in[25];
  const float* b_ic   = (const float*)d_in[26];

  float* pred = (float*)d_out;
  float* alph = pred + (size_t)NB * NTT * NV;

  char* w = (char*)d_ws;
  auto alloc = [&](size_t bytes) -> void* {
    void* p = (void*)w; w += (bytes + 255) & ~(size_t)255; return p;
  };
  unsigned short* feats_bf = (unsigned short*)alloc((size_t)NB*NP*DE * 2);
  unsigned short* wlo_t    = (unsigned short*)alloc((size_t)NV*KP * 2);
  unsigned short* whT      = (unsigned short*)alloc((size_t)G4*DD * 2);
  unsigned short* wut      = (unsigned short*)alloc((size_t)G4*KP * 2);
  unsigned short* wat      = (unsigned short*)alloc((size_t)G4*DE * 2);
  unsigned short* WkT      = (unsigned short*)alloc((size_t)DD*DE * 2);
  unsigned short* WLt      = (unsigned short*)alloc((size_t)KP*KG1 * 2);
  unsigned short* Wg       = (unsigned short*)alloc((size_t)DD*DD * 2);
  unsigned short* KFbf     = (unsigned short*)alloc((size_t)NB*NP*DD * 2);
  unsigned short* G2bf     = (unsigned short*)alloc((size_t)NB*NP*DD * 2);
  float2* sc12  = (float2*)alloc((size_t)NB*NP * 8);
  float* vq     = (float*)alloc((size_t)DD * 4);
  float* u_     = (float*)alloc((size_t)DD * 4);
  float* voff   = (float*)alloc((size_t)DD * 4);
  float* gw     = (float*)alloc((size_t)DD * 4);
  float* cscal  = (float*)alloc(16);
  float* mean_a = (float*)alloc((size_t)NB*DE * 4);
  float* hbuf   = (float*)alloc((size_t)NB*DD * 4);
  float* cb0    = (float*)alloc((size_t)NB*DD * 4);
  unsigned short* hstbf = (unsigned short*)alloc((size_t)(NS+1)*NB*DD * 2);
  unsigned short* zbf   = (unsigned short*)alloc((size_t)NS*NB*DE * 2);
  unsigned short* outo  = (unsigned short*)alloc((size_t)1920*KP * 2);
  float* gp     = (float*)alloc((size_t)KSPL*NB*G4 * 4);
  float* eu_all = (float*)alloc((size_t)NS*NB*G4 * 4);
  float* g1p    = (float*)alloc((size_t)6*NS*NB*KP * 4);
  unsigned int* syncc = (unsigned int*)alloc(256);

  k_zero<<<dim3((NB*NV)/256), dim3(256), 0, stream>>>(pred, alph, syncc);
  k_ln_feats<<<dim3(NB*NP), dim3(256), 0, stream>>>(features, ln_kv_g, ln_kv_b, feats_bf);
  k_mean<<<dim3((NB*DE)/256), dim3(256), 0, stream>>>(features, mean_a);
  k_cvt_T<<<dim3(NV/64, KP/64), dim3(256), 0, stream>>>(W_Lo, wlo_t, EM, NV, KP);
  k_cvt_T<<<dim3(G4/64, DD/64), dim3(256), 0, stream>>>(Wh, whT, DD, G4, DD);
  k_cvt_T<<<dim3(G4/64, KP/64), dim3(256), 0, stream>>>(Wu, wut, EM, G4, KP);
  k_cvt_T<<<dim3(G4/64, DE/64), dim3(256), 0, stream>>>(Wa, wat, DE, G4, DE);
  k_cvt_T<<<dim3(DD/64, DE/64), dim3(256), 0, stream>>>(Wk, WkT, DE, DD, DE);
  k_cvt_wlt<<<dim3(KP/64, KG1/64), dim3(256), 0, stream>>>(W_Lh, W_Lz, WLt);
  k_wg<<<dim3((DD*DD)/256), dim3(256), 0, stream>>>(Wq, ln_q_g, Wg);
  k_pre_vq<<<dim3(1), dim3(512), 0, stream>>>(Wq, bk, vq);
  k_uvoff<<<dim3(1), dim3(512), 0, stream>>>(Wq, ln_q_g, ln_q_b, bq, Wbeta, bbeta,
      bk, u_, voff, gw, cscal);
  k_KF<<<dim3(NB*NP/64, DD/64), dim3(256), 0, stream>>>(feats_bf, WkT, KFbf);
  k_QG2<<<dim3(NB*NP/64, DD/64), dim3(256), 0, stream>>>(KFbf, Wg, ln_q_g, vq, G2bf);
  k_sc12<<<dim3(NB*NP/8), dim3(512), 0, stream>>>(KFbf, u_, voff, cscal, sc12);
  k_init_g<<<dim3(DD/64), dim3(256), 0, stream>>>(mean_a, W_ih, b_ih, hbuf, hstbf);
  k_init_g<<<dim3(DD/64), dim3(256), 0, stream>>>(mean_a, W_ic, b_ic, cb0, nullptr);
  k_EU<<<dim3(G4/64, NS), dim3(256), 0, stream>>>(emb_table, captions, wut, eu_all);

  // persistent fused decode loop (merged roles)
  k_loop<<<dim3(NBLK), dim3(512), 0, stream>>>(eu_all, b_gates, cb0, hstbf,
      G2bf, sc12, feats_bf, gw, cscal, whT, wat, gp, alph, zbf, syncc);

  k_G1m<<<dim3(5, NS, 6), dim3(256), 0, stream>>>(hstbf, zbf, WLt, g1p);
  k_G1red<<<dim3((NS*NB*KP)/256), dim3(256), 0, stream>>>(g1p, b_Lh, b_Lz,
      emb_table, captions, outo);
  k_G2<<<dim3(NV/256, 15), dim3(256), 0, stream>>>(outo, wlo_t, b_Lo, pred);
}

// Round 4
// 2663.698 us; speedup vs baseline: 1.0867x; 1.0459x over previous
//
#include <hip/hip_runtime.h>
#include <hip/hip_bf16.h>

// Decoder (LSTM + attention captioner), MI355X. Round 16:
//  - r15 post-mortem: 75us/step CONSTANT across r13/r14/r15 despite major
//    changes to fences, payload paths, and z parallelism -> cost lives in
//    what didn't change: (1) single-counter barrier, 256 contenders on one
//    MALL line, ~20us each x58; (2) VGPR=64 (launch_bounds choice) ->
//    scores/z/gather loops run with ~1 load in flight, ~10-15us exposed
//    latency per phase.
//  - r16: (a) hierarchical 2-level barrier: 16 groups x 16 blocks, root
//    counter sees 16 adders, go-flags on separate 128B lines, s_sleep
//    backoff. (b) explicit MLP: scores 3x6-row batches, z 12x12-row
//    batches, gp gather 48-loads-then-sum, all in named reg arrays.

#define NB 64
#define NP 144
#define DE 1792
#define DD 512
#define DA 512
#define EM 300
#define NV 32000
#define NTT 30
#define NS 29
#define G4 2048
#define KP 320
#define KG1 2304
#define LN_EPS 1e-5f
#define RSCALE 0.044194173824159216f   // 1/sqrt(512)

#define NBLK 256      // persistent grid
#define NGB 192       // blocks that also run the GEMM role
#define KSPL 12       // K splits in GEMM role
#define KSL 192       // K per split (12*192 = 2304)
#define NGRP 16       // barrier groups

typedef __attribute__((ext_vector_type(8))) short short8;
typedef __attribute__((ext_vector_type(4))) float f32x4;
typedef __attribute__((ext_vector_type(8))) unsigned short ushort8v;

__device__ __forceinline__ float bf2f(unsigned short u){
  union { unsigned int i; float f; } w; w.i = ((unsigned int)u) << 16; return w.f;
}
__device__ __forceinline__ unsigned short f2bf(float f){
  union { float f; unsigned int i; } u; u.f = f;
  unsigned int r = u.i + 0x7FFFu + ((u.i >> 16) & 1u);
  return (unsigned short)(r >> 16);
}
__device__ __forceinline__ float sigm(float x){ return 1.f/(1.f + __expf(-x)); }

// ---- agent-scope coherent (sc1) accessors: bypass L2, no cache invalidation
__device__ __forceinline__ float aload_f(const float* p){
  return __hip_atomic_load((float*)p, __ATOMIC_RELAXED, __HIP_MEMORY_SCOPE_AGENT);
}
__device__ __forceinline__ unsigned long long aload_u64(const void* p){
  return __hip_atomic_load((unsigned long long*)p, __ATOMIC_RELAXED, __HIP_MEMORY_SCOPE_AGENT);
}
__device__ __forceinline__ void astore_u16(unsigned short* p, unsigned short v){
  __hip_atomic_store(p, v, __ATOMIC_RELAXED, __HIP_MEMORY_SCOPE_AGENT);
}
__device__ __forceinline__ void astore_f(float* p, float v){
  __hip_atomic_store(p, v, __ATOMIC_RELAXED, __HIP_MEMORY_SCOPE_AGENT);
}
__device__ __forceinline__ void astore_u32(unsigned int* p, unsigned int v){
  __hip_atomic_store(p, v, __ATOMIC_RELAXED, __HIP_MEMORY_SCOPE_AGENT);
}

__device__ __forceinline__ float wave_reduce_sum(float v){
  #pragma unroll
  for (int o = 32; o >= 1; o >>= 1) v += __shfl_xor(v, o);
  return v;
}
__device__ __forceinline__ float wave_reduce_max(float v){
  #pragma unroll
  for (int o = 32; o >= 1; o >>= 1) v = fmaxf(v, __shfl_xor(v, o));
  return v;
}
__device__ __forceinline__ float block_sum256(float v, float* sbuf){
  v = wave_reduce_sum(v);
  const int lane = threadIdx.x & 63, wid = threadIdx.x >> 6;
  if (lane == 0) sbuf[wid] = v;
  __syncthreads();
  const float r = sbuf[0] + sbuf[1] + sbuf[2] + sbuf[3];
  __syncthreads();
  return r;
}
__device__ __forceinline__ float block_sum512(float v, float* sbuf8){
  v = wave_reduce_sum(v);
  const int lane = threadIdx.x & 63, wid = threadIdx.x >> 6;
  if (lane == 0) sbuf8[wid] = v;
  __syncthreads();
  float r = 0.f;
  #pragma unroll
  for (int i = 0; i < 8; ++i) r += sbuf8[i];
  __syncthreads();
  return r;
}

// ---- hierarchical grid barrier (r16): 16 groups of 16 blocks.
// layout in sb (u32, 128B lines): [g*32] group counters g=0..15;
// [16*32] root counter; [(17+g)*32] go-flags. Monotonic epochs, no reset.
// Payload ordering: __syncthreads drains vmcnt per wave before the add.
__device__ __forceinline__ void gsync2(unsigned int* sb, unsigned int e, int g){
  __syncthreads();
  if (threadIdx.x == 0){
    unsigned int* gc = sb + g*32;
    unsigned int* rc = sb + 16*32;
    unsigned int* gg = sb + (17 + g)*32;
    const unsigned int old = __hip_atomic_fetch_add(gc, 1u, __ATOMIC_RELAXED,
                                                    __HIP_MEMORY_SCOPE_AGENT);
    if (old == e*16u - 1u){                 // last of group -> promote
      const unsigned int r = __hip_atomic_fetch_add(rc, 1u, __ATOMIC_RELAXED,
                                                    __HIP_MEMORY_SCOPE_AGENT);
      if (r == e*16u - 1u){                 // last group -> broadcast
        #pragma unroll
        for (int i = 0; i < NGRP; ++i)
          astore_u32(sb + (17+i)*32, e);
      }
    }
    while (__hip_atomic_load(gg, __ATOMIC_RELAXED, __HIP_MEMORY_SCOPE_AGENT) < e)
      __builtin_amdgcn_s_sleep(1);
  }
  __syncthreads();
}

// ---- shared MFMA 64x64-tile helpers (validated r4..r10) ----
__device__ __forceinline__ void stage_tile(const unsigned short* __restrict__ src,
    int row_stride, int k0, char* lds){
  const int tid = threadIdx.x;
  #pragma unroll
  for (int c = 0; c < 2; ++c){
    const int o = tid + c*256;
    const int m = o >> 3, ks8 = o & 7;
    const ushort8v v = *(const ushort8v*)&src[(size_t)m*row_stride + k0 + ks8*8];
    *(ushort8v*)&lds[m*128 + ((ks8 ^ (m&7))<<4)] = v;
  }
}
__device__ __forceinline__ void mma64(const char* Alds, const char* Blds,
    int w, int lane, f32x4 acc[4]){
  #pragma unroll
  for (int ks = 0; ks < 2; ++ks){
    const int slot = ks*4 + (lane>>4);
    const int n = w*16 + (lane&15);
    const short8 bfv = *(const short8*)&Blds[n*128 + ((slot ^ (n&7))<<4)];
    #pragma unroll
    for (int fm = 0; fm < 4; ++fm){
      const int m = fm*16 + (lane&15);
      const short8 afv = *(const short8*)&Alds[m*128 + ((slot ^ (m&7))<<4)];
      acc[fm] = __builtin_amdgcn_mfma_f32_16x16x32_bf16(afv, bfv, acc[fm], 0, 0, 0);
    }
  }
}

// ---- zero t=0 rows of both outputs + the grid-sync area (graph replay!)
__global__ __launch_bounds__(256) void k_zero(float* __restrict__ pred,
                                              float* __restrict__ alph,
                                              unsigned int* __restrict__ syncc){
  const int idx = blockIdx.x * 256 + threadIdx.x;
  if (idx < 2048) astore_u32(&syncc[idx], 0u);
  {
    const int b = idx / NV, v = idx - b * NV;
    pred[(size_t)b * NTT * NV + v] = 0.f;
  }
  if (idx < NB * NP){
    const int b = idx / NP, p = idx - b * NP;
    alph[(size_t)b * NTT * NP + p] = 0.f;
  }
}

// ---- LayerNorm(features) -> bf16
__global__ __launch_bounds__(256) void k_ln_feats(const float* __restrict__ feats,
    const float* __restrict__ g, const float* __restrict__ bb,
    unsigned short* __restrict__ out){
  __shared__ float sbuf[4];
  const int row = blockIdx.x;
  const float* x = feats + (size_t)row * DE;
  float v[7]; float s = 0.f;
  #pragma unroll
  for (int i = 0; i < 7; ++i){ v[i] = x[i*256 + threadIdx.x]; s += v[i]; }
  const float mean = block_sum256(s, sbuf) * (1.f/DE);
  float q = 0.f;
  #pragma unroll
  for (int i = 0; i < 7; ++i){ const float d = v[i] - mean; q += d*d; }
  const float var = block_sum256(q, sbuf) * (1.f/DE);
  const float rinv = rsqrtf(var + LN_EPS);
  #pragma unroll
  for (int i = 0; i < 7; ++i){
    const int idx = i*256 + threadIdx.x;
    out[(size_t)row*DE + idx] = f2bf((v[i]-mean)*rinv*g[idx] + bb[idx]);
  }
}

// ---- mean over patches
__global__ __launch_bounds__(256) void k_mean(const float* __restrict__ feats,
                                              float* __restrict__ mean_a){
  const int idx = blockIdx.x * 256 + threadIdx.x;
  const int b = idx / DE, d = idx - b * DE;
  const float* p = feats + (size_t)b * NP * DE + d;
  float s = 0.f;
  for (int pp = 0; pp < NP; ++pp) s += p[(size_t)pp * DE];
  mean_a[idx] = s * (1.f/NP);
}

// ---- generic transpose: src fp32 [K][N] -> dst bf16 [N][KPad]
__global__ __launch_bounds__(256) void k_cvt_T(const float* __restrict__ src,
    unsigned short* __restrict__ dst, const int K, const int N, const int KPad){
  __shared__ float t[64][65];
  const int n0 = blockIdx.x*64, k0 = blockIdx.y*64;
  for (int i = threadIdx.x; i < 4096; i += 256){
    const int k = i>>6, n = i&63;
    t[k][n] = (k0 + k < K) ? src[(size_t)(k0+k)*N + n0+n] : 0.f;
  }
  __syncthreads();
  for (int i = threadIdx.x; i < 4096; i += 256){
    const int n = i>>6, k = i&63;
    dst[(size_t)(n0+n)*KPad + k0+k] = f2bf(t[k][n]);
  }
}

// ---- WLt [320 e][2304 k] bf16 <- transpose of [W_Lh; W_Lz]
__global__ __launch_bounds__(256) void k_cvt_wlt(const float* __restrict__ W_Lh,
    const float* __restrict__ W_Lz, unsigned short* __restrict__ WLt){
  __shared__ float t[64][65];
  const int e0 = blockIdx.x*64, k0 = blockIdx.y*64;
  for (int i = threadIdx.x; i < 4096; i += 256){
    const int k = i>>6, e2 = i&63;
    const int kg = k0 + k, e = e0 + e2;
    float v = 0.f;
    if (e < EM) v = (kg < DD) ? W_Lh[(size_t)kg*EM + e] : W_Lz[(size_t)(kg-DD)*EM + e];
    t[k][e2] = v;
  }
  __syncthreads();
  for (int i = threadIdx.x; i < 4096; i += 256){
    const int e2 = i>>6, k = i&63;
    WLt[(size_t)(e0+e2)*KG1 + k0+k] = f2bf(t[k][e2]);
  }
}

// ---- Wg[k][a] = g[k]*Wq[k][a] bf16
__global__ __launch_bounds__(256) void k_wg(const float* __restrict__ Wq,
    const float* __restrict__ g, unsigned short* __restrict__ Wg){
  const int idx = blockIdx.x*256 + threadIdx.x;
  const int k = idx >> 9;
  Wg[idx] = f2bf(g[k]*Wq[idx]);
}

// ---- vq[k] = dot(Wq[k,:], bk)
__global__ __launch_bounds__(512) void k_pre_vq(const float* __restrict__ Wq,
    const float* __restrict__ bk, float* __restrict__ vq){
  const int k = threadIdx.x;
  const float* row = Wq + (size_t)k*DA;
  float acc = 0.f;
  for (int a = 0; a < DA; ++a) acc = fmaf(row[a], bk[a], acc);
  vq[k] = acc;
}

// ---- u[a], voff[a], gw, cscal[4]
__global__ __launch_bounds__(512) void k_uvoff(const float* __restrict__ Wq,
    const float* __restrict__ g, const float* __restrict__ bln,
    const float* __restrict__ bq, const float* __restrict__ Wbeta,
    const float* __restrict__ bbeta, const float* __restrict__ bk,
    float* __restrict__ u_, float* __restrict__ voff,
    float* __restrict__ gw, float* __restrict__ cscal){
  __shared__ float sbuf8[8];
  const int a = threadIdx.x;
  float uu = 0.f, vv = 0.f;
  for (int k = 0; k < DD; ++k){
    const float wv = Wq[(size_t)k*DA + a];
    uu = fmaf(g[k],   wv, uu);
    vv = fmaf(bln[k], wv, vv);
  }
  const float vo = vv + bq[a];
  u_[a]   = uu;
  voff[a] = vo;
  gw[a]   = g[a]*Wbeta[a];
  const float c1 = block_sum512(g[a]*Wbeta[a], sbuf8);
  const float c2 = block_sum512(bln[a]*Wbeta[a], sbuf8);
  const float c3 = block_sum512(uu*bk[a], sbuf8);
  const float c4 = block_sum512(vo*bk[a], sbuf8);
  if (a == 0){ cscal[0]=c1; cscal[1]=c2+bbeta[0]; cscal[2]=c3; cscal[3]=c4; }
}

// ---- KF = feats_bf @ Wk  (bf16 [NB*NP][512]).  grid (144, 8).
__global__ __launch_bounds__(256) void k_KF(const unsigned short* __restrict__ fb,
    const unsigned short* __restrict__ WkT, unsigned short* __restrict__ KF){
  __shared__ char Alds[8192];
  __shared__ char Blds[8192];
  const int mt = blockIdx.x, nt = blockIdx.y;
  const int tid = threadIdx.x, w = tid>>6, lane = tid&63;
  f32x4 acc[4];
  #pragma unroll
  for (int i = 0; i < 4; ++i) acc[i] = (f32x4)(0.f);
  for (int kt = 0; kt < 28; ++kt){
    __syncthreads();
    stage_tile(fb  + (size_t)mt*64*DE, DE, kt*64, Alds);
    stage_tile(WkT + (size_t)nt*64*DE, DE, kt*64, Blds);
    __syncthreads();
    mma64(Alds, Blds, w, lane, acc);
  }
  const int q = nt*64 + w*16 + (lane&15);
  #pragma unroll
  for (int fm = 0; fm < 4; ++fm)
    #pragma unroll
    for (int r = 0; r < 4; ++r){
      const int row = mt*64 + fm*16 + (lane>>4)*4 + r;
      KF[(size_t)row*DD + q] = f2bf(acc[fm][r]);
    }
}

// ---- G2[row][k] = sum_a KF[row][a]*Wg[k][a] + g[k]*vq[k].  grid (144, 8).
__global__ __launch_bounds__(256) void k_QG2(const unsigned short* __restrict__ KF,
    const unsigned short* __restrict__ Wg, const float* __restrict__ g_,
    const float* __restrict__ vq, unsigned short* __restrict__ G2){
  __shared__ char Alds[8192];
  __shared__ char Blds[8192];
  const int mt = blockIdx.x, nt = blockIdx.y;
  const int tid = threadIdx.x, w = tid>>6, lane = tid&63;
  f32x4 acc[4];
  #pragma unroll
  for (int i = 0; i < 4; ++i) acc[i] = (f32x4)(0.f);
  for (int kt = 0; kt < 8; ++kt){
    __syncthreads();
    stage_tile(KF + (size_t)mt*64*DD, DD, kt*64, Alds);
    stage_tile(Wg + (size_t)nt*64*DD, DD, kt*64, Blds);
    __syncthreads();
    mma64(Alds, Blds, w, lane, acc);
  }
  const int q = nt*64 + w*16 + (lane&15);
  const float add = g_[q]*vq[q];
  #pragma unroll
  for (int fm = 0; fm < 4; ++fm)
    #pragma unroll
    for (int r = 0; r < 4; ++r){
      const int row = mt*64 + fm*16 + (lane>>4)*4 + r;
      G2[(size_t)row*DD + q] = f2bf(acc[fm][r] + add);
    }
}

// ---- sc12[row].  grid 144 x 512.
__global__ __launch_bounds__(512) void k_sc12(const unsigned short* __restrict__ KF,
    const float* __restrict__ u_, const float* __restrict__ voff,
    const float* __restrict__ cscal, float2* __restrict__ sc12){
  const int w = threadIdx.x>>6, lane = threadIdx.x&63;
  const int row = blockIdx.x*8 + w;
  const unsigned short* kf = KF + (size_t)row*DD + lane*8;
  float s1 = 0.f, s2 = 0.f;
  #pragma unroll
  for (int j = 0; j < 8; ++j){
    const float kv = bf2f(kf[j]);
    s1 = fmaf(u_[lane*8 + j],   kv, s1);
    s2 = fmaf(voff[lane*8 + j], kv, s2);
  }
  s1 = wave_reduce_sum(s1);
  s2 = wave_reduce_sum(s2);
  if (lane == 0){
    float2 o; o.x = s1 + cscal[2]; o.y = s2 + cscal[3];
    sc12[row] = o;
  }
}

// ---- h0/c0 GEMM (+ optional bf16 mirror)
__global__ __launch_bounds__(256) void k_init_g(const float* __restrict__ mean_a,
    const float* __restrict__ W, const float* __restrict__ bias,
    float* __restrict__ out, unsigned short* __restrict__ outbf){
  __shared__ float la[64*68];
  __shared__ float lb[64*68];
  const int j0 = blockIdx.x*64;
  const int tid = threadIdx.x, tr = tid&15, tn = tid>>4;
  float acc[16] = {0.f};
  for (int a0 = 0; a0 < DE; a0 += 64){
    __syncthreads();
    for (int i = tid; i < 4096; i += 256){
      const int b = i>>6, k = i&63;
      la[k*68 + b] = mean_a[(size_t)b*DE + a0+k];
    }
    for (int i = tid; i < 4096; i += 256){
      const int k = i>>6, j = i&63;
      lb[k*68 + j] = W[(size_t)(a0+k)*DD + j0+j];
    }
    __syncthreads();
    for (int k = 0; k < 64; ++k){
      float av[4], bv[4];
      #pragma unroll
      for (int ii = 0; ii < 4; ++ii) av[ii] = la[k*68 + tr*4+ii];
      #pragma unroll
      for (int jj = 0; jj < 4; ++jj) bv[jj] = lb[k*68 + tn*4+jj];
      #pragma unroll
      for (int ii = 0; ii < 4; ++ii)
        #pragma unroll
        for (int jj = 0; jj < 4; ++jj)
          acc[ii*4+jj] = fmaf(av[ii], bv[jj], acc[ii*4+jj]);
    }
  }
  #pragma unroll
  for (int ii = 0; ii < 4; ++ii)
    #pragma unroll
    for (int jj = 0; jj < 4; ++jj){
      const size_t idx = (size_t)(tr*4+ii)*DD + j0 + tn*4+jj;
      const float val = acc[ii*4+jj] + bias[j0 + tn*4+jj];
      out[idx] = val;
      if (outbf) outbf[idx] = f2bf(val);
    }
}

// ---- precompute eu_all[s][b][2048] = emb(s)@Wu (fp32).  grid (32 jt, 29 s).
__global__ __launch_bounds__(256) void k_EU(const float* __restrict__ emb_table,
    const int* __restrict__ captions, const unsigned short* __restrict__ wut,
    float* __restrict__ eu){
  __shared__ char Alds[8192];
  __shared__ char Blds[8192];
  __shared__ int capL[64];
  const int jt = blockIdx.x, s = blockIdx.y;
  const int tid = threadIdx.x, w = tid>>6, lane = tid&63;
  if (tid < 64) capL[tid] = captions[tid*NTT + s];
  f32x4 acc[4];
  #pragma unroll
  for (int i = 0; i < 4; ++i) acc[i] = (f32x4)(0.f);
  for (int kt = 0; kt < 5; ++kt){
    __syncthreads();
    #pragma unroll
    for (int c = 0; c < 2; ++c){
      const int o = tid + c*256;
      const int m = o>>3, ks8 = o&7;
      const int e0 = kt*64 + ks8*8;
      const float* er = emb_table + (size_t)capL[m]*EM;
      ushort8v v;
      #pragma unroll
      for (int jj = 0; jj < 8; ++jj)
        v[jj] = (e0 + jj < EM) ? f2bf(er[e0 + jj]) : (unsigned short)0;
      *(ushort8v*)&Alds[m*128 + ((ks8 ^ (m&7))<<4)] = v;
    }
    stage_tile(wut + (size_t)jt*64*KP, KP, kt*64, Blds);
    __syncthreads();
    mma64(Alds, Blds, w, lane, acc);
  }
  const int j = jt*64 + w*16 + (lane&15);
  #pragma unroll
  for (int fm = 0; fm < 4; ++fm)
    #pragma unroll
    for (int r = 0; r < 4; ++r){
      const int b = fm*16 + (lane>>4)*4 + r;
      eu[((size_t)s*NB + b)*G4 + j] = acc[fm][r];
    }
}

// ======== persistent decode loop (r16: hierarchical barrier + MLP) ========
// grid 256 x 512.  A-part: every block, b = bid&63, sl = bid>>6.
// GEMM-part: blocks 0..191, ks = bid>>4, nt8 = bid&15, 48KB weight slice
// LDS-resident.  2 hierarchical grid syncs/step.  LDS ~76.3KB -> capacity
// 2 blocks/CU -> grid always co-resident.
__global__ __launch_bounds__(512, 4) void k_loop(
    const float* __restrict__ eu, const float* __restrict__ b_gates,
    const float* __restrict__ c0in, unsigned short* __restrict__ hst,
    const unsigned short* __restrict__ G2, const float2* __restrict__ sc12,
    const unsigned short* __restrict__ fb, const float* __restrict__ gw,
    const float* __restrict__ cscal, const unsigned short* __restrict__ whT,
    const unsigned short* __restrict__ wat, float* __restrict__ gp,
    float* __restrict__ alph, unsigned short* __restrict__ zbf,
    unsigned int* __restrict__ syncc){
  __shared__ char sW[49152];            // GEMM: 6 weight tiles [kt*2+half]
  __shared__ char sA[24576];            // GEMM: 3 A-tiles
  __shared__ alignas(16) unsigned short hL[DD];
  __shared__ float sc[NP];
  __shared__ float al[NP];
  __shared__ float sred[32];
  __shared__ float sbufM[8];
  __shared__ float sbufS[8];
  const int tid = threadIdx.x, w = tid>>6, lane = tid&63;
  const int bid = blockIdx.x;
  const int b = bid & 63, sl = bid >> 6;     // A mapping
  const bool isg = (bid < NGB);
  const int ksG = bid >> 4, nt8 = bid & 15;  // GEMM mapping (valid if isg)
  const int grp = bid & 15;                  // barrier group
  unsigned int e = 0;

  // GEMM blocks: load resident weight slice [128 cols][192 k] once
  if (isg){
    for (int i = tid; i < 6*4096; i += 512){
      const int ti = i >> 12, rem = i & 4095;
      const int n = rem >> 6, kk = rem & 63;
      const int kt = ti >> 1, half = ti & 1;
      const int j = nt8*128 + half*64 + n;
      const int k = ksG*KSL + kt*64 + kk;
      const unsigned short wv = (k < DD) ? whT[(size_t)j*DD + k]
                                         : wat[(size_t)j*DE + (k - DD)];
      *(unsigned short*)&sW[ti*8192 + n*128 + (((kk>>3) ^ (n&7))<<4) + (kk&7)*2] = wv;
    }
  }
  // A constants
  float creg = c0in[(size_t)b*DD + tid];
  const float bg0 = b_gates[tid],        bg1 = b_gates[DD + tid];
  const float bg2 = b_gates[2*DD + tid], bg3 = b_gates[3*DD + tid];
  const float gwv = gw[tid];
  const float csc0 = cscal[0], csc1 = cscal[1];
  const float* gpb = gp + (size_t)b*G4 + tid;
  const int halfG = w >> 2, w2 = w & 3;

  for (int s = 0; s <= NS; ++s){
    float hn;
    if (s == 0){
      const unsigned short hb = hst[(size_t)b*DD + tid];   // h0 (pre-kernel)
      hn = bf2f(hb);
      hL[tid] = hb;
    } else {
      const float* eur = eu + ((size_t)(s-1)*NB + b)*G4 + tid;
      // explicit MLP: issue all 48 sc1 loads before summing
      float gv[4*KSPL];
      #pragma unroll
      for (int ks = 0; ks < KSPL; ++ks){
        const float* gr = gpb + (size_t)ks*NB*G4;
        gv[ks*4+0] = aload_f(gr);
        gv[ks*4+1] = aload_f(gr + DD);
        gv[ks*4+2] = aload_f(gr + 2*DD);
        gv[ks*4+3] = aload_f(gr + 3*DD);
      }
      float g0 = bg0 + eur[0];
      float g1 = bg1 + eur[DD];
      float g2 = bg2 + eur[2*DD];
      float g3 = bg3 + eur[3*DD];
      #pragma unroll
      for (int ks = 0; ks < KSPL; ++ks){
        g0 += gv[ks*4+0]; g1 += gv[ks*4+1];
        g2 += gv[ks*4+2]; g3 += gv[ks*4+3];
      }
      creg = sigm(g1)*creg + sigm(g0)*tanhf(g3);
      hn = sigm(g2)*tanhf(creg);
      const unsigned short hb = f2bf(hn);
      if (sl == 0) astore_u16(&hst[((size_t)s*NB + b)*DD + tid], hb);
      hL[tid] = hb;
      if (s == NS) break;               // h_29 published; done
    }
    // ---- LN stats + beta
    float p1 = hn, p2 = hn*hn, p3 = hn*gwv;
    #pragma unroll
    for (int o = 32; o >= 1; o >>= 1){
      p1 += __shfl_xor(p1, o);
      p2 += __shfl_xor(p2, o);
      p3 += __shfl_xor(p3, o);
    }
    if (lane == 0){ sred[w*4] = p1; sred[w*4+1] = p2; sred[w*4+2] = p3; }
    __syncthreads();
    float S1 = 0.f, S2 = 0.f, S3 = 0.f;
    #pragma unroll
    for (int i = 0; i < 8; ++i){
      S1 += sred[i*4]; S2 += sred[i*4+1]; S3 += sred[i*4+2];
    }
    const float mean = S1*(1.f/512.f);
    const float var  = S2*(1.f/512.f) - mean*mean;
    const float rinv = rsqrtf(var + LN_EPS);
    const float beta = sigm(rinv*(S3 - mean*csc0) + csc1);
    // ---- scores: wave w owns rows w+8i; batches of 6 for MLP
    const ushort4 h0v = *(const ushort4*)&hL[lane*8];
    const ushort4 h1v = *(const ushort4*)&hL[lane*8 + 4];
    #pragma unroll 1
    for (int i0 = 0; i0 < 18; i0 += 6){
      ushort4 U0[6], U1[6];
      float2 SV[6];
      #pragma unroll
      for (int j = 0; j < 6; ++j){
        const int p = w + 8*(i0+j);
        const unsigned short* g2r = G2 + (size_t)(b*NP + p)*DD + lane*8;
        U0[j] = *(const ushort4*)g2r;
        U1[j] = *(const ushort4*)(g2r + 4);
        if (lane == 0) SV[j] = sc12[b*NP + p];
      }
      #pragma unroll
      for (int j = 0; j < 6; ++j){
        float a2 = 0.f;
        a2 = fmaf(bf2f(U0[j].x), bf2f(h0v.x), a2); a2 = fmaf(bf2f(U0[j].y), bf2f(h0v.y), a2);
        a2 = fmaf(bf2f(U0[j].z), bf2f(h0v.z), a2); a2 = fmaf(bf2f(U0[j].w), bf2f(h0v.w), a2);
        a2 = fmaf(bf2f(U1[j].x), bf2f(h1v.x), a2); a2 = fmaf(bf2f(U1[j].y), bf2f(h1v.y), a2);
        a2 = fmaf(bf2f(U1[j].z), bf2f(h1v.z), a2); a2 = fmaf(bf2f(U1[j].w), bf2f(h1v.w), a2);
        a2 = wave_reduce_sum(a2);
        if (lane == 0)
          sc[w + 8*(i0+j)] = RSCALE*(rinv*a2 - rinv*mean*SV[j].x + SV[j].y);
      }
    }
    __syncthreads();
    // ---- softmax over 144
    const float v = (tid < NP) ? sc[tid] : -1e30f;
    const float mv = wave_reduce_max(v);
    if (lane == 0) sbufM[w] = mv;
    __syncthreads();
    float mm = sbufM[0];
    #pragma unroll
    for (int i = 1; i < 8; ++i) mm = fmaxf(mm, sbufM[i]);
    const float ev = (tid < NP) ? __expf(v - mm) : 0.f;
    const float sv = wave_reduce_sum(ev);
    if (lane == 0) sbufS[w] = sv;
    __syncthreads();
    float ssum = 0.f;
    #pragma unroll
    for (int i = 0; i < 8; ++i) ssum += sbufS[i];
    if (tid < NP){
      const float a3 = ev / ssum;
      al[tid] = a3;
      if (sl == 0) alph[((size_t)b*NTT + s + 1)*NP + tid] = a3;
    }
    __syncthreads();
    // ---- z slice: cols [sl*448, sl*448+448), batches of 12 for MLP
    if (tid < 448){
      const int d = sl*448 + tid;
      const unsigned short* fcol = fb + (size_t)b*NP*DE + d;
      float acc = 0.f;
      #pragma unroll 1
      for (int p0 = 0; p0 < NP; p0 += 12){
        unsigned short fv[12];
        #pragma unroll
        for (int j = 0; j < 12; ++j) fv[j] = fcol[(size_t)(p0+j)*DE];
        #pragma unroll
        for (int j = 0; j < 12; ++j) acc = fmaf(al[p0+j], bf2f(fv[j]), acc);
      }
      astore_u16(&zbf[((size_t)s*NB + b)*DE + d], f2bf(acc*beta));
    }
    gsync2(syncc, ++e, grp);   // h_s, z_s published
    // ---- GEMM part (blocks 0..191): gates partial for step s
    if (isg){
      {
        const int m = tid >> 3, ks8 = tid & 7;
        #pragma unroll
        for (int kt = 0; kt < 3; ++kt){
          const int k0 = ksG*KSL + kt*64;      // 64-aligned; single source
          const unsigned short* src = (k0 < DD)
              ? hst + ((size_t)s*NB + m)*DD + k0
              : zbf + ((size_t)s*NB + m)*DE + (k0 - DD);
          union { unsigned long long q[2]; ushort8v v; } uu;
          uu.q[0] = aload_u64(src + ks8*8);
          uu.q[1] = aload_u64(src + ks8*8 + 4);
          *(ushort8v*)&sA[kt*8192 + m*128 + ((ks8 ^ (m&7))<<4)] = uu.v;
        }
      }
      __syncthreads();
      f32x4 acc[4];
      #pragma unroll
      for (int i = 0; i < 4; ++i) acc[i] = (f32x4)(0.f);
      #pragma unroll
      for (int kt = 0; kt < 3; ++kt)
        mma64(sA + kt*8192, sW + (kt*2+halfG)*8192, w2, lane, acc);
      const int j = nt8*128 + halfG*64 + w2*16 + (lane&15);
      float* gps = gp + (size_t)ksG*NB*G4;
      #pragma unroll
      for (int fm = 0; fm < 4; ++fm)
        #pragma unroll
        for (int r = 0; r < 4; ++r){
          const int row = fm*16 + (lane>>4)*4 + r;
          astore_f(&gps[(size_t)row*G4 + j], acc[fm][r]);   // publish (sc1)
        }
    }
    gsync2(syncc, ++e, grp);   // gp published
  }
}

// ---- post G1: out_o partial MFMA.  grid (5 e-tiles, 29 s, 6 ksplit).
__global__ __launch_bounds__(256) void k_G1m(const unsigned short* __restrict__ hstbf,
    const unsigned short* __restrict__ zbf, const unsigned short* __restrict__ WLt,
    float* __restrict__ g1p){
  __shared__ char Alds[8192];
  __shared__ char Blds[8192];
  const int e0 = blockIdx.x*64, s = blockIdx.y, ks6 = blockIdx.z;
  const int tid = threadIdx.x, w = tid>>6, lane = tid&63;
  const unsigned short* hrow = hstbf + (size_t)(s+1)*NB*DD;
  const unsigned short* zrow = zbf + (size_t)s*NB*DE;
  f32x4 acc[4];
  #pragma unroll
  for (int i = 0; i < 4; ++i) acc[i] = (f32x4)(0.f);
  for (int kt = 0; kt < 6; ++kt){
    const int k0 = ks6*384 + kt*64;
    __syncthreads();
    if (k0 < DD) stage_tile(hrow, DD, k0, Alds);
    else         stage_tile(zrow, DE, k0 - DD, Alds);
    stage_tile(WLt + (size_t)e0*KG1, KG1, k0, Blds);
    __syncthreads();
    mma64(Alds, Blds, w, lane, acc);
  }
  const int e = e0 + w*16 + (lane&15);
  float* dst = g1p + (size_t)ks6*NS*NB*KP;
  #pragma unroll
  for (int fm = 0; fm < 4; ++fm)
    #pragma unroll
    for (int r = 0; r < 4; ++r){
      const int b = fm*16 + (lane>>4)*4 + r;
      dst[((size_t)s*NB + b)*KP + e] = acc[fm][r];
    }
}

// ---- post G1red: sum 6 partials + emb + biases -> outo bf16
__global__ __launch_bounds__(256) void k_G1red(const float* __restrict__ g1p,
    const float* __restrict__ b_Lh, const float* __restrict__ b_Lz,
    const float* __restrict__ emb_table, const int* __restrict__ captions,
    unsigned short* __restrict__ outo){
  const int idx = blockIdx.x*256 + threadIdx.x;
  const int row = idx / KP, e = idx - row*KP;
  const int s = row >> 6, b = row & 63;
  float v = 0.f;
  #pragma unroll
  for (int ks6 = 0; ks6 < 6; ++ks6) v += g1p[(size_t)ks6*NS*NB*KP + idx];
  if (e < EM){
    const int cap = captions[b*NTT + s];
    v += b_Lh[e] + b_Lz[e] + emb_table[(size_t)cap*EM + e];
  } else v = 0.f;
  outo[idx] = f2bf(v);
}

// ---- post G2: logits MFMA, M-tile 128, grid (125, 15), NONTEMPORAL stores.
__global__ __launch_bounds__(256) void k_G2(const unsigned short* __restrict__ Abf,
    const unsigned short* __restrict__ Bt, const float* __restrict__ b_Lo,
    float* __restrict__ pred){
  __shared__ char Alds[128*128];
  __shared__ char Blds[256*128];
  const int nt = blockIdx.x, mt = blockIdx.y;
  const int tid = threadIdx.x, w = tid>>6, lane = tid&63;
  f32x4 acc[8][4];
  #pragma unroll
  for (int i = 0; i < 8; ++i)
    #pragma unroll
    for (int j = 0; j < 4; ++j)
      acc[i][j] = (f32x4)(0.f);
  for (int kt = 0; kt < 5; ++kt){
    const int k0 = kt*64;
    __syncthreads();
    #pragma unroll
    for (int c2 = 0; c2 < 4; ++c2){
      const int o16 = tid + c2*256;
      const int m = o16>>3, ks8 = o16&7;
      const ushort8v v = *(const ushort8v*)&Abf[(size_t)(mt*128+m)*KP + k0 + ks8*8];
      *(ushort8v*)&Alds[m*128 + ((ks8 ^ (m&7))<<4)] = v;
    }
    #pragma unroll
    for (int c2 = 0; c2 < 8; ++c2){
      const int o16 = tid + c2*256;
      const int n = o16>>3, ks8 = o16&7;
      const ushort8v v = *(const ushort8v*)&Bt[(size_t)(nt*256+n)*KP + k0 + ks8*8];
      *(ushort8v*)&Blds[n*128 + ((ks8 ^ (n&7))<<4)] = v;
    }
    __syncthreads();
    #pragma unroll
    for (int ks = 0; ks < 2; ++ks){
      const int slot = ks*4 + (lane>>4);
      short8 af[8];
      #pragma unroll
      for (int fm = 0; fm < 8; ++fm){
        const int m = fm*16 + (lane&15);
        af[fm] = *(const short8*)&Alds[m*128 + ((slot ^ (m&7))<<4)];
      }
      #pragma unroll
      for (int fn = 0; fn < 4; ++fn){
        const int n = w*64 + fn*16 + (lane&15);
        const short8 bfv = *(const short8*)&Blds[n*128 + ((slot ^ (n&7))<<4)];
        #pragma unroll
        for (int fm = 0; fm < 8; ++fm)
          acc[fm][fn] = __builtin_amdgcn_mfma_f32_16x16x32_bf16(af[fm], bfv, acc[fm][fn], 0, 0, 0);
      }
    }
  }
  const int ncol0 = nt*256 + w*64 + (lane&15);
  #pragma unroll
  for (int fm = 0; fm < 8; ++fm){
    #pragma unroll
    for (int r = 0; r < 4; ++r){
      const int row = mt*128 + fm*16 + (lane>>4)*4 + r;
      if (row < NS*NB){
        const int s = row >> 6, b = row & 63;
        float* prow = &pred[((size_t)b*NTT + s + 1)*NV + ncol0];
        #pragma unroll
        for (int fn = 0; fn < 4; ++fn)
          __builtin_nontemporal_store(acc[fm][fn][r] + b_Lo[ncol0 + fn*16],
                                      &prow[fn*16]);
      }
    }
  }
}

extern "C" void kernel_launch(void* const* d_in, const int* in_sizes, int n_in,
                              void* d_out, int out_size, void* d_ws, size_t ws_size,
                              hipStream_t stream){
  const float* features  = (const float*)d_in[0];
  const int*   captions  = (const int*)  d_in[1];
  const float* emb_table = (const float*)d_in[2];
  const float* ln_q_g = (const float*)d_in[3];
  const float* ln_q_b = (const float*)d_in[4];
  const float* ln_kv_g= (const float*)d_in[5];
  const float* ln_kv_b= (const float*)d_in[6];
  const float* Wq     = (const float*)d_in[7];
  const float* bq     = (const float*)d_in[8];
  const float* Wk     = (const float*)d_in[9];
  const float* bk     = (const float*)d_in[10];
  const float* Wbeta  = (const float*)d_in[11];
  const float* bbeta  = (const float*)d_in[12];
  const float* Wh     = (const float*)d_in[13];
  const float* Wu     = (const float*)d_in[14];
  const float* Wa     = (const float*)d_in[15];
  const float* b_gates= (const float*)d_in[16];
  const float* W_Lh   = (const float*)d_in[17];
  const float* b_Lh   = (const float*)d_in[18];
  const float* W_Lz   = (const float*)d_in[19];
  const float* b_Lz   = (const float*)d_in[20];
  const float* W_Lo   = (const float*)d_in[21];
  const float* b_Lo   = (const float*)d_in[22];
  const float* W_ih   = (const float*)d_in[23];
  const float* b_ih   = (const float*)d_in[24];
  const float* W_ic   = (const float*)d_in[25];
  const float* b_ic   = (const float*)d_in[26];

  float* pred = (float*)d_out;
  float* alph = pred + (size_t)NB * NTT * NV;

  char* w = (char*)d_ws;
  auto alloc = [&](size_t bytes) -> void* {
    void* p = (void*)w; w += (bytes + 255) & ~(size_t)255; return p;
  };
  unsigned short* feats_bf = (unsigned short*)alloc((size_t)NB*NP*DE * 2);
  unsigned short* wlo_t    = (unsigned short*)alloc((size_t)NV*KP * 2);
  unsigned short* whT      = (unsigned short*)alloc((size_t)G4*DD * 2);
  unsigned short* wut      = (unsigned short*)alloc((size_t)G4*KP * 2);
  unsigned short* wat      = (unsigned short*)alloc((size_t)G4*DE * 2);
  unsigned short* WkT      = (unsigned short*)alloc((size_t)DD*DE * 2);
  unsigned short* WLt      = (unsigned short*)alloc((size_t)KP*KG1 * 2);
  unsigned short* Wg       = (unsigned short*)alloc((size_t)DD*DD * 2);
  unsigned short* KFbf     = (unsigned short*)alloc((size_t)NB*NP*DD * 2);
  unsigned short* G2bf     = (unsigned short*)alloc((size_t)NB*NP*DD * 2);
  float2* sc12  = (float2*)alloc((size_t)NB*NP * 8);
  float* vq     = (float*)alloc((size_t)DD * 4);
  float* u_     = (float*)alloc((size_t)DD * 4);
  float* voff   = (float*)alloc((size_t)DD * 4);
  float* gw     = (float*)alloc((size_t)DD * 4);
  float* cscal  = (float*)alloc(16);
  float* mean_a = (float*)alloc((size_t)NB*DE * 4);
  float* hbuf   = (float*)alloc((size_t)NB*DD * 4);
  float* cb0    = (float*)alloc((size_t)NB*DD * 4);
  unsigned short* hstbf = (unsigned short*)alloc((size_t)(NS+1)*NB*DD * 2);
  unsigned short* zbf   = (unsigned short*)alloc((size_t)NS*NB*DE * 2);
  unsigned short* outo  = (unsigned short*)alloc((size_t)1920*KP * 2);
  float* gp     = (float*)alloc((size_t)KSPL*NB*G4 * 4);
  float* eu_all = (float*)alloc((size_t)NS*NB*G4 * 4);
  float* g1p    = (float*)alloc((size_t)6*NS*NB*KP * 4);
  unsigned int* syncc = (unsigned int*)alloc(8192);

  k_zero<<<dim3((NB*NV)/256), dim3(256), 0, stream>>>(pred, alph, syncc);
  k_ln_feats<<<dim3(NB*NP), dim3(256), 0, stream>>>(features, ln_kv_g, ln_kv_b, feats_bf);
  k_mean<<<dim3((NB*DE)/256), dim3(256), 0, stream>>>(features, mean_a);
  k_cvt_T<<<dim3(NV/64, KP/64), dim3(256), 0, stream>>>(W_Lo, wlo_t, EM, NV, KP);
  k_cvt_T<<<dim3(G4/64, DD/64), dim3(256), 0, stream>>>(Wh, whT, DD, G4, DD);
  k_cvt_T<<<dim3(G4/64, KP/64), dim3(256), 0, stream>>>(Wu, wut, EM, G4, KP);
  k_cvt_T<<<dim3(G4/64, DE/64), dim3(256), 0, stream>>>(Wa, wat, DE, G4, DE);
  k_cvt_T<<<dim3(DD/64, DE/64), dim3(256), 0, stream>>>(Wk, WkT, DE, DD, DE);
  k_cvt_wlt<<<dim3(KP/64, KG1/64), dim3(256), 0, stream>>>(W_Lh, W_Lz, WLt);
  k_wg<<<dim3((DD*DD)/256), dim3(256), 0, stream>>>(Wq, ln_q_g, Wg);
  k_pre_vq<<<dim3(1), dim3(512), 0, stream>>>(Wq, bk, vq);
  k_uvoff<<<dim3(1), dim3(512), 0, stream>>>(Wq, ln_q_g, ln_q_b, bq, Wbeta, bbeta,
      bk, u_, voff, gw, cscal);
  k_KF<<<dim3(NB*NP/64, DD/64), dim3(256), 0, stream>>>(feats_bf, WkT, KFbf);
  k_QG2<<<dim3(NB*NP/64, DD/64), dim3(256), 0, stream>>>(KFbf, Wg, ln_q_g, vq, G2bf);
  k_sc12<<<dim3(NB*NP/8), dim3(512), 0, stream>>>(KFbf, u_, voff, cscal, sc12);
  k_init_g<<<dim3(DD/64), dim3(256), 0, stream>>>(mean_a, W_ih, b_ih, hbuf, hstbf);
  k_init_g<<<dim3(DD/64), dim3(256), 0, stream>>>(mean_a, W_ic, b_ic, cb0, nullptr);
  k_EU<<<dim3(G4/64, NS), dim3(256), 0, stream>>>(emb_table, captions, wut, eu_all);

  // persistent fused decode loop (merged roles, hierarchical barrier)
  k_loop<<<dim3(NBLK), dim3(512), 0, stream>>>(eu_all, b_gates, cb0, hstbf,
      G2bf, sc12, feats_bf, gw, cscal, whT, wat, gp, alph, zbf, syncc);

  k_G1m<<<dim3(5, NS, 6), dim3(256), 0, stream>>>(hstbf, zbf, WLt, g1p);
  k_G1red<<<dim3((NS*NB*KP)/256), dim3(256), 0, stream>>>(g1p, b_Lh, b_Lz,
      emb_table, captions, outo);
  k_G2<<<dim3(NV/256, 15), dim3(256), 0, stream>>>(outo, wlo_t, b_Lo, pred);
}

// Round 5
// 1517.885 us; speedup vs baseline: 1.9070x; 1.7549x over previous
//
#include <hip/hip_runtime.h>
#include <hip/hip_bf16.h>

// Decoder (LSTM + attention captioner), MI355X. Round 17:
//  - r13..r16 post-mortem: persistent-kernel variants all ~2.06-2.29ms
//    regardless of fences/sc1/roles/barrier design. Root cause: persistent
//    grid = 1 block/CU = 8 waves/CU; every phase latency-serialized, no
//    cross-phase overlap. Launch-based r12 does the same work at 45us/step.
//    REVERTED to r12 (proven 1872.6us).
//  - r17 deltas vs r12 (surgical):
//    (1) k_B grid (32,4)->(32,6): 192 blocks, K-split 384; KSPL=6 in k_A.
//    (2) k_A z-GEMV: explicit 12-wide load batching (MLP).
//    (3) k_A scores: 6-row load batching.

#define NB 64
#define NP 144
#define DE 1792
#define DD 512
#define DA 512
#define EM 300
#define NV 32000
#define NTT 30
#define NS 29
#define G4 2048
#define KP 320
#define KG1 2304
#define LN_EPS 1e-5f
#define RSCALE 0.044194173824159216f   // 1/sqrt(512)
#define KSPL 6        // K splits in k_B (2304 = 6 x 384)

typedef __attribute__((ext_vector_type(8))) short short8;
typedef __attribute__((ext_vector_type(4))) float f32x4;
typedef __attribute__((ext_vector_type(8))) unsigned short ushort8v;

__device__ __forceinline__ float bf2f(unsigned short u){
  union { unsigned int i; float f; } w; w.i = ((unsigned int)u) << 16; return w.f;
}
__device__ __forceinline__ unsigned short f2bf(float f){
  union { float f; unsigned int i; } u; u.f = f;
  unsigned int r = u.i + 0x7FFFu + ((u.i >> 16) & 1u);
  return (unsigned short)(r >> 16);
}
__device__ __forceinline__ float sigm(float x){ return 1.f/(1.f + __expf(-x)); }

__device__ __forceinline__ float wave_reduce_sum(float v){
  #pragma unroll
  for (int o = 32; o >= 1; o >>= 1) v += __shfl_xor(v, o);
  return v;
}
__device__ __forceinline__ float wave_reduce_max(float v){
  #pragma unroll
  for (int o = 32; o >= 1; o >>= 1) v = fmaxf(v, __shfl_xor(v, o));
  return v;
}
__device__ __forceinline__ float block_sum256(float v, float* sbuf){
  v = wave_reduce_sum(v);
  const int lane = threadIdx.x & 63, wid = threadIdx.x >> 6;
  if (lane == 0) sbuf[wid] = v;
  __syncthreads();
  const float r = sbuf[0] + sbuf[1] + sbuf[2] + sbuf[3];
  __syncthreads();
  return r;
}
__device__ __forceinline__ float block_sum512(float v, float* sbuf8){
  v = wave_reduce_sum(v);
  const int lane = threadIdx.x & 63, wid = threadIdx.x >> 6;
  if (lane == 0) sbuf8[wid] = v;
  __syncthreads();
  float r = 0.f;
  #pragma unroll
  for (int i = 0; i < 8; ++i) r += sbuf8[i];
  __syncthreads();
  return r;
}

// ---- shared MFMA 64x64-tile helpers (validated r4..r10) ----
__device__ __forceinline__ void stage_tile(const unsigned short* __restrict__ src,
    int row_stride, int k0, char* lds){
  const int tid = threadIdx.x;
  #pragma unroll
  for (int c = 0; c < 2; ++c){
    const int o = tid + c*256;
    const int m = o >> 3, ks8 = o & 7;
    const ushort8v v = *(const ushort8v*)&src[(size_t)m*row_stride + k0 + ks8*8];
    *(ushort8v*)&lds[m*128 + ((ks8 ^ (m&7))<<4)] = v;
  }
}
__device__ __forceinline__ void mma64(const char* Alds, const char* Blds,
    int w, int lane, f32x4 acc[4]){
  #pragma unroll
  for (int ks = 0; ks < 2; ++ks){
    const int slot = ks*4 + (lane>>4);
    const int n = w*16 + (lane&15);
    const short8 bfv = *(const short8*)&Blds[n*128 + ((slot ^ (n&7))<<4)];
    #pragma unroll
    for (int fm = 0; fm < 4; ++fm){
      const int m = fm*16 + (lane&15);
      const short8 afv = *(const short8*)&Alds[m*128 + ((slot ^ (m&7))<<4)];
      acc[fm] = __builtin_amdgcn_mfma_f32_16x16x32_bf16(afv, bfv, acc[fm], 0, 0, 0);
    }
  }
}

// ---- zero t=0 rows of both outputs
__global__ __launch_bounds__(256) void k_zero(float* __restrict__ pred,
                                              float* __restrict__ alph){
  const int idx = blockIdx.x * 256 + threadIdx.x;
  {
    const int b = idx / NV, v = idx - b * NV;
    pred[(size_t)b * NTT * NV + v] = 0.f;
  }
  if (idx < NB * NP){
    const int b = idx / NP, p = idx - b * NP;
    alph[(size_t)b * NTT * NP + p] = 0.f;
  }
}

// ---- LayerNorm(features) -> bf16
__global__ __launch_bounds__(256) void k_ln_feats(const float* __restrict__ feats,
    const float* __restrict__ g, const float* __restrict__ bb,
    unsigned short* __restrict__ out){
  __shared__ float sbuf[4];
  const int row = blockIdx.x;
  const float* x = feats + (size_t)row * DE;
  float v[7]; float s = 0.f;
  #pragma unroll
  for (int i = 0; i < 7; ++i){ v[i] = x[i*256 + threadIdx.x]; s += v[i]; }
  const float mean = block_sum256(s, sbuf) * (1.f/DE);
  float q = 0.f;
  #pragma unroll
  for (int i = 0; i < 7; ++i){ const float d = v[i] - mean; q += d*d; }
  const float var = block_sum256(q, sbuf) * (1.f/DE);
  const float rinv = rsqrtf(var + LN_EPS);
  #pragma unroll
  for (int i = 0; i < 7; ++i){
    const int idx = i*256 + threadIdx.x;
    out[(size_t)row*DE + idx] = f2bf((v[i]-mean)*rinv*g[idx] + bb[idx]);
  }
}

// ---- mean over patches
__global__ __launch_bounds__(256) void k_mean(const float* __restrict__ feats,
                                              float* __restrict__ mean_a){
  const int idx = blockIdx.x * 256 + threadIdx.x;
  const int b = idx / DE, d = idx - b * DE;
  const float* p = feats + (size_t)b * NP * DE + d;
  float s = 0.f;
  for (int pp = 0; pp < NP; ++pp) s += p[(size_t)pp * DE];
  mean_a[idx] = s * (1.f/NP);
}

// ---- generic transpose: src fp32 [K][N] -> dst bf16 [N][KPad]
__global__ __launch_bounds__(256) void k_cvt_T(const float* __restrict__ src,
    unsigned short* __restrict__ dst, const int K, const int N, const int KPad){
  __shared__ float t[64][65];
  const int n0 = blockIdx.x*64, k0 = blockIdx.y*64;
  for (int i = threadIdx.x; i < 4096; i += 256){
    const int k = i>>6, n = i&63;
    t[k][n] = (k0 + k < K) ? src[(size_t)(k0+k)*N + n0+n] : 0.f;
  }
  __syncthreads();
  for (int i = threadIdx.x; i < 4096; i += 256){
    const int n = i>>6, k = i&63;
    dst[(size_t)(n0+n)*KPad + k0+k] = f2bf(t[k][n]);
  }
}

// ---- WLt [320 e][2304 k] bf16 <- transpose of [W_Lh; W_Lz]
__global__ __launch_bounds__(256) void k_cvt_wlt(const float* __restrict__ W_Lh,
    const float* __restrict__ W_Lz, unsigned short* __restrict__ WLt){
  __shared__ float t[64][65];
  const int e0 = blockIdx.x*64, k0 = blockIdx.y*64;
  for (int i = threadIdx.x; i < 4096; i += 256){
    const int k = i>>6, e2 = i&63;
    const int kg = k0 + k, e = e0 + e2;
    float v = 0.f;
    if (e < EM) v = (kg < DD) ? W_Lh[(size_t)kg*EM + e] : W_Lz[(size_t)(kg-DD)*EM + e];
    t[k][e2] = v;
  }
  __syncthreads();
  for (int i = threadIdx.x; i < 4096; i += 256){
    const int e2 = i>>6, k = i&63;
    WLt[(size_t)(e0+e2)*KG1 + k0+k] = f2bf(t[k][e2]);
  }
}

// ---- Wg[k][a] = g[k]*Wq[k][a] bf16
__global__ __launch_bounds__(256) void k_wg(const float* __restrict__ Wq,
    const float* __restrict__ g, unsigned short* __restrict__ Wg){
  const int idx = blockIdx.x*256 + threadIdx.x;
  const int k = idx >> 9;
  Wg[idx] = f2bf(g[k]*Wq[idx]);
}

// ---- vq[k] = dot(Wq[k,:], bk)
__global__ __launch_bounds__(512) void k_pre_vq(const float* __restrict__ Wq,
    const float* __restrict__ bk, float* __restrict__ vq){
  const int k = threadIdx.x;
  const float* row = Wq + (size_t)k*DA;
  float acc = 0.f;
  for (int a = 0; a < DA; ++a) acc = fmaf(row[a], bk[a], acc);
  vq[k] = acc;
}

// ---- u[a], voff[a], gw, cscal[4]
__global__ __launch_bounds__(512) void k_uvoff(const float* __restrict__ Wq,
    const float* __restrict__ g, const float* __restrict__ bln,
    const float* __restrict__ bq, const float* __restrict__ Wbeta,
    const float* __restrict__ bbeta, const float* __restrict__ bk,
    float* __restrict__ u_, float* __restrict__ voff,
    float* __restrict__ gw, float* __restrict__ cscal){
  __shared__ float sbuf8[8];
  const int a = threadIdx.x;
  float uu = 0.f, vv = 0.f;
  for (int k = 0; k < DD; ++k){
    const float wv = Wq[(size_t)k*DA + a];
    uu = fmaf(g[k],   wv, uu);
    vv = fmaf(bln[k], wv, vv);
  }
  const float vo = vv + bq[a];
  u_[a]   = uu;
  voff[a] = vo;
  gw[a]   = g[a]*Wbeta[a];
  const float c1 = block_sum512(g[a]*Wbeta[a], sbuf8);
  const float c2 = block_sum512(bln[a]*Wbeta[a], sbuf8);
  const float c3 = block_sum512(uu*bk[a], sbuf8);
  const float c4 = block_sum512(vo*bk[a], sbuf8);
  if (a == 0){ cscal[0]=c1; cscal[1]=c2+bbeta[0]; cscal[2]=c3; cscal[3]=c4; }
}

// ---- KF = feats_bf @ Wk  (bf16 [NB*NP][512]).  grid (144, 8).
__global__ __launch_bounds__(256) void k_KF(const unsigned short* __restrict__ fb,
    const unsigned short* __restrict__ WkT, unsigned short* __restrict__ KF){
  __shared__ char Alds[8192];
  __shared__ char Blds[8192];
  const int mt = blockIdx.x, nt = blockIdx.y;
  const int tid = threadIdx.x, w = tid>>6, lane = tid&63;
  f32x4 acc[4];
  #pragma unroll
  for (int i = 0; i < 4; ++i) acc[i] = (f32x4)(0.f);
  for (int kt = 0; kt < 28; ++kt){
    __syncthreads();
    stage_tile(fb  + (size_t)mt*64*DE, DE, kt*64, Alds);
    stage_tile(WkT + (size_t)nt*64*DE, DE, kt*64, Blds);
    __syncthreads();
    mma64(Alds, Blds, w, lane, acc);
  }
  const int q = nt*64 + w*16 + (lane&15);
  #pragma unroll
  for (int fm = 0; fm < 4; ++fm)
    #pragma unroll
    for (int r = 0; r < 4; ++r){
      const int row = mt*64 + fm*16 + (lane>>4)*4 + r;
      KF[(size_t)row*DD + q] = f2bf(acc[fm][r]);
    }
}

// ---- G2[row][k] = sum_a KF[row][a]*Wg[k][a] + g[k]*vq[k].  grid (144, 8).
__global__ __launch_bounds__(256) void k_QG2(const unsigned short* __restrict__ KF,
    const unsigned short* __restrict__ Wg, const float* __restrict__ g_,
    const float* __restrict__ vq, unsigned short* __restrict__ G2){
  __shared__ char Alds[8192];
  __shared__ char Blds[8192];
  const int mt = blockIdx.x, nt = blockIdx.y;
  const int tid = threadIdx.x, w = tid>>6, lane = tid&63;
  f32x4 acc[4];
  #pragma unroll
  for (int i = 0; i < 4; ++i) acc[i] = (f32x4)(0.f);
  for (int kt = 0; kt < 8; ++kt){
    __syncthreads();
    stage_tile(KF + (size_t)mt*64*DD, DD, kt*64, Alds);
    stage_tile(Wg + (size_t)nt*64*DD, DD, kt*64, Blds);
    __syncthreads();
    mma64(Alds, Blds, w, lane, acc);
  }
  const int q = nt*64 + w*16 + (lane&15);
  const float add = g_[q]*vq[q];
  #pragma unroll
  for (int fm = 0; fm < 4; ++fm)
    #pragma unroll
    for (int r = 0; r < 4; ++r){
      const int row = mt*64 + fm*16 + (lane>>4)*4 + r;
      G2[(size_t)row*DD + q] = f2bf(acc[fm][r] + add);
    }
}

// ---- sc12[row].  grid 144 x 512.
__global__ __launch_bounds__(512) void k_sc12(const unsigned short* __restrict__ KF,
    const float* __restrict__ u_, const float* __restrict__ voff,
    const float* __restrict__ cscal, float2* __restrict__ sc12){
  const int w = threadIdx.x>>6, lane = threadIdx.x&63;
  const int row = blockIdx.x*8 + w;
  const unsigned short* kf = KF + (size_t)row*DD + lane*8;
  float s1 = 0.f, s2 = 0.f;
  #pragma unroll
  for (int j = 0; j < 8; ++j){
    const float kv = bf2f(kf[j]);
    s1 = fmaf(u_[lane*8 + j],   kv, s1);
    s2 = fmaf(voff[lane*8 + j], kv, s2);
  }
  s1 = wave_reduce_sum(s1);
  s2 = wave_reduce_sum(s2);
  if (lane == 0){
    float2 o; o.x = s1 + cscal[2]; o.y = s2 + cscal[3];
    sc12[row] = o;
  }
}

// ---- h0/c0 GEMM (+ optional bf16 mirror)
__global__ __launch_bounds__(256) void k_init_g(const float* __restrict__ mean_a,
    const float* __restrict__ W, const float* __restrict__ bias,
    float* __restrict__ out, unsigned short* __restrict__ outbf){
  __shared__ float la[64*68];
  __shared__ float lb[64*68];
  const int j0 = blockIdx.x*64;
  const int tid = threadIdx.x, tr = tid&15, tn = tid>>4;
  float acc[16] = {0.f};
  for (int a0 = 0; a0 < DE; a0 += 64){
    __syncthreads();
    for (int i = tid; i < 4096; i += 256){
      const int b = i>>6, k = i&63;
      la[k*68 + b] = mean_a[(size_t)b*DE + a0+k];
    }
    for (int i = tid; i < 4096; i += 256){
      const int k = i>>6, j = i&63;
      lb[k*68 + j] = W[(size_t)(a0+k)*DD + j0+j];
    }
    __syncthreads();
    for (int k = 0; k < 64; ++k){
      float av[4], bv[4];
      #pragma unroll
      for (int ii = 0; ii < 4; ++ii) av[ii] = la[k*68 + tr*4+ii];
      #pragma unroll
      for (int jj = 0; jj < 4; ++jj) bv[jj] = lb[k*68 + tn*4+jj];
      #pragma unroll
      for (int ii = 0; ii < 4; ++ii)
        #pragma unroll
        for (int jj = 0; jj < 4; ++jj)
          acc[ii*4+jj] = fmaf(av[ii], bv[jj], acc[ii*4+jj]);
    }
  }
  #pragma unroll
  for (int ii = 0; ii < 4; ++ii)
    #pragma unroll
    for (int jj = 0; jj < 4; ++jj){
      const size_t idx = (size_t)(tr*4+ii)*DD + j0 + tn*4+jj;
      const float val = acc[ii*4+jj] + bias[j0 + tn*4+jj];
      out[idx] = val;
      if (outbf) outbf[idx] = f2bf(val);
    }
}

// ---- precompute eu_all[s][b][2048] = emb(s)@Wu (fp32).  grid (32 jt, 29 s).
__global__ __launch_bounds__(256) void k_EU(const float* __restrict__ emb_table,
    const int* __restrict__ captions, const unsigned short* __restrict__ wut,
    float* __restrict__ eu){
  __shared__ char Alds[8192];
  __shared__ char Blds[8192];
  __shared__ int capL[64];
  const int jt = blockIdx.x, s = blockIdx.y;
  const int tid = threadIdx.x, w = tid>>6, lane = tid&63;
  if (tid < 64) capL[tid] = captions[tid*NTT + s];
  f32x4 acc[4];
  #pragma unroll
  for (int i = 0; i < 4; ++i) acc[i] = (f32x4)(0.f);
  for (int kt = 0; kt < 5; ++kt){
    __syncthreads();
    #pragma unroll
    for (int c = 0; c < 2; ++c){
      const int o = tid + c*256;
      const int m = o>>3, ks8 = o&7;
      const int e0 = kt*64 + ks8*8;
      const float* er = emb_table + (size_t)capL[m]*EM;
      ushort8v v;
      #pragma unroll
      for (int jj = 0; jj < 8; ++jj)
        v[jj] = (e0 + jj < EM) ? f2bf(er[e0 + jj]) : (unsigned short)0;
      *(ushort8v*)&Alds[m*128 + ((ks8 ^ (m&7))<<4)] = v;
    }
    stage_tile(wut + (size_t)jt*64*KP, KP, kt*64, Blds);
    __syncthreads();
    mma64(Alds, Blds, w, lane, acc);
  }
  const int j = jt*64 + w*16 + (lane&15);
  #pragma unroll
  for (int fm = 0; fm < 4; ++fm)
    #pragma unroll
    for (int r = 0; r < 4; ++r){
      const int b = fm*16 + (lane>>4)*4 + r;
      eu[((size_t)s*NB + b)*G4 + j] = acc[fm][r];
    }
}

// ======== per-step kernel A (r12 + MLP batching, KSPL=6)
__global__ __launch_bounds__(512) void k_A(
    const float* __restrict__ gp, const float* __restrict__ eu,
    const float* __restrict__ b_gates, const float* __restrict__ cin,
    float* __restrict__ cout, unsigned short* __restrict__ hst,
    const unsigned short* __restrict__ G2, const float2* __restrict__ sc12,
    const unsigned short* __restrict__ fb, const float* __restrict__ gw,
    const float* __restrict__ cscal, const int s, const int do_att,
    float* __restrict__ alph, unsigned short* __restrict__ zbf){
  __shared__ alignas(16) unsigned short hL[DD];
  __shared__ float sc[NP];
  __shared__ float al[NP];
  __shared__ float sredA[8*4];
  __shared__ float sbufM[8];
  __shared__ float sbufS[8];
  const int sl = blockIdx.x, b = blockIdx.y, tid = threadIdx.x;
  const int w = tid>>6, lane = tid&63;
  float hn;
  if (s == 0){
    const unsigned short hb = hst[(size_t)b*DD + tid];
    hn = bf2f(hb);
    hL[tid] = hb;
  } else {
    const int m = s - 1;
    // explicit MLP: issue all KSPL*4 partial loads before summing
    float gv[4*KSPL];
    #pragma unroll
    for (int ks = 0; ks < KSPL; ++ks){
      const float* gr = gp + ((size_t)ks*NB + b)*G4 + tid;
      gv[ks*4+0] = gr[0];
      gv[ks*4+1] = gr[DD];
      gv[ks*4+2] = gr[2*DD];
      gv[ks*4+3] = gr[3*DD];
    }
    const float* eur = eu + ((size_t)m*NB + b)*G4 + tid;
    float gs0 = b_gates[tid]        + eur[0];
    float gs1 = b_gates[DD + tid]   + eur[DD];
    float gs2 = b_gates[2*DD + tid] + eur[2*DD];
    float gs3 = b_gates[3*DD + tid] + eur[3*DD];
    #pragma unroll
    for (int ks = 0; ks < KSPL; ++ks){
      gs0 += gv[ks*4+0]; gs1 += gv[ks*4+1];
      gs2 += gv[ks*4+2]; gs3 += gv[ks*4+3];
    }
    const size_t idx = (size_t)b*DD + tid;
    const float cn = sigm(gs1)*cin[idx] + sigm(gs0)*tanhf(gs3);
    hn = sigm(gs2)*tanhf(cn);
    cout[idx] = cn;
    const unsigned short hb = f2bf(hn);
    hst[(size_t)s*NB*DD + idx] = hb;
    hL[tid] = hb;
  }
  if (!do_att) return;
  float p1 = hn, p2 = hn*hn, p3 = hn*gw[tid];
  #pragma unroll
  for (int o = 32; o >= 1; o >>= 1){
    p1 += __shfl_xor(p1, o);
    p2 += __shfl_xor(p2, o);
    p3 += __shfl_xor(p3, o);
  }
  if (lane == 0){ sredA[w*4] = p1; sredA[w*4+1] = p2; sredA[w*4+2] = p3; }
  __syncthreads();
  float S1 = 0.f, S2 = 0.f, S3 = 0.f;
  #pragma unroll
  for (int i = 0; i < 8; ++i){
    S1 += sredA[i*4]; S2 += sredA[i*4+1]; S3 += sredA[i*4+2];
  }
  const float mean = S1*(1.f/512.f);
  const float var  = S2*(1.f/512.f) - mean*mean;
  const float rinv = rsqrtf(var + LN_EPS);
  const float beta = sigm(rinv*(S3 - mean*cscal[0]) + cscal[1]);
  const ushort4 h0 = *(const ushort4*)&hL[lane*8];
  const ushort4 h1 = *(const ushort4*)&hL[lane*8 + 4];
  // scores in batches of 6 rows (MLP)
  #pragma unroll 1
  for (int i0 = 0; i0 < 18; i0 += 6){
    ushort4 U0[6], U1[6];
    float2 SV[6];
    #pragma unroll
    for (int j = 0; j < 6; ++j){
      const int p = w + 8*(i0+j);
      const unsigned short* g2r = G2 + (size_t)(b*NP + p)*DD + lane*8;
      U0[j] = *(const ushort4*)g2r;
      U1[j] = *(const ushort4*)(g2r + 4);
      if (lane == 0) SV[j] = sc12[b*NP + p];
    }
    #pragma unroll
    for (int j = 0; j < 6; ++j){
      float a2 = 0.f;
      a2 = fmaf(bf2f(U0[j].x), bf2f(h0.x), a2); a2 = fmaf(bf2f(U0[j].y), bf2f(h0.y), a2);
      a2 = fmaf(bf2f(U0[j].z), bf2f(h0.z), a2); a2 = fmaf(bf2f(U0[j].w), bf2f(h0.w), a2);
      a2 = fmaf(bf2f(U1[j].x), bf2f(h1.x), a2); a2 = fmaf(bf2f(U1[j].y), bf2f(h1.y), a2);
      a2 = fmaf(bf2f(U1[j].z), bf2f(h1.z), a2); a2 = fmaf(bf2f(U1[j].w), bf2f(h1.w), a2);
      a2 = wave_reduce_sum(a2);
      if (lane == 0)
        sc[w + 8*(i0+j)] = RSCALE*(rinv*a2 - rinv*mean*SV[j].x + SV[j].y);
    }
  }
  __syncthreads();
  const float v = (tid < NP) ? sc[tid] : -1e30f;
  const float mv = wave_reduce_max(v);
  if (lane == 0) sbufM[w] = mv;
  __syncthreads();
  float mm = sbufM[0];
  #pragma unroll
  for (int i = 1; i < 8; ++i) mm = fmaxf(mm, sbufM[i]);
  const float e = (tid < NP) ? __expf(v - mm) : 0.f;
  const float sv = wave_reduce_sum(e);
  if (lane == 0) sbufS[w] = sv;
  __syncthreads();
  float ssum = 0.f;
  #pragma unroll
  for (int i = 0; i < 8; ++i) ssum += sbufS[i];
  if (tid < NP){
    const float a3 = e / ssum;
    al[tid] = a3;
    if (sl == 0) alph[((size_t)b*NTT + s + 1)*NP + tid] = a3;
  }
  __syncthreads();
  if (tid < 448){
    const int d = sl*448 + tid;
    const unsigned short* fcol = fb + (size_t)b*NP*DE + d;
    float acc = 0.f;
    // z-GEMV in batches of 12 (MLP)
    #pragma unroll 1
    for (int p0 = 0; p0 < NP; p0 += 12){
      unsigned short fv[12];
      #pragma unroll
      for (int j = 0; j < 12; ++j) fv[j] = fcol[(size_t)(p0+j)*DE];
      #pragma unroll
      for (int j = 0; j < 12; ++j) acc = fmaf(al[p0+j], bf2f(fv[j]), acc);
    }
    zbf[((size_t)s*NB + b)*DE + d] = f2bf(acc*beta);
  }
}

// ======== per-step kernel B (r12 + K-split 6).  grid (32, 6).
__global__ __launch_bounds__(256) void k_B(
    const unsigned short* __restrict__ hst, const unsigned short* __restrict__ zbf,
    const unsigned short* __restrict__ whT, const unsigned short* __restrict__ wat,
    const int s, float* __restrict__ gp){
  __shared__ char Alds[8192];
  __shared__ char Blds[8192];
  const int jt = blockIdx.x, ks = blockIdx.y;
  const int tid = threadIdx.x, w = tid>>6, lane = tid&63;
  const unsigned short* hrow = hst + (size_t)s*NB*DD;
  const unsigned short* zrow = zbf + (size_t)s*NB*DE;
  f32x4 acc[4];
  #pragma unroll
  for (int i = 0; i < 4; ++i) acc[i] = (f32x4)(0.f);
  for (int kt = 0; kt < 6; ++kt){
    const int k0 = ks*384 + kt*64;
    __syncthreads();
    if (k0 < DD) stage_tile(hrow, DD, k0, Alds);
    else         stage_tile(zrow, DE, k0 - DD, Alds);
    #pragma unroll
    for (int c2 = 0; c2 < 2; ++c2){
      const int o = tid + c2*256;
      const int m = o>>3, ks8 = o&7;
      const int col = (m>>4)*DD + jt*16 + (m&15);
      const unsigned short* src = (k0 < DD)
          ? whT + (size_t)col*DD + k0
          : wat + (size_t)col*DE + (k0 - DD);
      const ushort8v v = *(const ushort8v*)&src[ks8*8];
      *(ushort8v*)&Blds[m*128 + ((ks8 ^ (m&7))<<4)] = v;
    }
    __syncthreads();
    mma64(Alds, Blds, w, lane, acc);
  }
  const int jcol = jt*16 + (lane&15);
  float* gps = gp + (size_t)ks*NB*G4;
  #pragma unroll
  for (int fm = 0; fm < 4; ++fm)
    #pragma unroll
    for (int r = 0; r < 4; ++r){
      const int b = fm*16 + (lane>>4)*4 + r;
      gps[(size_t)b*G4 + w*DD + jcol] = acc[fm][r];
    }
}

// ---- post G1: out_o partial MFMA.  grid (5 e-tiles, 29 s, 6 ksplit).
__global__ __launch_bounds__(256) void k_G1m(const unsigned short* __restrict__ hstbf,
    const unsigned short* __restrict__ zbf, const unsigned short* __restrict__ WLt,
    float* __restrict__ g1p){
  __shared__ char Alds[8192];
  __shared__ char Blds[8192];
  const int e0 = blockIdx.x*64, s = blockIdx.y, ks6 = blockIdx.z;
  const int tid = threadIdx.x, w = tid>>6, lane = tid&63;
  const unsigned short* hrow = hstbf + (size_t)(s+1)*NB*DD;
  const unsigned short* zrow = zbf + (size_t)s*NB*DE;
  f32x4 acc[4];
  #pragma unroll
  for (int i = 0; i < 4; ++i) acc[i] = (f32x4)(0.f);
  for (int kt = 0; kt < 6; ++kt){
    const int k0 = ks6*384 + kt*64;
    __syncthreads();
    if (k0 < DD) stage_tile(hrow, DD, k0, Alds);
    else         stage_tile(zrow, DE, k0 - DD, Alds);
    stage_tile(WLt + (size_t)e0*KG1, KG1, k0, Blds);
    __syncthreads();
    mma64(Alds, Blds, w, lane, acc);
  }
  const int e = e0 + w*16 + (lane&15);
  float* dst = g1p + (size_t)ks6*NS*NB*KP;
  #pragma unroll
  for (int fm = 0; fm < 4; ++fm)
    #pragma unroll
    for (int r = 0; r < 4; ++r){
      const int b = fm*16 + (lane>>4)*4 + r;
      dst[((size_t)s*NB + b)*KP + e] = acc[fm][r];
    }
}

// ---- post G1red: sum 6 partials + emb + biases -> outo bf16
__global__ __launch_bounds__(256) void k_G1red(const float* __restrict__ g1p,
    const float* __restrict__ b_Lh, const float* __restrict__ b_Lz,
    const float* __restrict__ emb_table, const int* __restrict__ captions,
    unsigned short* __restrict__ outo){
  const int idx = blockIdx.x*256 + threadIdx.x;
  const int row = idx / KP, e = idx - row*KP;
  const int s = row >> 6, b = row & 63;
  float v = 0.f;
  #pragma unroll
  for (int ks6 = 0; ks6 < 6; ++ks6) v += g1p[(size_t)ks6*NS*NB*KP + idx];
  if (e < EM){
    const int cap = captions[b*NTT + s];
    v += b_Lh[e] + b_Lz[e] + emb_table[(size_t)cap*EM + e];
  } else v = 0.f;
  outo[idx] = f2bf(v);
}

// ---- post G2: logits MFMA, M-tile 128, grid (125, 15), NONTEMPORAL stores.
__global__ __launch_bounds__(256) void k_G2(const unsigned short* __restrict__ Abf,
    const unsigned short* __restrict__ Bt, const float* __restrict__ b_Lo,
    float* __restrict__ pred){
  __shared__ char Alds[128*128];
  __shared__ char Blds[256*128];
  const int nt = blockIdx.x, mt = blockIdx.y;
  const int tid = threadIdx.x, w = tid>>6, lane = tid&63;
  f32x4 acc[8][4];
  #pragma unroll
  for (int i = 0; i < 8; ++i)
    #pragma unroll
    for (int j = 0; j < 4; ++j)
      acc[i][j] = (f32x4)(0.f);
  for (int kt = 0; kt < 5; ++kt){
    const int k0 = kt*64;
    __syncthreads();
    #pragma unroll
    for (int c2 = 0; c2 < 4; ++c2){
      const int o16 = tid + c2*256;
      const int m = o16>>3, ks8 = o16&7;
      const ushort8v v = *(const ushort8v*)&Abf[(size_t)(mt*128+m)*KP + k0 + ks8*8];
      *(ushort8v*)&Alds[m*128 + ((ks8 ^ (m&7))<<4)] = v;
    }
    #pragma unroll
    for (int c2 = 0; c2 < 8; ++c2){
      const int o16 = tid + c2*256;
      const int n = o16>>3, ks8 = o16&7;
      const ushort8v v = *(const ushort8v*)&Bt[(size_t)(nt*256+n)*KP + k0 + ks8*8];
      *(ushort8v*)&Blds[n*128 + ((ks8 ^ (n&7))<<4)] = v;
    }
    __syncthreads();
    #pragma unroll
    for (int ks = 0; ks < 2; ++ks){
      const int slot = ks*4 + (lane>>4);
      short8 af[8];
      #pragma unroll
      for (int fm = 0; fm < 8; ++fm){
        const int m = fm*16 + (lane&15);
        af[fm] = *(const short8*)&Alds[m*128 + ((slot ^ (m&7))<<4)];
      }
      #pragma unroll
      for (int fn = 0; fn < 4; ++fn){
        const int n = w*64 + fn*16 + (lane&15);
        const short8 bfv = *(const short8*)&Blds[n*128 + ((slot ^ (n&7))<<4)];
        #pragma unroll
        for (int fm = 0; fm < 8; ++fm)
          acc[fm][fn] = __builtin_amdgcn_mfma_f32_16x16x32_bf16(af[fm], bfv, acc[fm][fn], 0, 0, 0);
      }
    }
  }
  const int ncol0 = nt*256 + w*64 + (lane&15);
  #pragma unroll
  for (int fm = 0; fm < 8; ++fm){
    #pragma unroll
    for (int r = 0; r < 4; ++r){
      const int row = mt*128 + fm*16 + (lane>>4)*4 + r;
      if (row < NS*NB){
        const int s = row >> 6, b = row & 63;
        float* prow = &pred[((size_t)b*NTT + s + 1)*NV + ncol0];
        #pragma unroll
        for (int fn = 0; fn < 4; ++fn)
          __builtin_nontemporal_store(acc[fm][fn][r] + b_Lo[ncol0 + fn*16],
                                      &prow[fn*16]);
      }
    }
  }
}

extern "C" void kernel_launch(void* const* d_in, const int* in_sizes, int n_in,
                              void* d_out, int out_size, void* d_ws, size_t ws_size,
                              hipStream_t stream){
  const float* features  = (const float*)d_in[0];
  const int*   captions  = (const int*)  d_in[1];
  const float* emb_table = (const float*)d_in[2];
  const float* ln_q_g = (const float*)d_in[3];
  const float* ln_q_b = (const float*)d_in[4];
  const float* ln_kv_g= (const float*)d_in[5];
  const float* ln_kv_b= (const float*)d_in[6];
  const float* Wq     = (const float*)d_in[7];
  const float* bq     = (const float*)d_in[8];
  const float* Wk     = (const float*)d_in[9];
  const float* bk     = (const float*)d_in[10];
  const float* Wbeta  = (const float*)d_in[11];
  const float* bbeta  = (const float*)d_in[12];
  const float* Wh     = (const float*)d_in[13];
  const float* Wu     = (const float*)d_in[14];
  const float* Wa     = (const float*)d_in[15];
  const float* b_gates= (const float*)d_in[16];
  const float* W_Lh   = (const float*)d_in[17];
  const float* b_Lh   = (const float*)d_in[18];
  const float* W_Lz   = (const float*)d_in[19];
  const float* b_Lz   = (const float*)d_in[20];
  const float* W_Lo   = (const float*)d_in[21];
  const float* b_Lo   = (const float*)d_in[22];
  const float* W_ih   = (const float*)d_in[23];
  const float* b_ih   = (const float*)d_in[24];
  const float* W_ic   = (const float*)d_in[25];
  const float* b_ic   = (const float*)d_in[26];

  float* pred = (float*)d_out;
  float* alph = pred + (size_t)NB * NTT * NV;

  char* w = (char*)d_ws;
  auto alloc = [&](size_t bytes) -> void* {
    void* p = (void*)w; w += (bytes + 255) & ~(size_t)255; return p;
  };
  unsigned short* feats_bf = (unsigned short*)alloc((size_t)NB*NP*DE * 2);
  unsigned short* wlo_t    = (unsigned short*)alloc((size_t)NV*KP * 2);
  unsigned short* whT      = (unsigned short*)alloc((size_t)G4*DD * 2);
  unsigned short* wut      = (unsigned short*)alloc((size_t)G4*KP * 2);
  unsigned short* wat      = (unsigned short*)alloc((size_t)G4*DE * 2);
  unsigned short* WkT      = (unsigned short*)alloc((size_t)DD*DE * 2);
  unsigned short* WLt      = (unsigned short*)alloc((size_t)KP*KG1 * 2);
  unsigned short* Wg       = (unsigned short*)alloc((size_t)DD*DD * 2);
  unsigned short* KFbf     = (unsigned short*)alloc((size_t)NB*NP*DD * 2);
  unsigned short* G2bf     = (unsigned short*)alloc((size_t)NB*NP*DD * 2);
  float2* sc12  = (float2*)alloc((size_t)NB*NP * 8);
  float* vq     = (float*)alloc((size_t)DD * 4);
  float* u_     = (float*)alloc((size_t)DD * 4);
  float* voff   = (float*)alloc((size_t)DD * 4);
  float* gw     = (float*)alloc((size_t)DD * 4);
  float* cscal  = (float*)alloc(16);
  float* mean_a = (float*)alloc((size_t)NB*DE * 4);
  float* hbuf   = (float*)alloc((size_t)NB*DD * 4);
  float* cb0    = (float*)alloc((size_t)NB*DD * 4);
  float* cb1    = (float*)alloc((size_t)NB*DD * 4);
  unsigned short* hstbf = (unsigned short*)alloc((size_t)(NS+1)*NB*DD * 2);
  unsigned short* zbf   = (unsigned short*)alloc((size_t)NS*NB*DE * 2);
  unsigned short* outo  = (unsigned short*)alloc((size_t)1920*KP * 2);
  float* gp     = (float*)alloc((size_t)KSPL*NB*G4 * 4);
  float* eu_all = (float*)alloc((size_t)NS*NB*G4 * 4);
  float* g1p    = (float*)alloc((size_t)6*NS*NB*KP * 4);
  float* cb[2] = { cb0, cb1 };

  k_zero<<<dim3((NB*NV)/256), dim3(256), 0, stream>>>(pred, alph);
  k_ln_feats<<<dim3(NB*NP), dim3(256), 0, stream>>>(features, ln_kv_g, ln_kv_b, feats_bf);
  k_mean<<<dim3((NB*DE)/256), dim3(256), 0, stream>>>(features, mean_a);
  k_cvt_T<<<dim3(NV/64, KP/64), dim3(256), 0, stream>>>(W_Lo, wlo_t, EM, NV, KP);
  k_cvt_T<<<dim3(G4/64, DD/64), dim3(256), 0, stream>>>(Wh, whT, DD, G4, DD);
  k_cvt_T<<<dim3(G4/64, KP/64), dim3(256), 0, stream>>>(Wu, wut, EM, G4, KP);
  k_cvt_T<<<dim3(G4/64, DE/64), dim3(256), 0, stream>>>(Wa, wat, DE, G4, DE);
  k_cvt_T<<<dim3(DD/64, DE/64), dim3(256), 0, stream>>>(Wk, WkT, DE, DD, DE);
  k_cvt_wlt<<<dim3(KP/64, KG1/64), dim3(256), 0, stream>>>(W_Lh, W_Lz, WLt);
  k_wg<<<dim3((DD*DD)/256), dim3(256), 0, stream>>>(Wq, ln_q_g, Wg);
  k_pre_vq<<<dim3(1), dim3(512), 0, stream>>>(Wq, bk, vq);
  k_uvoff<<<dim3(1), dim3(512), 0, stream>>>(Wq, ln_q_g, ln_q_b, bq, Wbeta, bbeta,
      bk, u_, voff, gw, cscal);
  k_KF<<<dim3(NB*NP/64, DD/64), dim3(256), 0, stream>>>(feats_bf, WkT, KFbf);
  k_QG2<<<dim3(NB*NP/64, DD/64), dim3(256), 0, stream>>>(KFbf, Wg, ln_q_g, vq, G2bf);
  k_sc12<<<dim3(NB*NP/8), dim3(512), 0, stream>>>(KFbf, u_, voff, cscal, sc12);
  k_init_g<<<dim3(DD/64), dim3(256), 0, stream>>>(mean_a, W_ih, b_ih, hbuf, hstbf);
  k_init_g<<<dim3(DD/64), dim3(256), 0, stream>>>(mean_a, W_ic, b_ic, cb0, nullptr);
  k_EU<<<dim3(G4/64, NS), dim3(256), 0, stream>>>(emb_table, captions, wut, eu_all);

  for (int s = 0; s < NS; ++s){
    k_A<<<dim3(4, NB), dim3(512), 0, stream>>>(gp, eu_all, b_gates,
        cb[(s & 1) ^ 1], cb[s & 1], hstbf, G2bf, sc12, feats_bf,
        gw, cscal, s, 1, alph, zbf);
    k_B<<<dim3(32, KSPL), dim3(256), 0, stream>>>(hstbf, zbf, whT, wat, s, gp);
  }
  // final LSTM -> h_29
  k_A<<<dim3(1, NB), dim3(512), 0, stream>>>(gp, eu_all, b_gates,
      cb[(NS & 1) ^ 1], cb[NS & 1], hstbf, G2bf, sc12, feats_bf,
      gw, cscal, NS, 0, alph, zbf);

  k_G1m<<<dim3(5, NS, 6), dim3(256), 0, stream>>>(hstbf, zbf, WLt, g1p);
  k_G1red<<<dim3((NS*NB*KP)/256), dim3(256), 0, stream>>>(g1p, b_Lh, b_Lz,
      emb_table, captions, outo);
  k_G2<<<dim3(NV/256, 15), dim3(256), 0, stream>>>(outo, wlo_t, b_Lo, pred);
}

// Round 6
// 1378.631 us; speedup vs baseline: 2.0997x; 1.1010x over previous
//
#include <hip/hip_runtime.h>
#include <hip/hip_bf16.h>

// Decoder (LSTM + attention captioner), MI355X. Round 18:
//  - r17 post-mortem: revert-to-launches + kB 6-split + MLP batching:
//    1872.6 -> 1517.9us. Loop ~38us/step, k_G2 138us, pre ~180us.
//  - r18 deltas:
//    (1) k_G2: bijective XCD-grouping swizzle (1D grid 1875; each XCD owns
//        ~16 contiguous nt slices -> Bt slice 2.6MB L2-resident; was: every
//        XCD streamed all 20.5MB of Bt -> FETCH 157MB).
//    (2) k_B K-split 6->12 (2304 = 12x192), grid (32,12)=384 blocks; k_A
//        gathers 48 batched gp loads (r16-validated shape).
//    (3) k_A: XCD-grouping swizzle - 4 sl-blocks of each b + 8 b's per XCD
//        (G2 score fetch per XCD 4.7->1.2 MB/step).

#define NB 64
#define NP 144
#define DE 1792
#define DD 512
#define DA 512
#define EM 300
#define NV 32000
#define NTT 30
#define NS 29
#define G4 2048
#define KP 320
#define KG1 2304
#define LN_EPS 1e-5f
#define RSCALE 0.044194173824159216f   // 1/sqrt(512)
#define KSPL 12       // K splits in k_B (2304 = 12 x 192)

typedef __attribute__((ext_vector_type(8))) short short8;
typedef __attribute__((ext_vector_type(4))) float f32x4;
typedef __attribute__((ext_vector_type(8))) unsigned short ushort8v;

__device__ __forceinline__ float bf2f(unsigned short u){
  union { unsigned int i; float f; } w; w.i = ((unsigned int)u) << 16; return w.f;
}
__device__ __forceinline__ unsigned short f2bf(float f){
  union { float f; unsigned int i; } u; u.f = f;
  unsigned int r = u.i + 0x7FFFu + ((u.i >> 16) & 1u);
  return (unsigned short)(r >> 16);
}
__device__ __forceinline__ float sigm(float x){ return 1.f/(1.f + __expf(-x)); }

__device__ __forceinline__ float wave_reduce_sum(float v){
  #pragma unroll
  for (int o = 32; o >= 1; o >>= 1) v += __shfl_xor(v, o);
  return v;
}
__device__ __forceinline__ float wave_reduce_max(float v){
  #pragma unroll
  for (int o = 32; o >= 1; o >>= 1) v = fmaxf(v, __shfl_xor(v, o));
  return v;
}
__device__ __forceinline__ float block_sum256(float v, float* sbuf){
  v = wave_reduce_sum(v);
  const int lane = threadIdx.x & 63, wid = threadIdx.x >> 6;
  if (lane == 0) sbuf[wid] = v;
  __syncthreads();
  const float r = sbuf[0] + sbuf[1] + sbuf[2] + sbuf[3];
  __syncthreads();
  return r;
}
__device__ __forceinline__ float block_sum512(float v, float* sbuf8){
  v = wave_reduce_sum(v);
  const int lane = threadIdx.x & 63, wid = threadIdx.x >> 6;
  if (lane == 0) sbuf8[wid] = v;
  __syncthreads();
  float r = 0.f;
  #pragma unroll
  for (int i = 0; i < 8; ++i) r += sbuf8[i];
  __syncthreads();
  return r;
}

// ---- shared MFMA 64x64-tile helpers (validated r4..r10) ----
__device__ __forceinline__ void stage_tile(const unsigned short* __restrict__ src,
    int row_stride, int k0, char* lds){
  const int tid = threadIdx.x;
  #pragma unroll
  for (int c = 0; c < 2; ++c){
    const int o = tid + c*256;
    const int m = o >> 3, ks8 = o & 7;
    const ushort8v v = *(const ushort8v*)&src[(size_t)m*row_stride + k0 + ks8*8];
    *(ushort8v*)&lds[m*128 + ((ks8 ^ (m&7))<<4)] = v;
  }
}
__device__ __forceinline__ void mma64(const char* Alds, const char* Blds,
    int w, int lane, f32x4 acc[4]){
  #pragma unroll
  for (int ks = 0; ks < 2; ++ks){
    const int slot = ks*4 + (lane>>4);
    const int n = w*16 + (lane&15);
    const short8 bfv = *(const short8*)&Blds[n*128 + ((slot ^ (n&7))<<4)];
    #pragma unroll
    for (int fm = 0; fm < 4; ++fm){
      const int m = fm*16 + (lane&15);
      const short8 afv = *(const short8*)&Alds[m*128 + ((slot ^ (m&7))<<4)];
      acc[fm] = __builtin_amdgcn_mfma_f32_16x16x32_bf16(afv, bfv, acc[fm], 0, 0, 0);
    }
  }
}

// ---- zero t=0 rows of both outputs
__global__ __launch_bounds__(256) void k_zero(float* __restrict__ pred,
                                              float* __restrict__ alph){
  const int idx = blockIdx.x * 256 + threadIdx.x;
  {
    const int b = idx / NV, v = idx - b * NV;
    pred[(size_t)b * NTT * NV + v] = 0.f;
  }
  if (idx < NB * NP){
    const int b = idx / NP, p = idx - b * NP;
    alph[(size_t)b * NTT * NP + p] = 0.f;
  }
}

// ---- LayerNorm(features) -> bf16
__global__ __launch_bounds__(256) void k_ln_feats(const float* __restrict__ feats,
    const float* __restrict__ g, const float* __restrict__ bb,
    unsigned short* __restrict__ out){
  __shared__ float sbuf[4];
  const int row = blockIdx.x;
  const float* x = feats + (size_t)row * DE;
  float v[7]; float s = 0.f;
  #pragma unroll
  for (int i = 0; i < 7; ++i){ v[i] = x[i*256 + threadIdx.x]; s += v[i]; }
  const float mean = block_sum256(s, sbuf) * (1.f/DE);
  float q = 0.f;
  #pragma unroll
  for (int i = 0; i < 7; ++i){ const float d = v[i] - mean; q += d*d; }
  const float var = block_sum256(q, sbuf) * (1.f/DE);
  const float rinv = rsqrtf(var + LN_EPS);
  #pragma unroll
  for (int i = 0; i < 7; ++i){
    const int idx = i*256 + threadIdx.x;
    out[(size_t)row*DE + idx] = f2bf((v[i]-mean)*rinv*g[idx] + bb[idx]);
  }
}

// ---- mean over patches
__global__ __launch_bounds__(256) void k_mean(const float* __restrict__ feats,
                                              float* __restrict__ mean_a){
  const int idx = blockIdx.x * 256 + threadIdx.x;
  const int b = idx / DE, d = idx - b * DE;
  const float* p = feats + (size_t)b * NP * DE + d;
  float s = 0.f;
  for (int pp = 0; pp < NP; ++pp) s += p[(size_t)pp * DE];
  mean_a[idx] = s * (1.f/NP);
}

// ---- generic transpose: src fp32 [K][N] -> dst bf16 [N][KPad]
__global__ __launch_bounds__(256) void k_cvt_T(const float* __restrict__ src,
    unsigned short* __restrict__ dst, const int K, const int N, const int KPad){
  __shared__ float t[64][65];
  const int n0 = blockIdx.x*64, k0 = blockIdx.y*64;
  for (int i = threadIdx.x; i < 4096; i += 256){
    const int k = i>>6, n = i&63;
    t[k][n] = (k0 + k < K) ? src[(size_t)(k0+k)*N + n0+n] : 0.f;
  }
  __syncthreads();
  for (int i = threadIdx.x; i < 4096; i += 256){
    const int n = i>>6, k = i&63;
    dst[(size_t)(n0+n)*KPad + k0+k] = f2bf(t[k][n]);
  }
}

// ---- WLt [320 e][2304 k] bf16 <- transpose of [W_Lh; W_Lz]
__global__ __launch_bounds__(256) void k_cvt_wlt(const float* __restrict__ W_Lh,
    const float* __restrict__ W_Lz, unsigned short* __restrict__ WLt){
  __shared__ float t[64][65];
  const int e0 = blockIdx.x*64, k0 = blockIdx.y*64;
  for (int i = threadIdx.x; i < 4096; i += 256){
    const int k = i>>6, e2 = i&63;
    const int kg = k0 + k, e = e0 + e2;
    float v = 0.f;
    if (e < EM) v = (kg < DD) ? W_Lh[(size_t)kg*EM + e] : W_Lz[(size_t)(kg-DD)*EM + e];
    t[k][e2] = v;
  }
  __syncthreads();
  for (int i = threadIdx.x; i < 4096; i += 256){
    const int e2 = i>>6, k = i&63;
    WLt[(size_t)(e0+e2)*KG1 + k0+k] = f2bf(t[k][e2]);
  }
}

// ---- Wg[k][a] = g[k]*Wq[k][a] bf16
__global__ __launch_bounds__(256) void k_wg(const float* __restrict__ Wq,
    const float* __restrict__ g, unsigned short* __restrict__ Wg){
  const int idx = blockIdx.x*256 + threadIdx.x;
  const int k = idx >> 9;
  Wg[idx] = f2bf(g[k]*Wq[idx]);
}

// ---- vq[k] = dot(Wq[k,:], bk)
__global__ __launch_bounds__(512) void k_pre_vq(const float* __restrict__ Wq,
    const float* __restrict__ bk, float* __restrict__ vq){
  const int k = threadIdx.x;
  const float* row = Wq + (size_t)k*DA;
  float acc = 0.f;
  for (int a = 0; a < DA; ++a) acc = fmaf(row[a], bk[a], acc);
  vq[k] = acc;
}

// ---- u[a], voff[a], gw, cscal[4]
__global__ __launch_bounds__(512) void k_uvoff(const float* __restrict__ Wq,
    const float* __restrict__ g, const float* __restrict__ bln,
    const float* __restrict__ bq, const float* __restrict__ Wbeta,
    const float* __restrict__ bbeta, const float* __restrict__ bk,
    float* __restrict__ u_, float* __restrict__ voff,
    float* __restrict__ gw, float* __restrict__ cscal){
  __shared__ float sbuf8[8];
  const int a = threadIdx.x;
  float uu = 0.f, vv = 0.f;
  for (int k = 0; k < DD; ++k){
    const float wv = Wq[(size_t)k*DA + a];
    uu = fmaf(g[k],   wv, uu);
    vv = fmaf(bln[k], wv, vv);
  }
  const float vo = vv + bq[a];
  u_[a]   = uu;
  voff[a] = vo;
  gw[a]   = g[a]*Wbeta[a];
  const float c1 = block_sum512(g[a]*Wbeta[a], sbuf8);
  const float c2 = block_sum512(bln[a]*Wbeta[a], sbuf8);
  const float c3 = block_sum512(uu*bk[a], sbuf8);
  const float c4 = block_sum512(vo*bk[a], sbuf8);
  if (a == 0){ cscal[0]=c1; cscal[1]=c2+bbeta[0]; cscal[2]=c3; cscal[3]=c4; }
}

// ---- KF = feats_bf @ Wk  (bf16 [NB*NP][512]).  grid (144, 8).
__global__ __launch_bounds__(256) void k_KF(const unsigned short* __restrict__ fb,
    const unsigned short* __restrict__ WkT, unsigned short* __restrict__ KF){
  __shared__ char Alds[8192];
  __shared__ char Blds[8192];
  const int mt = blockIdx.x, nt = blockIdx.y;
  const int tid = threadIdx.x, w = tid>>6, lane = tid&63;
  f32x4 acc[4];
  #pragma unroll
  for (int i = 0; i < 4; ++i) acc[i] = (f32x4)(0.f);
  for (int kt = 0; kt < 28; ++kt){
    __syncthreads();
    stage_tile(fb  + (size_t)mt*64*DE, DE, kt*64, Alds);
    stage_tile(WkT + (size_t)nt*64*DE, DE, kt*64, Blds);
    __syncthreads();
    mma64(Alds, Blds, w, lane, acc);
  }
  const int q = nt*64 + w*16 + (lane&15);
  #pragma unroll
  for (int fm = 0; fm < 4; ++fm)
    #pragma unroll
    for (int r = 0; r < 4; ++r){
      const int row = mt*64 + fm*16 + (lane>>4)*4 + r;
      KF[(size_t)row*DD + q] = f2bf(acc[fm][r]);
    }
}

// ---- G2[row][k] = sum_a KF[row][a]*Wg[k][a] + g[k]*vq[k].  grid (144, 8).
__global__ __launch_bounds__(256) void k_QG2(const unsigned short* __restrict__ KF,
    const unsigned short* __restrict__ Wg, const float* __restrict__ g_,
    const float* __restrict__ vq, unsigned short* __restrict__ G2){
  __shared__ char Alds[8192];
  __shared__ char Blds[8192];
  const int mt = blockIdx.x, nt = blockIdx.y;
  const int tid = threadIdx.x, w = tid>>6, lane = tid&63;
  f32x4 acc[4];
  #pragma unroll
  for (int i = 0; i < 4; ++i) acc[i] = (f32x4)(0.f);
  for (int kt = 0; kt < 8; ++kt){
    __syncthreads();
    stage_tile(KF + (size_t)mt*64*DD, DD, kt*64, Alds);
    stage_tile(Wg + (size_t)nt*64*DD, DD, kt*64, Blds);
    __syncthreads();
    mma64(Alds, Blds, w, lane, acc);
  }
  const int q = nt*64 + w*16 + (lane&15);
  const float add = g_[q]*vq[q];
  #pragma unroll
  for (int fm = 0; fm < 4; ++fm)
    #pragma unroll
    for (int r = 0; r < 4; ++r){
      const int row = mt*64 + fm*16 + (lane>>4)*4 + r;
      G2[(size_t)row*DD + q] = f2bf(acc[fm][r] + add);
    }
}

// ---- sc12[row].  grid 144 x 512.
__global__ __launch_bounds__(512) void k_sc12(const unsigned short* __restrict__ KF,
    const float* __restrict__ u_, const float* __restrict__ voff,
    const float* __restrict__ cscal, float2* __restrict__ sc12){
  const int w = threadIdx.x>>6, lane = threadIdx.x&63;
  const int row = blockIdx.x*8 + w;
  const unsigned short* kf = KF + (size_t)row*DD + lane*8;
  float s1 = 0.f, s2 = 0.f;
  #pragma unroll
  for (int j = 0; j < 8; ++j){
    const float kv = bf2f(kf[j]);
    s1 = fmaf(u_[lane*8 + j],   kv, s1);
    s2 = fmaf(voff[lane*8 + j], kv, s2);
  }
  s1 = wave_reduce_sum(s1);
  s2 = wave_reduce_sum(s2);
  if (lane == 0){
    float2 o; o.x = s1 + cscal[2]; o.y = s2 + cscal[3];
    sc12[row] = o;
  }
}

// ---- h0/c0 GEMM (+ optional bf16 mirror)
__global__ __launch_bounds__(256) void k_init_g(const float* __restrict__ mean_a,
    const float* __restrict__ W, const float* __restrict__ bias,
    float* __restrict__ out, unsigned short* __restrict__ outbf){
  __shared__ float la[64*68];
  __shared__ float lb[64*68];
  const int j0 = blockIdx.x*64;
  const int tid = threadIdx.x, tr = tid&15, tn = tid>>4;
  float acc[16] = {0.f};
  for (int a0 = 0; a0 < DE; a0 += 64){
    __syncthreads();
    for (int i = tid; i < 4096; i += 256){
      const int b = i>>6, k = i&63;
      la[k*68 + b] = mean_a[(size_t)b*DE + a0+k];
    }
    for (int i = tid; i < 4096; i += 256){
      const int k = i>>6, j = i&63;
      lb[k*68 + j] = W[(size_t)(a0+k)*DD + j0+j];
    }
    __syncthreads();
    for (int k = 0; k < 64; ++k){
      float av[4], bv[4];
      #pragma unroll
      for (int ii = 0; ii < 4; ++ii) av[ii] = la[k*68 + tr*4+ii];
      #pragma unroll
      for (int jj = 0; jj < 4; ++jj) bv[jj] = lb[k*68 + tn*4+jj];
      #pragma unroll
      for (int ii = 0; ii < 4; ++ii)
        #pragma unroll
        for (int jj = 0; jj < 4; ++jj)
          acc[ii*4+jj] = fmaf(av[ii], bv[jj], acc[ii*4+jj]);
    }
  }
  #pragma unroll
  for (int ii = 0; ii < 4; ++ii)
    #pragma unroll
    for (int jj = 0; jj < 4; ++jj){
      const size_t idx = (size_t)(tr*4+ii)*DD + j0 + tn*4+jj;
      const float val = acc[ii*4+jj] + bias[j0 + tn*4+jj];
      out[idx] = val;
      if (outbf) outbf[idx] = f2bf(val);
    }
}

// ---- precompute eu_all[s][b][2048] = emb(s)@Wu (fp32).  grid (32 jt, 29 s).
__global__ __launch_bounds__(256) void k_EU(const float* __restrict__ emb_table,
    const int* __restrict__ captions, const unsigned short* __restrict__ wut,
    float* __restrict__ eu){
  __shared__ char Alds[8192];
  __shared__ char Blds[8192];
  __shared__ int capL[64];
  const int jt = blockIdx.x, s = blockIdx.y;
  const int tid = threadIdx.x, w = tid>>6, lane = tid&63;
  if (tid < 64) capL[tid] = captions[tid*NTT + s];
  f32x4 acc[4];
  #pragma unroll
  for (int i = 0; i < 4; ++i) acc[i] = (f32x4)(0.f);
  for (int kt = 0; kt < 5; ++kt){
    __syncthreads();
    #pragma unroll
    for (int c = 0; c < 2; ++c){
      const int o = tid + c*256;
      const int m = o>>3, ks8 = o&7;
      const int e0 = kt*64 + ks8*8;
      const float* er = emb_table + (size_t)capL[m]*EM;
      ushort8v v;
      #pragma unroll
      for (int jj = 0; jj < 8; ++jj)
        v[jj] = (e0 + jj < EM) ? f2bf(er[e0 + jj]) : (unsigned short)0;
      *(ushort8v*)&Alds[m*128 + ((ks8 ^ (m&7))<<4)] = v;
    }
    stage_tile(wut + (size_t)jt*64*KP, KP, kt*64, Blds);
    __syncthreads();
    mma64(Alds, Blds, w, lane, acc);
  }
  const int j = jt*64 + w*16 + (lane&15);
  #pragma unroll
  for (int fm = 0; fm < 4; ++fm)
    #pragma unroll
    for (int r = 0; r < 4; ++r){
      const int b = fm*16 + (lane>>4)*4 + r;
      eu[((size_t)s*NB + b)*G4 + j] = acc[fm][r];
    }
}

// ======== per-step kernel A (r17 + XCD grouping, KSPL=12)
__global__ __launch_bounds__(512) void k_A(
    const float* __restrict__ gp, const float* __restrict__ eu,
    const float* __restrict__ b_gates, const float* __restrict__ cin,
    float* __restrict__ cout, unsigned short* __restrict__ hst,
    const unsigned short* __restrict__ G2, const float2* __restrict__ sc12,
    const unsigned short* __restrict__ fb, const float* __restrict__ gw,
    const float* __restrict__ cscal, const int s, const int do_att,
    float* __restrict__ alph, unsigned short* __restrict__ zbf){
  __shared__ alignas(16) unsigned short hL[DD];
  __shared__ float sc[NP];
  __shared__ float al[NP];
  __shared__ float sredA[8*4];
  __shared__ float sbufM[8];
  __shared__ float sbufS[8];
  // XCD grouping: blocks of same b (and 8 b's) share an XCD (bid%8 heuristic)
  int sl, b;
  if (gridDim.x == 1){ sl = 0; b = blockIdx.y; }
  else {
    const int lin = blockIdx.x + 4*blockIdx.y;
    const int xcd = lin & 7, i = lin >> 3;
    b = xcd*8 + (i & 7);
    sl = i >> 3;
  }
  const int tid = threadIdx.x;
  const int w = tid>>6, lane = tid&63;
  float hn;
  if (s == 0){
    const unsigned short hb = hst[(size_t)b*DD + tid];
    hn = bf2f(hb);
    hL[tid] = hb;
  } else {
    const int m = s - 1;
    // explicit MLP: issue all KSPL*4 partial loads before summing
    float gv[4*KSPL];
    #pragma unroll
    for (int ks = 0; ks < KSPL; ++ks){
      const float* gr = gp + ((size_t)ks*NB + b)*G4 + tid;
      gv[ks*4+0] = gr[0];
      gv[ks*4+1] = gr[DD];
      gv[ks*4+2] = gr[2*DD];
      gv[ks*4+3] = gr[3*DD];
    }
    const float* eur = eu + ((size_t)m*NB + b)*G4 + tid;
    float gs0 = b_gates[tid]        + eur[0];
    float gs1 = b_gates[DD + tid]   + eur[DD];
    float gs2 = b_gates[2*DD + tid] + eur[2*DD];
    float gs3 = b_gates[3*DD + tid] + eur[3*DD];
    #pragma unroll
    for (int ks = 0; ks < KSPL; ++ks){
      gs0 += gv[ks*4+0]; gs1 += gv[ks*4+1];
      gs2 += gv[ks*4+2]; gs3 += gv[ks*4+3];
    }
    const size_t idx = (size_t)b*DD + tid;
    const float cn = sigm(gs1)*cin[idx] + sigm(gs0)*tanhf(gs3);
    hn = sigm(gs2)*tanhf(cn);
    cout[idx] = cn;
    const unsigned short hb = f2bf(hn);
    hst[(size_t)s*NB*DD + idx] = hb;
    hL[tid] = hb;
  }
  if (!do_att) return;
  float p1 = hn, p2 = hn*hn, p3 = hn*gw[tid];
  #pragma unroll
  for (int o = 32; o >= 1; o >>= 1){
    p1 += __shfl_xor(p1, o);
    p2 += __shfl_xor(p2, o);
    p3 += __shfl_xor(p3, o);
  }
  if (lane == 0){ sredA[w*4] = p1; sredA[w*4+1] = p2; sredA[w*4+2] = p3; }
  __syncthreads();
  float S1 = 0.f, S2 = 0.f, S3 = 0.f;
  #pragma unroll
  for (int i = 0; i < 8; ++i){
    S1 += sredA[i*4]; S2 += sredA[i*4+1]; S3 += sredA[i*4+2];
  }
  const float mean = S1*(1.f/512.f);
  const float var  = S2*(1.f/512.f) - mean*mean;
  const float rinv = rsqrtf(var + LN_EPS);
  const float beta = sigm(rinv*(S3 - mean*cscal[0]) + cscal[1]);
  const ushort4 h0 = *(const ushort4*)&hL[lane*8];
  const ushort4 h1 = *(const ushort4*)&hL[lane*8 + 4];
  // scores in batches of 6 rows (MLP)
  #pragma unroll 1
  for (int i0 = 0; i0 < 18; i0 += 6){
    ushort4 U0[6], U1[6];
    float2 SV[6];
    #pragma unroll
    for (int j = 0; j < 6; ++j){
      const int p = w + 8*(i0+j);
      const unsigned short* g2r = G2 + (size_t)(b*NP + p)*DD + lane*8;
      U0[j] = *(const ushort4*)g2r;
      U1[j] = *(const ushort4*)(g2r + 4);
      if (lane == 0) SV[j] = sc12[b*NP + p];
    }
    #pragma unroll
    for (int j = 0; j < 6; ++j){
      float a2 = 0.f;
      a2 = fmaf(bf2f(U0[j].x), bf2f(h0.x), a2); a2 = fmaf(bf2f(U0[j].y), bf2f(h0.y), a2);
      a2 = fmaf(bf2f(U0[j].z), bf2f(h0.z), a2); a2 = fmaf(bf2f(U0[j].w), bf2f(h0.w), a2);
      a2 = fmaf(bf2f(U1[j].x), bf2f(h1.x), a2); a2 = fmaf(bf2f(U1[j].y), bf2f(h1.y), a2);
      a2 = fmaf(bf2f(U1[j].z), bf2f(h1.z), a2); a2 = fmaf(bf2f(U1[j].w), bf2f(h1.w), a2);
      a2 = wave_reduce_sum(a2);
      if (lane == 0)
        sc[w + 8*(i0+j)] = RSCALE*(rinv*a2 - rinv*mean*SV[j].x + SV[j].y);
    }
  }
  __syncthreads();
  const float v = (tid < NP) ? sc[tid] : -1e30f;
  const float mv = wave_reduce_max(v);
  if (lane == 0) sbufM[w] = mv;
  __syncthreads();
  float mm = sbufM[0];
  #pragma unroll
  for (int i = 1; i < 8; ++i) mm = fmaxf(mm, sbufM[i]);
  const float e = (tid < NP) ? __expf(v - mm) : 0.f;
  const float sv = wave_reduce_sum(e);
  if (lane == 0) sbufS[w] = sv;
  __syncthreads();
  float ssum = 0.f;
  #pragma unroll
  for (int i = 0; i < 8; ++i) ssum += sbufS[i];
  if (tid < NP){
    const float a3 = e / ssum;
    al[tid] = a3;
    if (sl == 0) alph[((size_t)b*NTT + s + 1)*NP + tid] = a3;
  }
  __syncthreads();
  if (tid < 448){
    const int d = sl*448 + tid;
    const unsigned short* fcol = fb + (size_t)b*NP*DE + d;
    float acc = 0.f;
    // z-GEMV in batches of 12 (MLP)
    #pragma unroll 1
    for (int p0 = 0; p0 < NP; p0 += 12){
      unsigned short fv[12];
      #pragma unroll
      for (int j = 0; j < 12; ++j) fv[j] = fcol[(size_t)(p0+j)*DE];
      #pragma unroll
      for (int j = 0; j < 12; ++j) acc = fmaf(al[p0+j], bf2f(fv[j]), acc);
    }
    zbf[((size_t)s*NB + b)*DE + d] = f2bf(acc*beta);
  }
}

// ======== per-step kernel B (K-split 12).  grid (32, 12).
__global__ __launch_bounds__(256) void k_B(
    const unsigned short* __restrict__ hst, const unsigned short* __restrict__ zbf,
    const unsigned short* __restrict__ whT, const unsigned short* __restrict__ wat,
    const int s, float* __restrict__ gp){
  __shared__ char Alds[8192];
  __shared__ char Blds[8192];
  const int jt = blockIdx.x, ks = blockIdx.y;
  const int tid = threadIdx.x, w = tid>>6, lane = tid&63;
  const unsigned short* hrow = hst + (size_t)s*NB*DD;
  const unsigned short* zrow = zbf + (size_t)s*NB*DE;
  f32x4 acc[4];
  #pragma unroll
  for (int i = 0; i < 4; ++i) acc[i] = (f32x4)(0.f);
  for (int kt = 0; kt < 3; ++kt){
    const int k0 = ks*192 + kt*64;
    __syncthreads();
    if (k0 < DD) stage_tile(hrow, DD, k0, Alds);
    else         stage_tile(zrow, DE, k0 - DD, Alds);
    #pragma unroll
    for (int c2 = 0; c2 < 2; ++c2){
      const int o = tid + c2*256;
      const int m = o>>3, ks8 = o&7;
      const int col = (m>>4)*DD + jt*16 + (m&15);
      const unsigned short* src = (k0 < DD)
          ? whT + (size_t)col*DD + k0
          : wat + (size_t)col*DE + (k0 - DD);
      const ushort8v v = *(const ushort8v*)&src[ks8*8];
      *(ushort8v*)&Blds[m*128 + ((ks8 ^ (m&7))<<4)] = v;
    }
    __syncthreads();
    mma64(Alds, Blds, w, lane, acc);
  }
  const int jcol = jt*16 + (lane&15);
  float* gps = gp + (size_t)ks*NB*G4;
  #pragma unroll
  for (int fm = 0; fm < 4; ++fm)
    #pragma unroll
    for (int r = 0; r < 4; ++r){
      const int b = fm*16 + (lane>>4)*4 + r;
      gps[(size_t)b*G4 + w*DD + jcol] = acc[fm][r];
    }
}

// ---- post G1: out_o partial MFMA.  grid (5 e-tiles, 29 s, 6 ksplit).
__global__ __launch_bounds__(256) void k_G1m(const unsigned short* __restrict__ hstbf,
    const unsigned short* __restrict__ zbf, const unsigned short* __restrict__ WLt,
    float* __restrict__ g1p){
  __shared__ char Alds[8192];
  __shared__ char Blds[8192];
  const int e0 = blockIdx.x*64, s = blockIdx.y, ks6 = blockIdx.z;
  const int tid = threadIdx.x, w = tid>>6, lane = tid&63;
  const unsigned short* hrow = hstbf + (size_t)(s+1)*NB*DD;
  const unsigned short* zrow = zbf + (size_t)s*NB*DE;
  f32x4 acc[4];
  #pragma unroll
  for (int i = 0; i < 4; ++i) acc[i] = (f32x4)(0.f);
  for (int kt = 0; kt < 6; ++kt){
    const int k0 = ks6*384 + kt*64;
    __syncthreads();
    if (k0 < DD) stage_tile(hrow, DD, k0, Alds);
    else         stage_tile(zrow, DE, k0 - DD, Alds);
    stage_tile(WLt + (size_t)e0*KG1, KG1, k0, Blds);
    __syncthreads();
    mma64(Alds, Blds, w, lane, acc);
  }
  const int e = e0 + w*16 + (lane&15);
  float* dst = g1p + (size_t)ks6*NS*NB*KP;
  #pragma unroll
  for (int fm = 0; fm < 4; ++fm)
    #pragma unroll
    for (int r = 0; r < 4; ++r){
      const int b = fm*16 + (lane>>4)*4 + r;
      dst[((size_t)s*NB + b)*KP + e] = acc[fm][r];
    }
}

// ---- post G1red: sum 6 partials + emb + biases -> outo bf16
__global__ __launch_bounds__(256) void k_G1red(const float* __restrict__ g1p,
    const float* __restrict__ b_Lh, const float* __restrict__ b_Lz,
    const float* __restrict__ emb_table, const int* __restrict__ captions,
    unsigned short* __restrict__ outo){
  const int idx = blockIdx.x*256 + threadIdx.x;
  const int row = idx / KP, e = idx - row*KP;
  const int s = row >> 6, b = row & 63;
  float v = 0.f;
  #pragma unroll
  for (int ks6 = 0; ks6 < 6; ++ks6) v += g1p[(size_t)ks6*NS*NB*KP + idx];
  if (e < EM){
    const int cap = captions[b*NTT + s];
    v += b_Lh[e] + b_Lz[e] + emb_table[(size_t)cap*EM + e];
  } else v = 0.f;
  outo[idx] = f2bf(v);
}

// ---- post G2: logits MFMA, M-tile 128.  1D grid 1875 with bijective
// XCD-grouping swizzle: each XCD owns ~16 contiguous nt slices (Bt slice
// 2.6MB -> L2-resident) and all 15 mt for those nt.  NONTEMPORAL stores.
__global__ __launch_bounds__(256) void k_G2(const unsigned short* __restrict__ Abf,
    const unsigned short* __restrict__ Bt, const float* __restrict__ b_Lo,
    float* __restrict__ pred){
  __shared__ char Alds[128*128];
  __shared__ char Blds[256*128];
  // nwg=1875, NXCD=8: q=234, r=3 (xcd 0..2 have 235 blocks)
  const int bid = blockIdx.x;
  const int xcd = bid & 7, idx8 = bid >> 3;
  const int wgid = (xcd < 3 ? xcd*235 : 705 + (xcd-3)*234) + idx8;
  const int nt = wgid / 15, mt = wgid - nt*15;
  const int tid = threadIdx.x, w = tid>>6, lane = tid&63;
  f32x4 acc[8][4];
  #pragma unroll
  for (int i = 0; i < 8; ++i)
    #pragma unroll
    for (int j = 0; j < 4; ++j)
      acc[i][j] = (f32x4)(0.f);
  for (int kt = 0; kt < 5; ++kt){
    const int k0 = kt*64;
    __syncthreads();
    #pragma unroll
    for (int c2 = 0; c2 < 4; ++c2){
      const int o16 = tid + c2*256;
      const int m = o16>>3, ks8 = o16&7;
      const ushort8v v = *(const ushort8v*)&Abf[(size_t)(mt*128+m)*KP + k0 + ks8*8];
      *(ushort8v*)&Alds[m*128 + ((ks8 ^ (m&7))<<4)] = v;
    }
    #pragma unroll
    for (int c2 = 0; c2 < 8; ++c2){
      const int o16 = tid + c2*256;
      const int n = o16>>3, ks8 = o16&7;
      const ushort8v v = *(const ushort8v*)&Bt[(size_t)(nt*256+n)*KP + k0 + ks8*8];
      *(ushort8v*)&Blds[n*128 + ((ks8 ^ (n&7))<<4)] = v;
    }
    __syncthreads();
    #pragma unroll
    for (int ks = 0; ks < 2; ++ks){
      const int slot = ks*4 + (lane>>4);
      short8 af[8];
      #pragma unroll
      for (int fm = 0; fm < 8; ++fm){
        const int m = fm*16 + (lane&15);
        af[fm] = *(const short8*)&Alds[m*128 + ((slot ^ (m&7))<<4)];
      }
      #pragma unroll
      for (int fn = 0; fn < 4; ++fn){
        const int n = w*64 + fn*16 + (lane&15);
        const short8 bfv = *(const short8*)&Blds[n*128 + ((slot ^ (n&7))<<4)];
        #pragma unroll
        for (int fm = 0; fm < 8; ++fm)
          acc[fm][fn] = __builtin_amdgcn_mfma_f32_16x16x32_bf16(af[fm], bfv, acc[fm][fn], 0, 0, 0);
      }
    }
  }
  const int ncol0 = nt*256 + w*64 + (lane&15);
  #pragma unroll
  for (int fm = 0; fm < 8; ++fm){
    #pragma unroll
    for (int r = 0; r < 4; ++r){
      const int row = mt*128 + fm*16 + (lane>>4)*4 + r;
      if (row < NS*NB){
        const int s = row >> 6, b = row & 63;
        float* prow = &pred[((size_t)b*NTT + s + 1)*NV + ncol0];
        #pragma unroll
        for (int fn = 0; fn < 4; ++fn)
          __builtin_nontemporal_store(acc[fm][fn][r] + b_Lo[ncol0 + fn*16],
                                      &prow[fn*16]);
      }
    }
  }
}

extern "C" void kernel_launch(void* const* d_in, const int* in_sizes, int n_in,
                              void* d_out, int out_size, void* d_ws, size_t ws_size,
                              hipStream_t stream){
  const float* features  = (const float*)d_in[0];
  const int*   captions  = (const int*)  d_in[1];
  const float* emb_table = (const float*)d_in[2];
  const float* ln_q_g = (const float*)d_in[3];
  const float* ln_q_b = (const float*)d_in[4];
  const float* ln_kv_g= (const float*)d_in[5];
  const float* ln_kv_b= (const float*)d_in[6];
  const float* Wq     = (const float*)d_in[7];
  const float* bq     = (const float*)d_in[8];
  const float* Wk     = (const float*)d_in[9];
  const float* bk     = (const float*)d_in[10];
  const float* Wbeta  = (const float*)d_in[11];
  const float* bbeta  = (const float*)d_in[12];
  const float* Wh     = (const float*)d_in[13];
  const float* Wu     = (const float*)d_in[14];
  const float* Wa     = (const float*)d_in[15];
  const float* b_gates= (const float*)d_in[16];
  const float* W_Lh   = (const float*)d_in[17];
  const float* b_Lh   = (const float*)d_in[18];
  const float* W_Lz   = (const float*)d_in[19];
  const float* b_Lz   = (const float*)d_in[20];
  const float* W_Lo   = (const float*)d_in[21];
  const float* b_Lo   = (const float*)d_in[22];
  const float* W_ih   = (const float*)d_in[23];
  const float* b_ih   = (const float*)d_in[24];
  const float* W_ic   = (const float*)d_in[25];
  const float* b_ic   = (const float*)d_in[26];

  float* pred = (float*)d_out;
  float* alph = pred + (size_t)NB * NTT * NV;

  char* w = (char*)d_ws;
  auto alloc = [&](size_t bytes) -> void* {
    void* p = (void*)w; w += (bytes + 255) & ~(size_t)255; return p;
  };
  unsigned short* feats_bf = (unsigned short*)alloc((size_t)NB*NP*DE * 2);
  unsigned short* wlo_t    = (unsigned short*)alloc((size_t)NV*KP * 2);
  unsigned short* whT      = (unsigned short*)alloc((size_t)G4*DD * 2);
  unsigned short* wut      = (unsigned short*)alloc((size_t)G4*KP * 2);
  unsigned short* wat      = (unsigned short*)alloc((size_t)G4*DE * 2);
  unsigned short* WkT      = (unsigned short*)alloc((size_t)DD*DE * 2);
  unsigned short* WLt      = (unsigned short*)alloc((size_t)KP*KG1 * 2);
  unsigned short* Wg       = (unsigned short*)alloc((size_t)DD*DD * 2);
  unsigned short* KFbf     = (unsigned short*)alloc((size_t)NB*NP*DD * 2);
  unsigned short* G2bf     = (unsigned short*)alloc((size_t)NB*NP*DD * 2);
  float2* sc12  = (float2*)alloc((size_t)NB*NP * 8);
  float* vq     = (float*)alloc((size_t)DD * 4);
  float* u_     = (float*)alloc((size_t)DD * 4);
  float* voff   = (float*)alloc((size_t)DD * 4);
  float* gw     = (float*)alloc((size_t)DD * 4);
  float* cscal  = (float*)alloc(16);
  float* mean_a = (float*)alloc((size_t)NB*DE * 4);
  float* hbuf   = (float*)alloc((size_t)NB*DD * 4);
  float* cb0    = (float*)alloc((size_t)NB*DD * 4);
  float* cb1    = (float*)alloc((size_t)NB*DD * 4);
  unsigned short* hstbf = (unsigned short*)alloc((size_t)(NS+1)*NB*DD * 2);
  unsigned short* zbf   = (unsigned short*)alloc((size_t)NS*NB*DE * 2);
  unsigned short* outo  = (unsigned short*)alloc((size_t)1920*KP * 2);
  float* gp     = (float*)alloc((size_t)KSPL*NB*G4 * 4);
  float* eu_all = (float*)alloc((size_t)NS*NB*G4 * 4);
  float* g1p    = (float*)alloc((size_t)6*NS*NB*KP * 4);
  float* cb[2] = { cb0, cb1 };

  k_zero<<<dim3((NB*NV)/256), dim3(256), 0, stream>>>(pred, alph);
  k_ln_feats<<<dim3(NB*NP), dim3(256), 0, stream>>>(features, ln_kv_g, ln_kv_b, feats_bf);
  k_mean<<<dim3((NB*DE)/256), dim3(256), 0, stream>>>(features, mean_a);
  k_cvt_T<<<dim3(NV/64, KP/64), dim3(256), 0, stream>>>(W_Lo, wlo_t, EM, NV, KP);
  k_cvt_T<<<dim3(G4/64, DD/64), dim3(256), 0, stream>>>(Wh, whT, DD, G4, DD);
  k_cvt_T<<<dim3(G4/64, KP/64), dim3(256), 0, stream>>>(Wu, wut, EM, G4, KP);
  k_cvt_T<<<dim3(G4/64, DE/64), dim3(256), 0, stream>>>(Wa, wat, DE, G4, DE);
  k_cvt_T<<<dim3(DD/64, DE/64), dim3(256), 0, stream>>>(Wk, WkT, DE, DD, DE);
  k_cvt_wlt<<<dim3(KP/64, KG1/64), dim3(256), 0, stream>>>(W_Lh, W_Lz, WLt);
  k_wg<<<dim3((DD*DD)/256), dim3(256), 0, stream>>>(Wq, ln_q_g, Wg);
  k_pre_vq<<<dim3(1), dim3(512), 0, stream>>>(Wq, bk, vq);
  k_uvoff<<<dim3(1), dim3(512), 0, stream>>>(Wq, ln_q_g, ln_q_b, bq, Wbeta, bbeta,
      bk, u_, voff, gw, cscal);
  k_KF<<<dim3(NB*NP/64, DD/64), dim3(256), 0, stream>>>(feats_bf, WkT, KFbf);
  k_QG2<<<dim3(NB*NP/64, DD/64), dim3(256), 0, stream>>>(KFbf, Wg, ln_q_g, vq, G2bf);
  k_sc12<<<dim3(NB*NP/8), dim3(512), 0, stream>>>(KFbf, u_, voff, cscal, sc12);
  k_init_g<<<dim3(DD/64), dim3(256), 0, stream>>>(mean_a, W_ih, b_ih, hbuf, hstbf);
  k_init_g<<<dim3(DD/64), dim3(256), 0, stream>>>(mean_a, W_ic, b_ic, cb0, nullptr);
  k_EU<<<dim3(G4/64, NS), dim3(256), 0, stream>>>(emb_table, captions, wut, eu_all);

  for (int s = 0; s < NS; ++s){
    k_A<<<dim3(4, NB), dim3(512), 0, stream>>>(gp, eu_all, b_gates,
        cb[(s & 1) ^ 1], cb[s & 1], hstbf, G2bf, sc12, feats_bf,
        gw, cscal, s, 1, alph, zbf);
    k_B<<<dim3(32, KSPL), dim3(256), 0, stream>>>(hstbf, zbf, whT, wat, s, gp);
  }
  // final LSTM -> h_29
  k_A<<<dim3(1, NB), dim3(512), 0, stream>>>(gp, eu_all, b_gates,
      cb[(NS & 1) ^ 1], cb[NS & 1], hstbf, G2bf, sc12, feats_bf,
      gw, cscal, NS, 0, alph, zbf);

  k_G1m<<<dim3(5, NS, 6), dim3(256), 0, stream>>>(hstbf, zbf, WLt, g1p);
  k_G1red<<<dim3((NS*NB*KP)/256), dim3(256), 0, stream>>>(g1p, b_Lh, b_Lz,
      emb_table, captions, outo);
  k_G2<<<dim3(1875), dim3(256), 0, stream>>>(outo, wlo_t, b_Lo, pred);
}

// Round 7
// 1314.573 us; speedup vs baseline: 2.2020x; 1.0487x over previous
//
#include <hip/hip_runtime.h>
#include <hip/hip_bf16.h>

// Decoder (LSTM + attention captioner), MI355X. Round 19:
//  - r18 post-mortem: 1517.9 -> 1378.6us (k_G2 XCD swizzle + kB 12-split +
//    k_A grouping). Loop ~34us/step now dominates (~1.0ms).
//  - r19: k_A traffic budget: required 49MB/step, actual 96MB (gp/G2/eu
//    read 4x redundantly by the 4 sl-blocks). Go to 2 slices/batch
//    (grid (2,NB)=128 blocks): redundancy halves (96->75MB/step); z-GEMV
//    takes 2 cols/thread via ushort2 (4B coalesced, better than 2B).
//    Scores: single 16B short8 G2 loads (was 2x8B).

#define NB 64
#define NP 144
#define DE 1792
#define DD 512
#define DA 512
#define EM 300
#define NV 32000
#define NTT 30
#define NS 29
#define G4 2048
#define KP 320
#define KG1 2304
#define LN_EPS 1e-5f
#define RSCALE 0.044194173824159216f   // 1/sqrt(512)
#define KSPL 12       // K splits in k_B (2304 = 12 x 192)

typedef __attribute__((ext_vector_type(8))) short short8;
typedef __attribute__((ext_vector_type(4))) float f32x4;
typedef __attribute__((ext_vector_type(8))) unsigned short ushort8v;

__device__ __forceinline__ float bf2f(unsigned short u){
  union { unsigned int i; float f; } w; w.i = ((unsigned int)u) << 16; return w.f;
}
__device__ __forceinline__ unsigned short f2bf(float f){
  union { float f; unsigned int i; } u; u.f = f;
  unsigned int r = u.i + 0x7FFFu + ((u.i >> 16) & 1u);
  return (unsigned short)(r >> 16);
}
__device__ __forceinline__ float sigm(float x){ return 1.f/(1.f + __expf(-x)); }

__device__ __forceinline__ float wave_reduce_sum(float v){
  #pragma unroll
  for (int o = 32; o >= 1; o >>= 1) v += __shfl_xor(v, o);
  return v;
}
__device__ __forceinline__ float wave_reduce_max(float v){
  #pragma unroll
  for (int o = 32; o >= 1; o >>= 1) v = fmaxf(v, __shfl_xor(v, o));
  return v;
}
__device__ __forceinline__ float block_sum256(float v, float* sbuf){
  v = wave_reduce_sum(v);
  const int lane = threadIdx.x & 63, wid = threadIdx.x >> 6;
  if (lane == 0) sbuf[wid] = v;
  __syncthreads();
  const float r = sbuf[0] + sbuf[1] + sbuf[2] + sbuf[3];
  __syncthreads();
  return r;
}
__device__ __forceinline__ float block_sum512(float v, float* sbuf8){
  v = wave_reduce_sum(v);
  const int lane = threadIdx.x & 63, wid = threadIdx.x >> 6;
  if (lane == 0) sbuf8[wid] = v;
  __syncthreads();
  float r = 0.f;
  #pragma unroll
  for (int i = 0; i < 8; ++i) r += sbuf8[i];
  __syncthreads();
  return r;
}

// ---- shared MFMA 64x64-tile helpers (validated r4..r10) ----
__device__ __forceinline__ void stage_tile(const unsigned short* __restrict__ src,
    int row_stride, int k0, char* lds){
  const int tid = threadIdx.x;
  #pragma unroll
  for (int c = 0; c < 2; ++c){
    const int o = tid + c*256;
    const int m = o >> 3, ks8 = o & 7;
    const ushort8v v = *(const ushort8v*)&src[(size_t)m*row_stride + k0 + ks8*8];
    *(ushort8v*)&lds[m*128 + ((ks8 ^ (m&7))<<4)] = v;
  }
}
__device__ __forceinline__ void mma64(const char* Alds, const char* Blds,
    int w, int lane, f32x4 acc[4]){
  #pragma unroll
  for (int ks = 0; ks < 2; ++ks){
    const int slot = ks*4 + (lane>>4);
    const int n = w*16 + (lane&15);
    const short8 bfv = *(const short8*)&Blds[n*128 + ((slot ^ (n&7))<<4)];
    #pragma unroll
    for (int fm = 0; fm < 4; ++fm){
      const int m = fm*16 + (lane&15);
      const short8 afv = *(const short8*)&Alds[m*128 + ((slot ^ (m&7))<<4)];
      acc[fm] = __builtin_amdgcn_mfma_f32_16x16x32_bf16(afv, bfv, acc[fm], 0, 0, 0);
    }
  }
}

// ---- zero t=0 rows of both outputs
__global__ __launch_bounds__(256) void k_zero(float* __restrict__ pred,
                                              float* __restrict__ alph){
  const int idx = blockIdx.x * 256 + threadIdx.x;
  {
    const int b = idx / NV, v = idx - b * NV;
    pred[(size_t)b * NTT * NV + v] = 0.f;
  }
  if (idx < NB * NP){
    const int b = idx / NP, p = idx - b * NP;
    alph[(size_t)b * NTT * NP + p] = 0.f;
  }
}

// ---- LayerNorm(features) -> bf16
__global__ __launch_bounds__(256) void k_ln_feats(const float* __restrict__ feats,
    const float* __restrict__ g, const float* __restrict__ bb,
    unsigned short* __restrict__ out){
  __shared__ float sbuf[4];
  const int row = blockIdx.x;
  const float* x = feats + (size_t)row * DE;
  float v[7]; float s = 0.f;
  #pragma unroll
  for (int i = 0; i < 7; ++i){ v[i] = x[i*256 + threadIdx.x]; s += v[i]; }
  const float mean = block_sum256(s, sbuf) * (1.f/DE);
  float q = 0.f;
  #pragma unroll
  for (int i = 0; i < 7; ++i){ const float d = v[i] - mean; q += d*d; }
  const float var = block_sum256(q, sbuf) * (1.f/DE);
  const float rinv = rsqrtf(var + LN_EPS);
  #pragma unroll
  for (int i = 0; i < 7; ++i){
    const int idx = i*256 + threadIdx.x;
    out[(size_t)row*DE + idx] = f2bf((v[i]-mean)*rinv*g[idx] + bb[idx]);
  }
}

// ---- mean over patches
__global__ __launch_bounds__(256) void k_mean(const float* __restrict__ feats,
                                              float* __restrict__ mean_a){
  const int idx = blockIdx.x * 256 + threadIdx.x;
  const int b = idx / DE, d = idx - b * DE;
  const float* p = feats + (size_t)b * NP * DE + d;
  float s = 0.f;
  for (int pp = 0; pp < NP; ++pp) s += p[(size_t)pp * DE];
  mean_a[idx] = s * (1.f/NP);
}

// ---- generic transpose: src fp32 [K][N] -> dst bf16 [N][KPad]
__global__ __launch_bounds__(256) void k_cvt_T(const float* __restrict__ src,
    unsigned short* __restrict__ dst, const int K, const int N, const int KPad){
  __shared__ float t[64][65];
  const int n0 = blockIdx.x*64, k0 = blockIdx.y*64;
  for (int i = threadIdx.x; i < 4096; i += 256){
    const int k = i>>6, n = i&63;
    t[k][n] = (k0 + k < K) ? src[(size_t)(k0+k)*N + n0+n] : 0.f;
  }
  __syncthreads();
  for (int i = threadIdx.x; i < 4096; i += 256){
    const int n = i>>6, k = i&63;
    dst[(size_t)(n0+n)*KPad + k0+k] = f2bf(t[k][n]);
  }
}

// ---- WLt [320 e][2304 k] bf16 <- transpose of [W_Lh; W_Lz]
__global__ __launch_bounds__(256) void k_cvt_wlt(const float* __restrict__ W_Lh,
    const float* __restrict__ W_Lz, unsigned short* __restrict__ WLt){
  __shared__ float t[64][65];
  const int e0 = blockIdx.x*64, k0 = blockIdx.y*64;
  for (int i = threadIdx.x; i < 4096; i += 256){
    const int k = i>>6, e2 = i&63;
    const int kg = k0 + k, e = e0 + e2;
    float v = 0.f;
    if (e < EM) v = (kg < DD) ? W_Lh[(size_t)kg*EM + e] : W_Lz[(size_t)(kg-DD)*EM + e];
    t[k][e2] = v;
  }
  __syncthreads();
  for (int i = threadIdx.x; i < 4096; i += 256){
    const int e2 = i>>6, k = i&63;
    WLt[(size_t)(e0+e2)*KG1 + k0+k] = f2bf(t[k][e2]);
  }
}

// ---- Wg[k][a] = g[k]*Wq[k][a] bf16
__global__ __launch_bounds__(256) void k_wg(const float* __restrict__ Wq,
    const float* __restrict__ g, unsigned short* __restrict__ Wg){
  const int idx = blockIdx.x*256 + threadIdx.x;
  const int k = idx >> 9;
  Wg[idx] = f2bf(g[k]*Wq[idx]);
}

// ---- vq[k] = dot(Wq[k,:], bk)
__global__ __launch_bounds__(512) void k_pre_vq(const float* __restrict__ Wq,
    const float* __restrict__ bk, float* __restrict__ vq){
  const int k = threadIdx.x;
  const float* row = Wq + (size_t)k*DA;
  float acc = 0.f;
  for (int a = 0; a < DA; ++a) acc = fmaf(row[a], bk[a], acc);
  vq[k] = acc;
}

// ---- u[a], voff[a], gw, cscal[4]
__global__ __launch_bounds__(512) void k_uvoff(const float* __restrict__ Wq,
    const float* __restrict__ g, const float* __restrict__ bln,
    const float* __restrict__ bq, const float* __restrict__ Wbeta,
    const float* __restrict__ bbeta, const float* __restrict__ bk,
    float* __restrict__ u_, float* __restrict__ voff,
    float* __restrict__ gw, float* __restrict__ cscal){
  __shared__ float sbuf8[8];
  const int a = threadIdx.x;
  float uu = 0.f, vv = 0.f;
  for (int k = 0; k < DD; ++k){
    const float wv = Wq[(size_t)k*DA + a];
    uu = fmaf(g[k],   wv, uu);
    vv = fmaf(bln[k], wv, vv);
  }
  const float vo = vv + bq[a];
  u_[a]   = uu;
  voff[a] = vo;
  gw[a]   = g[a]*Wbeta[a];
  const float c1 = block_sum512(g[a]*Wbeta[a], sbuf8);
  const float c2 = block_sum512(bln[a]*Wbeta[a], sbuf8);
  const float c3 = block_sum512(uu*bk[a], sbuf8);
  const float c4 = block_sum512(vo*bk[a], sbuf8);
  if (a == 0){ cscal[0]=c1; cscal[1]=c2+bbeta[0]; cscal[2]=c3; cscal[3]=c4; }
}

// ---- KF = feats_bf @ Wk  (bf16 [NB*NP][512]).  grid (144, 8).
__global__ __launch_bounds__(256) void k_KF(const unsigned short* __restrict__ fb,
    const unsigned short* __restrict__ WkT, unsigned short* __restrict__ KF){
  __shared__ char Alds[8192];
  __shared__ char Blds[8192];
  const int mt = blockIdx.x, nt = blockIdx.y;
  const int tid = threadIdx.x, w = tid>>6, lane = tid&63;
  f32x4 acc[4];
  #pragma unroll
  for (int i = 0; i < 4; ++i) acc[i] = (f32x4)(0.f);
  for (int kt = 0; kt < 28; ++kt){
    __syncthreads();
    stage_tile(fb  + (size_t)mt*64*DE, DE, kt*64, Alds);
    stage_tile(WkT + (size_t)nt*64*DE, DE, kt*64, Blds);
    __syncthreads();
    mma64(Alds, Blds, w, lane, acc);
  }
  const int q = nt*64 + w*16 + (lane&15);
  #pragma unroll
  for (int fm = 0; fm < 4; ++fm)
    #pragma unroll
    for (int r = 0; r < 4; ++r){
      const int row = mt*64 + fm*16 + (lane>>4)*4 + r;
      KF[(size_t)row*DD + q] = f2bf(acc[fm][r]);
    }
}

// ---- G2[row][k] = sum_a KF[row][a]*Wg[k][a] + g[k]*vq[k].  grid (144, 8).
__global__ __launch_bounds__(256) void k_QG2(const unsigned short* __restrict__ KF,
    const unsigned short* __restrict__ Wg, const float* __restrict__ g_,
    const float* __restrict__ vq, unsigned short* __restrict__ G2){
  __shared__ char Alds[8192];
  __shared__ char Blds[8192];
  const int mt = blockIdx.x, nt = blockIdx.y;
  const int tid = threadIdx.x, w = tid>>6, lane = tid&63;
  f32x4 acc[4];
  #pragma unroll
  for (int i = 0; i < 4; ++i) acc[i] = (f32x4)(0.f);
  for (int kt = 0; kt < 8; ++kt){
    __syncthreads();
    stage_tile(KF + (size_t)mt*64*DD, DD, kt*64, Alds);
    stage_tile(Wg + (size_t)nt*64*DD, DD, kt*64, Blds);
    __syncthreads();
    mma64(Alds, Blds, w, lane, acc);
  }
  const int q = nt*64 + w*16 + (lane&15);
  const float add = g_[q]*vq[q];
  #pragma unroll
  for (int fm = 0; fm < 4; ++fm)
    #pragma unroll
    for (int r = 0; r < 4; ++r){
      const int row = mt*64 + fm*16 + (lane>>4)*4 + r;
      G2[(size_t)row*DD + q] = f2bf(acc[fm][r] + add);
    }
}

// ---- sc12[row].  grid 144 x 512.
__global__ __launch_bounds__(512) void k_sc12(const unsigned short* __restrict__ KF,
    const float* __restrict__ u_, const float* __restrict__ voff,
    const float* __restrict__ cscal, float2* __restrict__ sc12){
  const int w = threadIdx.x>>6, lane = threadIdx.x&63;
  const int row = blockIdx.x*8 + w;
  const unsigned short* kf = KF + (size_t)row*DD + lane*8;
  float s1 = 0.f, s2 = 0.f;
  #pragma unroll
  for (int j = 0; j < 8; ++j){
    const float kv = bf2f(kf[j]);
    s1 = fmaf(u_[lane*8 + j],   kv, s1);
    s2 = fmaf(voff[lane*8 + j], kv, s2);
  }
  s1 = wave_reduce_sum(s1);
  s2 = wave_reduce_sum(s2);
  if (lane == 0){
    float2 o; o.x = s1 + cscal[2]; o.y = s2 + cscal[3];
    sc12[row] = o;
  }
}

// ---- h0/c0 GEMM (+ optional bf16 mirror)
__global__ __launch_bounds__(256) void k_init_g(const float* __restrict__ mean_a,
    const float* __restrict__ W, const float* __restrict__ bias,
    float* __restrict__ out, unsigned short* __restrict__ outbf){
  __shared__ float la[64*68];
  __shared__ float lb[64*68];
  const int j0 = blockIdx.x*64;
  const int tid = threadIdx.x, tr = tid&15, tn = tid>>4;
  float acc[16] = {0.f};
  for (int a0 = 0; a0 < DE; a0 += 64){
    __syncthreads();
    for (int i = tid; i < 4096; i += 256){
      const int b = i>>6, k = i&63;
      la[k*68 + b] = mean_a[(size_t)b*DE + a0+k];
    }
    for (int i = tid; i < 4096; i += 256){
      const int k = i>>6, j = i&63;
      lb[k*68 + j] = W[(size_t)(a0+k)*DD + j0+j];
    }
    __syncthreads();
    for (int k = 0; k < 64; ++k){
      float av[4], bv[4];
      #pragma unroll
      for (int ii = 0; ii < 4; ++ii) av[ii] = la[k*68 + tr*4+ii];
      #pragma unroll
      for (int jj = 0; jj < 4; ++jj) bv[jj] = lb[k*68 + tn*4+jj];
      #pragma unroll
      for (int ii = 0; ii < 4; ++ii)
        #pragma unroll
        for (int jj = 0; jj < 4; ++jj)
          acc[ii*4+jj] = fmaf(av[ii], bv[jj], acc[ii*4+jj]);
    }
  }
  #pragma unroll
  for (int ii = 0; ii < 4; ++ii)
    #pragma unroll
    for (int jj = 0; jj < 4; ++jj){
      const size_t idx = (size_t)(tr*4+ii)*DD + j0 + tn*4+jj;
      const float val = acc[ii*4+jj] + bias[j0 + tn*4+jj];
      out[idx] = val;
      if (outbf) outbf[idx] = f2bf(val);
    }
}

// ---- precompute eu_all[s][b][2048] = emb(s)@Wu (fp32).  grid (32 jt, 29 s).
__global__ __launch_bounds__(256) void k_EU(const float* __restrict__ emb_table,
    const int* __restrict__ captions, const unsigned short* __restrict__ wut,
    float* __restrict__ eu){
  __shared__ char Alds[8192];
  __shared__ char Blds[8192];
  __shared__ int capL[64];
  const int jt = blockIdx.x, s = blockIdx.y;
  const int tid = threadIdx.x, w = tid>>6, lane = tid&63;
  if (tid < 64) capL[tid] = captions[tid*NTT + s];
  f32x4 acc[4];
  #pragma unroll
  for (int i = 0; i < 4; ++i) acc[i] = (f32x4)(0.f);
  for (int kt = 0; kt < 5; ++kt){
    __syncthreads();
    #pragma unroll
    for (int c = 0; c < 2; ++c){
      const int o = tid + c*256;
      const int m = o>>3, ks8 = o&7;
      const int e0 = kt*64 + ks8*8;
      const float* er = emb_table + (size_t)capL[m]*EM;
      ushort8v v;
      #pragma unroll
      for (int jj = 0; jj < 8; ++jj)
        v[jj] = (e0 + jj < EM) ? f2bf(er[e0 + jj]) : (unsigned short)0;
      *(ushort8v*)&Alds[m*128 + ((ks8 ^ (m&7))<<4)] = v;
    }
    stage_tile(wut + (size_t)jt*64*KP, KP, kt*64, Blds);
    __syncthreads();
    mma64(Alds, Blds, w, lane, acc);
  }
  const int j = jt*64 + w*16 + (lane&15);
  #pragma unroll
  for (int fm = 0; fm < 4; ++fm)
    #pragma unroll
    for (int r = 0; r < 4; ++r){
      const int b = fm*16 + (lane>>4)*4 + r;
      eu[((size_t)s*NB + b)*G4 + j] = acc[fm][r];
    }
}

// ======== per-step kernel A (r19: 2 slices/batch, 16B score loads)
__global__ __launch_bounds__(512) void k_A(
    const float* __restrict__ gp, const float* __restrict__ eu,
    const float* __restrict__ b_gates, const float* __restrict__ cin,
    float* __restrict__ cout, unsigned short* __restrict__ hst,
    const unsigned short* __restrict__ G2, const float2* __restrict__ sc12,
    const unsigned short* __restrict__ fb, const float* __restrict__ gw,
    const float* __restrict__ cscal, const int s, const int do_att,
    float* __restrict__ alph, unsigned short* __restrict__ zbf){
  __shared__ alignas(16) unsigned short hL[DD];
  __shared__ float sc[NP];
  __shared__ float al[NP];
  __shared__ float sredA[8*4];
  __shared__ float sbufM[8];
  __shared__ float sbufS[8];
  // XCD grouping: 2 sl-blocks of each b + 8 b's share an XCD (bid%8)
  int sl, b;
  if (gridDim.x == 1){ sl = 0; b = blockIdx.y; }
  else {
    const int lin = blockIdx.x + 2*blockIdx.y;
    const int xcd = lin & 7, i = lin >> 3;
    b = xcd*8 + (i & 7);
    sl = i >> 3;
  }
  const int tid = threadIdx.x;
  const int w = tid>>6, lane = tid&63;
  float hn;
  if (s == 0){
    const unsigned short hb = hst[(size_t)b*DD + tid];
    hn = bf2f(hb);
    hL[tid] = hb;
  } else {
    const int m = s - 1;
    // explicit MLP: issue all KSPL*4 partial loads before summing
    float gv[4*KSPL];
    #pragma unroll
    for (int ks = 0; ks < KSPL; ++ks){
      const float* gr = gp + ((size_t)ks*NB + b)*G4 + tid;
      gv[ks*4+0] = gr[0];
      gv[ks*4+1] = gr[DD];
      gv[ks*4+2] = gr[2*DD];
      gv[ks*4+3] = gr[3*DD];
    }
    const float* eur = eu + ((size_t)m*NB + b)*G4 + tid;
    float gs0 = b_gates[tid]        + eur[0];
    float gs1 = b_gates[DD + tid]   + eur[DD];
    float gs2 = b_gates[2*DD + tid] + eur[2*DD];
    float gs3 = b_gates[3*DD + tid] + eur[3*DD];
    #pragma unroll
    for (int ks = 0; ks < KSPL; ++ks){
      gs0 += gv[ks*4+0]; gs1 += gv[ks*4+1];
      gs2 += gv[ks*4+2]; gs3 += gv[ks*4+3];
    }
    const size_t idx = (size_t)b*DD + tid;
    const float cn = sigm(gs1)*cin[idx] + sigm(gs0)*tanhf(gs3);
    hn = sigm(gs2)*tanhf(cn);
    cout[idx] = cn;
    const unsigned short hb = f2bf(hn);
    hst[(size_t)s*NB*DD + idx] = hb;
    hL[tid] = hb;
  }
  if (!do_att) return;
  float p1 = hn, p2 = hn*hn, p3 = hn*gw[tid];
  #pragma unroll
  for (int o = 32; o >= 1; o >>= 1){
    p1 += __shfl_xor(p1, o);
    p2 += __shfl_xor(p2, o);
    p3 += __shfl_xor(p3, o);
  }
  if (lane == 0){ sredA[w*4] = p1; sredA[w*4+1] = p2; sredA[w*4+2] = p3; }
  __syncthreads();
  float S1 = 0.f, S2 = 0.f, S3 = 0.f;
  #pragma unroll
  for (int i = 0; i < 8; ++i){
    S1 += sredA[i*4]; S2 += sredA[i*4+1]; S3 += sredA[i*4+2];
  }
  const float mean = S1*(1.f/512.f);
  const float var  = S2*(1.f/512.f) - mean*mean;
  const float rinv = rsqrtf(var + LN_EPS);
  const float beta = sigm(rinv*(S3 - mean*cscal[0]) + cscal[1]);
  const short8 hv = *(const short8*)&hL[lane*8];   // one 16B LDS load
  // scores in batches of 6 rows (MLP), 16B G2 loads
  #pragma unroll 1
  for (int i0 = 0; i0 < 18; i0 += 6){
    short8 U[6];
    float2 SV[6];
    #pragma unroll
    for (int j = 0; j < 6; ++j){
      const int p = w + 8*(i0+j);
      U[j] = *(const short8*)&G2[(size_t)(b*NP + p)*DD + lane*8];
      if (lane == 0) SV[j] = sc12[b*NP + p];
    }
    #pragma unroll
    for (int j = 0; j < 6; ++j){
      float a2 = 0.f;
      #pragma unroll
      for (int q = 0; q < 8; ++q)
        a2 = fmaf(bf2f((unsigned short)U[j][q]), bf2f((unsigned short)hv[q]), a2);
      a2 = wave_reduce_sum(a2);
      if (lane == 0)
        sc[w + 8*(i0+j)] = RSCALE*(rinv*a2 - rinv*mean*SV[j].x + SV[j].y);
    }
  }
  __syncthreads();
  const float v = (tid < NP) ? sc[tid] : -1e30f;
  const float mv = wave_reduce_max(v);
  if (lane == 0) sbufM[w] = mv;
  __syncthreads();
  float mm = sbufM[0];
  #pragma unroll
  for (int i = 1; i < 8; ++i) mm = fmaxf(mm, sbufM[i]);
  const float e = (tid < NP) ? __expf(v - mm) : 0.f;
  const float sv = wave_reduce_sum(e);
  if (lane == 0) sbufS[w] = sv;
  __syncthreads();
  float ssum = 0.f;
  #pragma unroll
  for (int i = 0; i < 8; ++i) ssum += sbufS[i];
  if (tid < NP){
    const float a3 = e / ssum;
    al[tid] = a3;
    if (sl == 0) alph[((size_t)b*NTT + s + 1)*NP + tid] = a3;
  }
  __syncthreads();
  if (tid < 448){
    const int d0 = sl*896 + tid*2;     // 2 cols/thread, ushort2 loads
    const unsigned short* fB = fb + (size_t)b*NP*DE + d0;
    float a0 = 0.f, a1 = 0.f;
    // z-GEMV in batches of 12 (MLP)
    #pragma unroll 1
    for (int p0 = 0; p0 < NP; p0 += 12){
      ushort2 fv[12];
      #pragma unroll
      for (int j = 0; j < 12; ++j) fv[j] = *(const ushort2*)&fB[(size_t)(p0+j)*DE];
      #pragma unroll
      for (int j = 0; j < 12; ++j){
        const float ap = al[p0+j];
        a0 = fmaf(ap, bf2f(fv[j].x), a0);
        a1 = fmaf(ap, bf2f(fv[j].y), a1);
      }
    }
    ushort2 zo;
    zo.x = f2bf(a0*beta);
    zo.y = f2bf(a1*beta);
    *(ushort2*)&zbf[((size_t)s*NB + b)*DE + d0] = zo;
  }
}

// ======== per-step kernel B (K-split 12).  grid (32, 12).
__global__ __launch_bounds__(256) void k_B(
    const unsigned short* __restrict__ hst, const unsigned short* __restrict__ zbf,
    const unsigned short* __restrict__ whT, const unsigned short* __restrict__ wat,
    const int s, float* __restrict__ gp){
  __shared__ char Alds[8192];
  __shared__ char Blds[8192];
  const int jt = blockIdx.x, ks = blockIdx.y;
  const int tid = threadIdx.x, w = tid>>6, lane = tid&63;
  const unsigned short* hrow = hst + (size_t)s*NB*DD;
  const unsigned short* zrow = zbf + (size_t)s*NB*DE;
  f32x4 acc[4];
  #pragma unroll
  for (int i = 0; i < 4; ++i) acc[i] = (f32x4)(0.f);
  for (int kt = 0; kt < 3; ++kt){
    const int k0 = ks*192 + kt*64;
    __syncthreads();
    if (k0 < DD) stage_tile(hrow, DD, k0, Alds);
    else         stage_tile(zrow, DE, k0 - DD, Alds);
    #pragma unroll
    for (int c2 = 0; c2 < 2; ++c2){
      const int o = tid + c2*256;
      const int m = o>>3, ks8 = o&7;
      const int col = (m>>4)*DD + jt*16 + (m&15);
      const unsigned short* src = (k0 < DD)
          ? whT + (size_t)col*DD + k0
          : wat + (size_t)col*DE + (k0 - DD);
      const ushort8v v = *(const ushort8v*)&src[ks8*8];
      *(ushort8v*)&Blds[m*128 + ((ks8 ^ (m&7))<<4)] = v;
    }
    __syncthreads();
    mma64(Alds, Blds, w, lane, acc);
  }
  const int jcol = jt*16 + (lane&15);
  float* gps = gp + (size_t)ks*NB*G4;
  #pragma unroll
  for (int fm = 0; fm < 4; ++fm)
    #pragma unroll
    for (int r = 0; r < 4; ++r){
      const int b = fm*16 + (lane>>4)*4 + r;
      gps[(size_t)b*G4 + w*DD + jcol] = acc[fm][r];
    }
}

// ---- post G1: out_o partial MFMA.  grid (5 e-tiles, 29 s, 6 ksplit).
__global__ __launch_bounds__(256) void k_G1m(const unsigned short* __restrict__ hstbf,
    const unsigned short* __restrict__ zbf, const unsigned short* __restrict__ WLt,
    float* __restrict__ g1p){
  __shared__ char Alds[8192];
  __shared__ char Blds[8192];
  const int e0 = blockIdx.x*64, s = blockIdx.y, ks6 = blockIdx.z;
  const int tid = threadIdx.x, w = tid>>6, lane = tid&63;
  const unsigned short* hrow = hstbf + (size_t)(s+1)*NB*DD;
  const unsigned short* zrow = zbf + (size_t)s*NB*DE;
  f32x4 acc[4];
  #pragma unroll
  for (int i = 0; i < 4; ++i) acc[i] = (f32x4)(0.f);
  for (int kt = 0; kt < 6; ++kt){
    const int k0 = ks6*384 + kt*64;
    __syncthreads();
    if (k0 < DD) stage_tile(hrow, DD, k0, Alds);
    else         stage_tile(zrow, DE, k0 - DD, Alds);
    stage_tile(WLt + (size_t)e0*KG1, KG1, k0, Blds);
    __syncthreads();
    mma64(Alds, Blds, w, lane, acc);
  }
  const int e = e0 + w*16 + (lane&15);
  float* dst = g1p + (size_t)ks6*NS*NB*KP;
  #pragma unroll
  for (int fm = 0; fm < 4; ++fm)
    #pragma unroll
    for (int r = 0; r < 4; ++r){
      const int b = fm*16 + (lane>>4)*4 + r;
      dst[((size_t)s*NB + b)*KP + e] = acc[fm][r];
    }
}

// ---- post G1red: sum 6 partials + emb + biases -> outo bf16
__global__ __launch_bounds__(256) void k_G1red(const float* __restrict__ g1p,
    const float* __restrict__ b_Lh, const float* __restrict__ b_Lz,
    const float* __restrict__ emb_table, const int* __restrict__ captions,
    unsigned short* __restrict__ outo){
  const int idx = blockIdx.x*256 + threadIdx.x;
  const int row = idx / KP, e = idx - row*KP;
  const int s = row >> 6, b = row & 63;
  float v = 0.f;
  #pragma unroll
  for (int ks6 = 0; ks6 < 6; ++ks6) v += g1p[(size_t)ks6*NS*NB*KP + idx];
  if (e < EM){
    const int cap = captions[b*NTT + s];
    v += b_Lh[e] + b_Lz[e] + emb_table[(size_t)cap*EM + e];
  } else v = 0.f;
  outo[idx] = f2bf(v);
}

// ---- post G2: logits MFMA, M-tile 128.  1D grid 1875 with bijective
// XCD-grouping swizzle (validated r18).  NONTEMPORAL stores.
__global__ __launch_bounds__(256) void k_G2(const unsigned short* __restrict__ Abf,
    const unsigned short* __restrict__ Bt, const float* __restrict__ b_Lo,
    float* __restrict__ pred){
  __shared__ char Alds[128*128];
  __shared__ char Blds[256*128];
  // nwg=1875, NXCD=8: q=234, r=3 (xcd 0..2 have 235 blocks)
  const int bid = blockIdx.x;
  const int xcd = bid & 7, idx8 = bid >> 3;
  const int wgid = (xcd < 3 ? xcd*235 : 705 + (xcd-3)*234) + idx8;
  const int nt = wgid / 15, mt = wgid - nt*15;
  const int tid = threadIdx.x, w = tid>>6, lane = tid&63;
  f32x4 acc[8][4];
  #pragma unroll
  for (int i = 0; i < 8; ++i)
    #pragma unroll
    for (int j = 0; j < 4; ++j)
      acc[i][j] = (f32x4)(0.f);
  for (int kt = 0; kt < 5; ++kt){
    const int k0 = kt*64;
    __syncthreads();
    #pragma unroll
    for (int c2 = 0; c2 < 4; ++c2){
      const int o16 = tid + c2*256;
      const int m = o16>>3, ks8 = o16&7;
      const ushort8v v = *(const ushort8v*)&Abf[(size_t)(mt*128+m)*KP + k0 + ks8*8];
      *(ushort8v*)&Alds[m*128 + ((ks8 ^ (m&7))<<4)] = v;
    }
    #pragma unroll
    for (int c2 = 0; c2 < 8; ++c2){
      const int o16 = tid + c2*256;
      const int n = o16>>3, ks8 = o16&7;
      const ushort8v v = *(const ushort8v*)&Bt[(size_t)(nt*256+n)*KP + k0 + ks8*8];
      *(ushort8v*)&Blds[n*128 + ((ks8 ^ (n&7))<<4)] = v;
    }
    __syncthreads();
    #pragma unroll
    for (int ks = 0; ks < 2; ++ks){
      const int slot = ks*4 + (lane>>4);
      short8 af[8];
      #pragma unroll
      for (int fm = 0; fm < 8; ++fm){
        const int m = fm*16 + (lane&15);
        af[fm] = *(const short8*)&Alds[m*128 + ((slot ^ (m&7))<<4)];
      }
      #pragma unroll
      for (int fn = 0; fn < 4; ++fn){
        const int n = w*64 + fn*16 + (lane&15);
        const short8 bfv = *(const short8*)&Blds[n*128 + ((slot ^ (n&7))<<4)];
        #pragma unroll
        for (int fm = 0; fm < 8; ++fm)
          acc[fm][fn] = __builtin_amdgcn_mfma_f32_16x16x32_bf16(af[fm], bfv, acc[fm][fn], 0, 0, 0);
      }
    }
  }
  const int ncol0 = nt*256 + w*64 + (lane&15);
  #pragma unroll
  for (int fm = 0; fm < 8; ++fm){
    #pragma unroll
    for (int r = 0; r < 4; ++r){
      const int row = mt*128 + fm*16 + (lane>>4)*4 + r;
      if (row < NS*NB){
        const int s = row >> 6, b = row & 63;
        float* prow = &pred[((size_t)b*NTT + s + 1)*NV + ncol0];
        #pragma unroll
        for (int fn = 0; fn < 4; ++fn)
          __builtin_nontemporal_store(acc[fm][fn][r] + b_Lo[ncol0 + fn*16],
                                      &prow[fn*16]);
      }
    }
  }
}

extern "C" void kernel_launch(void* const* d_in, const int* in_sizes, int n_in,
                              void* d_out, int out_size, void* d_ws, size_t ws_size,
                              hipStream_t stream){
  const float* features  = (const float*)d_in[0];
  const int*   captions  = (const int*)  d_in[1];
  const float* emb_table = (const float*)d_in[2];
  const float* ln_q_g = (const float*)d_in[3];
  const float* ln_q_b = (const float*)d_in[4];
  const float* ln_kv_g= (const float*)d_in[5];
  const float* ln_kv_b= (const float*)d_in[6];
  const float* Wq     = (const float*)d_in[7];
  const float* bq     = (const float*)d_in[8];
  const float* Wk     = (const float*)d_in[9];
  const float* bk     = (const float*)d_in[10];
  const float* Wbeta  = (const float*)d_in[11];
  const float* bbeta  = (const float*)d_in[12];
  const float* Wh     = (const float*)d_in[13];
  const float* Wu     = (const float*)d_in[14];
  const float* Wa     = (const float*)d_in[15];
  const float* b_gates= (const float*)d_in[16];
  const float* W_Lh   = (const float*)d_in[17];
  const float* b_Lh   = (const float*)d_in[18];
  const float* W_Lz   = (const float*)d_in[19];
  const float* b_Lz   = (const float*)d_in[20];
  const float* W_Lo   = (const float*)d_in[21];
  const float* b_Lo   = (const float*)d_in[22];
  const float* W_ih   = (const float*)d_in[23];
  const float* b_ih   = (const float*)d_in[24];
  const float* W_ic   = (const float*)d_in[25];
  const float* b_ic   = (const float*)d_in[26];

  float* pred = (float*)d_out;
  float* alph = pred + (size_t)NB * NTT * NV;

  char* w = (char*)d_ws;
  auto alloc = [&](size_t bytes) -> void* {
    void* p = (void*)w; w += (bytes + 255) & ~(size_t)255; return p;
  };
  unsigned short* feats_bf = (unsigned short*)alloc((size_t)NB*NP*DE * 2);
  unsigned short* wlo_t    = (unsigned short*)alloc((size_t)NV*KP * 2);
  unsigned short* whT      = (unsigned short*)alloc((size_t)G4*DD * 2);
  unsigned short* wut      = (unsigned short*)alloc((size_t)G4*KP * 2);
  unsigned short* wat      = (unsigned short*)alloc((size_t)G4*DE * 2);
  unsigned short* WkT      = (unsigned short*)alloc((size_t)DD*DE * 2);
  unsigned short* WLt      = (unsigned short*)alloc((size_t)KP*KG1 * 2);
  unsigned short* Wg       = (unsigned short*)alloc((size_t)DD*DD * 2);
  unsigned short* KFbf     = (unsigned short*)alloc((size_t)NB*NP*DD * 2);
  unsigned short* G2bf     = (unsigned short*)alloc((size_t)NB*NP*DD * 2);
  float2* sc12  = (float2*)alloc((size_t)NB*NP * 8);
  float* vq     = (float*)alloc((size_t)DD * 4);
  float* u_     = (float*)alloc((size_t)DD * 4);
  float* voff   = (float*)alloc((size_t)DD * 4);
  float* gw     = (float*)alloc((size_t)DD * 4);
  float* cscal  = (float*)alloc(16);
  float* mean_a = (float*)alloc((size_t)NB*DE * 4);
  float* hbuf   = (float*)alloc((size_t)NB*DD * 4);
  float* cb0    = (float*)alloc((size_t)NB*DD * 4);
  float* cb1    = (float*)alloc((size_t)NB*DD * 4);
  unsigned short* hstbf = (unsigned short*)alloc((size_t)(NS+1)*NB*DD * 2);
  unsigned short* zbf   = (unsigned short*)alloc((size_t)NS*NB*DE * 2);
  unsigned short* outo  = (unsigned short*)alloc((size_t)1920*KP * 2);
  float* gp     = (float*)alloc((size_t)KSPL*NB*G4 * 4);
  float* eu_all = (float*)alloc((size_t)NS*NB*G4 * 4);
  float* g1p    = (float*)alloc((size_t)6*NS*NB*KP * 4);
  float* cb[2] = { cb0, cb1 };

  k_zero<<<dim3((NB*NV)/256), dim3(256), 0, stream>>>(pred, alph);
  k_ln_feats<<<dim3(NB*NP), dim3(256), 0, stream>>>(features, ln_kv_g, ln_kv_b, feats_bf);
  k_mean<<<dim3((NB*DE)/256), dim3(256), 0, stream>>>(features, mean_a);
  k_cvt_T<<<dim3(NV/64, KP/64), dim3(256), 0, stream>>>(W_Lo, wlo_t, EM, NV, KP);
  k_cvt_T<<<dim3(G4/64, DD/64), dim3(256), 0, stream>>>(Wh, whT, DD, G4, DD);
  k_cvt_T<<<dim3(G4/64, KP/64), dim3(256), 0, stream>>>(Wu, wut, EM, G4, KP);
  k_cvt_T<<<dim3(G4/64, DE/64), dim3(256), 0, stream>>>(Wa, wat, DE, G4, DE);
  k_cvt_T<<<dim3(DD/64, DE/64), dim3(256), 0, stream>>>(Wk, WkT, DE, DD, DE);
  k_cvt_wlt<<<dim3(KP/64, KG1/64), dim3(256), 0, stream>>>(W_Lh, W_Lz, WLt);
  k_wg<<<dim3((DD*DD)/256), dim3(256), 0, stream>>>(Wq, ln_q_g, Wg);
  k_pre_vq<<<dim3(1), dim3(512), 0, stream>>>(Wq, bk, vq);
  k_uvoff<<<dim3(1), dim3(512), 0, stream>>>(Wq, ln_q_g, ln_q_b, bq, Wbeta, bbeta,
      bk, u_, voff, gw, cscal);
  k_KF<<<dim3(NB*NP/64, DD/64), dim3(256), 0, stream>>>(feats_bf, WkT, KFbf);
  k_QG2<<<dim3(NB*NP/64, DD/64), dim3(256), 0, stream>>>(KFbf, Wg, ln_q_g, vq, G2bf);
  k_sc12<<<dim3(NB*NP/8), dim3(512), 0, stream>>>(KFbf, u_, voff, cscal, sc12);
  k_init_g<<<dim3(DD/64), dim3(256), 0, stream>>>(mean_a, W_ih, b_ih, hbuf, hstbf);
  k_init_g<<<dim3(DD/64), dim3(256), 0, stream>>>(mean_a, W_ic, b_ic, cb0, nullptr);
  k_EU<<<dim3(G4/64, NS), dim3(256), 0, stream>>>(emb_table, captions, wut, eu_all);

  for (int s = 0; s < NS; ++s){
    k_A<<<dim3(2, NB), dim3(512), 0, stream>>>(gp, eu_all, b_gates,
        cb[(s & 1) ^ 1], cb[s & 1], hstbf, G2bf, sc12, feats_bf,
        gw, cscal, s, 1, alph, zbf);
    k_B<<<dim3(32, KSPL), dim3(256), 0, stream>>>(hstbf, zbf, whT, wat, s, gp);
  }
  // final LSTM -> h_29
  k_A<<<dim3(1, NB), dim3(512), 0, stream>>>(gp, eu_all, b_gates,
      cb[(NS & 1) ^ 1], cb[NS & 1], hstbf, G2bf, sc12, feats_bf,
      gw, cscal, NS, 0, alph, zbf);

  k_G1m<<<dim3(5, NS, 6), dim3(256), 0, stream>>>(hstbf, zbf, WLt, g1p);
  k_G1red<<<dim3((NS*NB*KP)/256), dim3(256), 0, stream>>>(g1p, b_Lh, b_Lz,
      emb_table, captions, outo);
  k_G2<<<dim3(1875), dim3(256), 0, stream>>>(outo, wlo_t, b_Lo, pred);
}